// Round 8
// baseline (1532.508 us; speedup 1.0000x reference)
//
#include <hip/hip_runtime.h>
#include <cstdint>
#include <cstddef>

#define N_NODES 50000
#define N_EDGES 400000
#define TOT_E   450000
#define G_GRAPHS 64
#define PB 256  // partial blocks for bnstats

typedef unsigned short u16;
typedef unsigned int u32;

__device__ __forceinline__ float b2f(u16 v) {
    union { u32 u; float f; } x; x.u = ((u32)v) << 16; return x.f;
}
__device__ __forceinline__ float lo2f(u32 u) {
    union { u32 u; float f; } x; x.u = u << 16; return x.f;
}
__device__ __forceinline__ float hi2f(u32 u) {
    union { u32 u; float f; } x; x.u = u & 0xffff0000u; return x.f;
}
__device__ __forceinline__ u16 f2b(float f) {
    union { float f; u32 u; } x; x.f = f;
    u32 r = x.u + 0x7fffu + ((x.u >> 16) & 1u);  // round-nearest-even
    return (u16)(r >> 16);
}

// ---------------- graph build ----------------
__global__ void k_init_deg(int* __restrict__ deg) {
    int i = blockIdx.x * blockDim.x + threadIdx.x;
    if (i < N_NODES) deg[i] = 1;  // self loop
}

__global__ void k_hist(const int* __restrict__ ei, int* __restrict__ deg) {
    int e = blockIdx.x * blockDim.x + threadIdx.x;
    if (e < N_EDGES) atomicAdd(&deg[ei[N_EDGES + e]], 1);
}

__global__ void k_scan(const int* __restrict__ deg, int* __restrict__ rowptr,
                       int* __restrict__ cursor) {
    __shared__ int buf[1024];
    __shared__ int carry_s;
    int tid = threadIdx.x;
    if (tid == 0) carry_s = 0;
    __syncthreads();
    for (int base = 0; base < N_NODES; base += 1024) {
        int i = base + tid;
        int v = (i < N_NODES) ? deg[i] : 0;
        buf[tid] = v;
        __syncthreads();
        for (int off = 1; off < 1024; off <<= 1) {
            int t = (tid >= off) ? buf[tid - off] : 0;
            __syncthreads();
            buf[tid] += t;
            __syncthreads();
        }
        int excl = buf[tid] - v;
        int carry = carry_s;
        if (i < N_NODES) { rowptr[i] = carry + excl; cursor[i] = carry + excl; }
        __syncthreads();
        if (tid == 1023) carry_s += buf[1023];
        __syncthreads();
    }
    if (tid == 0) rowptr[N_NODES] = carry_s;
}

__global__ void k_scatter(const int* __restrict__ ei, int* __restrict__ cursor,
                          int* __restrict__ col, int* __restrict__ cdst) {
    int e = blockIdx.x * blockDim.x + threadIdx.x;
    if (e < N_EDGES) {
        int s = ei[e], d = ei[N_EDGES + e];
        int p = atomicAdd(&cursor[d], 1);
        col[p] = s;
        cdst[p] = d;
    } else if (e < TOT_E) {
        int i = e - N_EDGES;
        int p = atomicAdd(&cursor[i], 1);
        col[p] = i;
        cdst[p] = i;
    }
}

// ---------------- register-tiled GEMM: Y[N,NO] = xform(X)[N,K] @ W[K,NO], bf16 out ----
// 32 rows x NO cols per block; 256 threads = 64 cols x 4 row-groups; each thread
// 8 rows x CPT cols. xs reads are wave-broadcast (same addr across lanes).
template<int K, int NO, bool XFORM>
__global__ void k_gemm(const float* __restrict__ X, const float* __restrict__ W,
                       const float* __restrict__ scale, const float* __restrict__ shift,
                       u16* __restrict__ Y) {
    constexpr int TM = 32;
    constexpr int CPT = NO / 64;
    __shared__ float xs[TM][K + 4];
    int tid = threadIdx.x;
    int r0 = blockIdx.x * TM;
    constexpr int NV = TM * K / 4;
    for (int i = tid; i < NV; i += 256) {
        int rr = (i * 4) / K, kk = (i * 4) % K;
        float4 v = make_float4(0.f, 0.f, 0.f, 0.f);
        if (r0 + rr < N_NODES) {
            v = *(const float4*)&X[(size_t)(r0 + rr) * K + kk];
            if (XFORM) {
                v.x = fmaxf(v.x * scale[kk] + shift[kk], 0.f);
                v.y = fmaxf(v.y * scale[kk + 1] + shift[kk + 1], 0.f);
                v.z = fmaxf(v.z * scale[kk + 2] + shift[kk + 2], 0.f);
                v.w = fmaxf(v.w * scale[kk + 3] + shift[kk + 3], 0.f);
            }
        }
        *(float4*)&xs[rr][kk] = v;
    }
    __syncthreads();
    int c = tid & 63;
    int rbase = (tid >> 6) * 8;
    float acc[8][CPT];
#pragma unroll
    for (int r = 0; r < 8; r++)
#pragma unroll
        for (int j = 0; j < CPT; j++) acc[r][j] = 0.f;

    for (int kq = 0; kq < K; kq += 4) {
        float4 xv[8];
#pragma unroll
        for (int r = 0; r < 8; r++) xv[r] = *(const float4*)&xs[rbase + r][kq];
#pragma unroll
        for (int kk = 0; kk < 4; kk++) {
            float w[CPT];
#pragma unroll
            for (int j = 0; j < CPT; j++) w[j] = W[(size_t)(kq + kk) * NO + c + 64 * j];
#pragma unroll
            for (int r = 0; r < 8; r++) {
                float xk = (kk == 0) ? xv[r].x : (kk == 1) ? xv[r].y : (kk == 2) ? xv[r].z : xv[r].w;
#pragma unroll
                for (int j = 0; j < CPT; j++) acc[r][j] = fmaf(xk, w[j], acc[r][j]);
            }
        }
    }
#pragma unroll
    for (int r = 0; r < 8; r++) {
        int grow = r0 + rbase + r;
        if (grow < N_NODES) {
#pragma unroll
            for (int j = 0; j < CPT; j++)
                Y[(size_t)grow * NO + c + 64 * j] = f2b(acc[r][j]);
        }
    }
}

// ---------------- attention scores (bf16 input, uint-packed reads) ----------------
template<int H, int C>
__global__ void k_scores(const u16* __restrict__ Hm, const float* __restrict__ asrc,
                         const float* __restrict__ adst, float* __restrict__ ssrc,
                         float* __restrict__ sdst) {
    int t = blockIdx.x * blockDim.x + threadIdx.x;
    if (t >= N_NODES * H) return;
    int i = t / H, h = t - i * H;
    const u32* row = (const u32*)(Hm + (size_t)i * H * C + h * C);
    float s1 = 0.f, s2 = 0.f;
#pragma unroll
    for (int c2 = 0; c2 < C / 2; c2++) {
        u32 u = row[c2];
        float v0 = lo2f(u), v1 = hi2f(u);
        int c = c2 * 2;
        s1 = fmaf(v0, asrc[h * C + c], fmaf(v1, asrc[h * C + c + 1], s1));
        s2 = fmaf(v0, adst[h * C + c], fmaf(v1, adst[h * C + c + 1], s2));
    }
    ssrc[t] = s1;
    sdst[t] = s2;
}

// ---------------- edge weights: w[p,h] = exp(leaky(ssrc[src]+sdst[dst])) ----------------
template<int H>
__global__ void k_ew(const float* __restrict__ ssrc, const float* __restrict__ sdst,
                     const int* __restrict__ col, const int* __restrict__ cdst,
                     float* __restrict__ w) {
    int t = blockIdx.x * blockDim.x + threadIdx.x;
    if (t >= TOT_E * H) return;
    int p = t / H, h = t - p * H;
    int s = col[p], d = cdst[p];
    float v = ssrc[(size_t)s * H + h] + sdst[(size_t)d * H + h];
    v = (v > 0.f) ? v : 0.2f * v;
    w[t] = __expf(v);
}

// ---------------- fused softmax-denominator + aggregation (bf16 gather) ----------------
template<int H, int C>
__global__ void k_agg(const u16* __restrict__ Hm, const float* __restrict__ w,
                      const int* __restrict__ rowptr, const int* __restrict__ col,
                      const float* __restrict__ bias, float* __restrict__ out) {
    constexpr int HC = H * C;
    constexpr int K = HC / 64;
    int wid = (int)((blockIdx.x * blockDim.x + threadIdx.x) >> 6);
    int lane = threadIdx.x & 63;
    if (wid >= N_NODES) return;
    float acc[K];
    int hidx[K];
#pragma unroll
    for (int k = 0; k < K; k++) { acc[k] = 0.f; hidx[k] = (lane + 64 * k) / C; }
    float z = 0.f;
    int beg = rowptr[wid], end = rowptr[wid + 1];
    for (int base = beg; base < end; base += 64) {
        int nmax = min(64, end - base);
        int myc = (base + lane < end) ? col[base + lane] : 0;
        int j = 0;
        for (; j + 4 <= nmax; j += 4) {
            int s0 = __shfl(myc, j), s1 = __shfl(myc, j + 1);
            int s2 = __shfl(myc, j + 2), s3 = __shfl(myc, j + 3);
            float w0 = 0.f, w1 = 0.f, w2 = 0.f, w3 = 0.f;
            if (lane < H) {
                w0 = w[(size_t)(base + j) * H + lane];
                w1 = w[(size_t)(base + j + 1) * H + lane];
                w2 = w[(size_t)(base + j + 2) * H + lane];
                w3 = w[(size_t)(base + j + 3) * H + lane];
                z += (w0 + w1) + (w2 + w3);
            }
            const u16* r0 = Hm + (size_t)s0 * HC;
            const u16* r1 = Hm + (size_t)s1 * HC;
            const u16* r2 = Hm + (size_t)s2 * HC;
            const u16* r3 = Hm + (size_t)s3 * HC;
#pragma unroll
            for (int k = 0; k < K; k++) {
                int el = lane + 64 * k;
                float a0 = b2f(r0[el]), a1 = b2f(r1[el]);
                float a2 = b2f(r2[el]), a3 = b2f(r3[el]);
                acc[k] = fmaf(__shfl(w0, hidx[k]), a0, acc[k]);
                acc[k] = fmaf(__shfl(w1, hidx[k]), a1, acc[k]);
                acc[k] = fmaf(__shfl(w2, hidx[k]), a2, acc[k]);
                acc[k] = fmaf(__shfl(w3, hidx[k]), a3, acc[k]);
            }
        }
        for (; j < nmax; j++) {
            int s0 = __shfl(myc, j);
            float w0 = 0.f;
            if (lane < H) { w0 = w[(size_t)(base + j) * H + lane]; z += w0; }
            const u16* r0 = Hm + (size_t)s0 * HC;
#pragma unroll
            for (int k = 0; k < K; k++)
                acc[k] = fmaf(__shfl(w0, hidx[k]), b2f(r0[lane + 64 * k]), acc[k]);
        }
    }
#pragma unroll
    for (int k = 0; k < K; k++) {
        float zk = __shfl(z, hidx[k]);
        int el = lane + 64 * k;
        out[(size_t)wid * HC + el] = acc[k] / (zk + 1e-16f) + bias[el];
    }
}

// ---------------- small linear: Y[N,NO] = relu(bn(X))[N,K] @ W[K,NO] + b ----------------
template<int K, int NO, int TPR>
__global__ void k_lin(const float* __restrict__ X, const float* __restrict__ W,
                      const float* __restrict__ wb, const float* __restrict__ scale,
                      const float* __restrict__ shift, float* __restrict__ Y) {
    constexpr int KS = K / TPR;  // k per wave-slice
    __shared__ float red[TPR][64][NO];
    int lane = threadIdx.x & 63;
    int wv = __builtin_amdgcn_readfirstlane(threadIdx.x >> 6);  // wave-uniform slice id
    int row = blockIdx.x * 64 + lane;
    int k0 = wv * KS;
    float acc[NO];
#pragma unroll
    for (int c = 0; c < NO; c++) acc[c] = 0.f;
    if (row < N_NODES) {
        const float* xr = X + (size_t)row * K + k0;
        for (int kk = 0; kk < KS; kk += 4) {
            float4 xv = *(const float4*)&xr[kk];
            int k = k0 + kk;
            float x0 = fmaxf(xv.x * scale[k] + shift[k], 0.f);
            float x1 = fmaxf(xv.y * scale[k + 1] + shift[k + 1], 0.f);
            float x2 = fmaxf(xv.z * scale[k + 2] + shift[k + 2], 0.f);
            float x3 = fmaxf(xv.w * scale[k + 3] + shift[k + 3], 0.f);
#pragma unroll
            for (int c = 0; c < NO; c++) {
                acc[c] = fmaf(x0, W[(size_t)k * NO + c],
                         fmaf(x1, W[(size_t)(k + 1) * NO + c],
                         fmaf(x2, W[(size_t)(k + 2) * NO + c],
                         fmaf(x3, W[(size_t)(k + 3) * NO + c], acc[c]))));
            }
        }
    }
#pragma unroll
    for (int c = 0; c < NO; c++) red[wv][lane][c] = acc[c];
    __syncthreads();
    for (int i = threadIdx.x; i < 64 * NO; i += 64 * TPR) {
        int r = i / NO, c = i - r * NO;
        float s = wb[c];
#pragma unroll
        for (int t = 0; t < TPR; t++) s += red[t][r][c];
        int grow = blockIdx.x * 64 + r;
        if (grow < N_NODES) Y[(size_t)grow * NO + c] = s;
    }
}

// ---------------- batchnorm stats: atomic-free per-block partials ----------------
template<int NO>
__global__ void k_bnstats(const float* __restrict__ X, float* __restrict__ psum,
                          float* __restrict__ psumsq) {
    constexpr int BS = (NO >= 256) ? NO : 256;
    constexpr int RPS = BS / NO;
    __shared__ float ls[BS], ls2[BS];
    int c = threadIdx.x % NO;
    int rsub = threadIdx.x / NO;
    constexpr int chunk = (N_NODES + PB - 1) / PB;
    int r0 = blockIdx.x * chunk;
    int r1 = min(N_NODES, r0 + chunk);
    float s = 0.f, s2 = 0.f;
    for (int r = r0 + rsub; r < r1; r += RPS) {
        float v = X[(size_t)r * NO + c];
        s += v;
        s2 += v * v;
    }
    if (RPS > 1) {
        ls[threadIdx.x] = s;
        ls2[threadIdx.x] = s2;
        __syncthreads();
        for (int off = BS / 2; off >= NO; off >>= 1) {
            if (threadIdx.x < off) {
                ls[threadIdx.x] += ls[threadIdx.x + off];
                ls2[threadIdx.x] += ls2[threadIdx.x + off];
            }
            __syncthreads();
        }
        s = ls[threadIdx.x];
        s2 = ls2[threadIdx.x];
    }
    if (rsub == 0) {
        psum[(size_t)blockIdx.x * NO + c] = s;
        psumsq[(size_t)blockIdx.x * NO + c] = s2;
    }
}

__global__ void k_bnfinal(const float* __restrict__ psum, const float* __restrict__ psumsq,
                          const float* __restrict__ g, const float* __restrict__ be,
                          float* __restrict__ scale, float* __restrict__ shift, int NO) {
    int t = threadIdx.x;
    if (t >= NO) return;
    float s = 0.f, s2 = 0.f;
    for (int b = 0; b < PB; b++) {
        s += psum[(size_t)b * NO + t];
        s2 += psumsq[(size_t)b * NO + t];
    }
    float mu = s / (float)N_NODES;
    float var = s2 / (float)N_NODES - mu * mu;
    float sc = g[t] * rsqrtf(var + 1e-5f);
    scale[t] = sc;
    shift[t] = be[t] - mu * sc;
}

// ---------------- pooling ----------------
__global__ void k_bhist(const int* __restrict__ batch, int* __restrict__ cnt) {
    __shared__ int h[G_GRAPHS];
    int tid = threadIdx.x;
    if (tid < G_GRAPHS) h[tid] = 0;
    __syncthreads();
    int i = blockIdx.x * blockDim.x + tid;
    if (i < N_NODES) atomicAdd(&h[batch[i]], 1);
    __syncthreads();
    if (tid < G_GRAPHS) atomicAdd(&cnt[tid], h[tid]);
}

__global__ void k_pool(const float* __restrict__ X, const int* __restrict__ batch,
                       const float* __restrict__ sc, const float* __restrict__ sh,
                       float* __restrict__ pooled) {
    int t = threadIdx.x;  // 384
    const int chunk = (N_NODES + 511) / 512;
    int r0 = blockIdx.x * chunk;
    int r1 = min(N_NODES, r0 + chunk);
    if (r0 >= N_NODES) return;
    float acc = 0.f;
    int cur = batch[r0];
    for (int r = r0; r < r1; r++) {
        int gid = batch[r];
        if (gid != cur) {
            atomicAdd(&pooled[(size_t)cur * 384 + t], acc);
            acc = 0.f;
            cur = gid;
        }
        float v = X[(size_t)r * 384 + t] * sc[t] + sh[t];
        acc += fmaxf(v, 0.f);
    }
    atomicAdd(&pooled[(size_t)cur * 384 + t], acc);
}

__global__ void k_final(const float* __restrict__ pooled, const int* __restrict__ cnt,
                        const float* __restrict__ lwf, const float* __restrict__ lbf,
                        float* __restrict__ out) {
    int t = threadIdx.x;  // 640
    if (t >= G_GRAPHS * 10) return;
    int g = t / 10, c = t - g * 10;
    float inv = 1.0f / fmaxf((float)cnt[g], 1.0f);
    float acc = lbf[c];
    for (int k = 0; k < 384; k++)
        acc = fmaf(pooled[(size_t)g * 384 + k] * inv, lwf[k * 10 + c], acc);
    out[t] = acc;
}

extern "C" void kernel_launch(void* const* d_in, const int* in_sizes, int n_in,
                              void* d_out, int out_size, void* d_ws, size_t ws_size,
                              hipStream_t stream) {
    const float* x    = (const float*)d_in[0];
    const int*   ei   = (const int*)d_in[1];
    const int*   batch= (const int*)d_in[2];
    const float* W1   = (const float*)d_in[3];
    const float* as1  = (const float*)d_in[4];
    const float* ad1  = (const float*)d_in[5];
    const float* b1   = (const float*)d_in[6];
    const float* g1   = (const float*)d_in[7];
    const float* be1  = (const float*)d_in[8];
    const float* lw1  = (const float*)d_in[9];
    const float* lb1  = (const float*)d_in[10];
    const float* gl1  = (const float*)d_in[11];
    const float* bel1 = (const float*)d_in[12];
    const float* W2   = (const float*)d_in[13];
    const float* as2  = (const float*)d_in[14];
    const float* ad2  = (const float*)d_in[15];
    const float* b2   = (const float*)d_in[16];
    const float* g2   = (const float*)d_in[17];
    const float* be2  = (const float*)d_in[18];
    const float* lw2  = (const float*)d_in[19];
    const float* lb2  = (const float*)d_in[20];
    const float* gl2  = (const float*)d_in[21];
    const float* bel2 = (const float*)d_in[22];
    const float* W3   = (const float*)d_in[23];
    const float* as3  = (const float*)d_in[24];
    const float* ad3  = (const float*)d_in[25];
    const float* b3   = (const float*)d_in[26];
    const float* g3   = (const float*)d_in[27];
    const float* be3  = (const float*)d_in[28];
    const float* lwf  = (const float*)d_in[29];
    const float* lbf  = (const float*)d_in[30];
    float* out = (float*)d_out;

    // ---- workspace carve ----
    char* p = (char*)d_ws;
    auto alloc = [&](size_t bytes) {
        char* r = p;
        p += (bytes + 255) & ~(size_t)255;
        return r;
    };
    int*   rowptr = (int*)alloc(4 * (size_t)(N_NODES + 1));
    int*   cursor = (int*)alloc(4 * (size_t)N_NODES);
    int*   deg    = (int*)alloc(4 * (size_t)N_NODES);
    int*   col    = (int*)alloc(4 * (size_t)TOT_E);
    int*   cdst   = (int*)alloc(4 * (size_t)TOT_E);
    float* ssrc   = (float*)alloc(4 * (size_t)N_NODES * 20);
    float* sdst   = (float*)alloc(4 * (size_t)N_NODES * 20);
    float* ew     = (float*)alloc(4 * (size_t)TOT_E * 20);
    u16*   hbuf   = (u16*)alloc(2 * (size_t)N_NODES * 512);
    float* obuf   = (float*)alloc(4 * (size_t)N_NODES * 512);
    float* xbuf   = (float*)alloc(4 * (size_t)N_NODES * 32);
    float* psum   = (float*)alloc(4 * (size_t)PB * 512);
    float* psumsq = (float*)alloc(4 * (size_t)PB * 512);
    float* scA    = (float*)alloc(4 * 512);
    float* shA    = (float*)alloc(4 * 512);
    float* scB    = (float*)alloc(4 * 64);
    float* shB    = (float*)alloc(4 * 64);
    float* pooled = (float*)alloc(4 * (size_t)G_GRAPHS * 384);
    int*   cnt    = (int*)alloc(4 * G_GRAPHS);

    const int LB = (N_NODES + 63) / 64;   // 782 row-tiles for k_lin
    const int GB = (N_NODES + 31) / 32;   // 1563 row-tiles for k_gemm

    // ---- graph build (reused by all 3 layers) ----
    k_init_deg<<<(N_NODES + 255) / 256, 256, 0, stream>>>(deg);
    k_hist<<<(N_EDGES + 255) / 256, 256, 0, stream>>>(ei, deg);
    k_scan<<<1, 1024, 0, stream>>>(deg, rowptr, cursor);
    k_scatter<<<(TOT_E + 255) / 256, 256, 0, stream>>>(ei, cursor, col, cdst);
    hipMemsetAsync(pooled, 0, 4 * (size_t)G_GRAPHS * 384 + 256, stream);  // pooled + cnt

    // ---- layer 1: GAT(128 -> 20x16) ----
    k_gemm<128, 320, false><<<GB, 256, 0, stream>>>(x, W1, nullptr, nullptr, hbuf);
    k_scores<20, 16><<<(N_NODES * 20 + 255) / 256, 256, 0, stream>>>(hbuf, as1, ad1, ssrc, sdst);
    k_ew<20><<<(TOT_E * 20 + 255) / 256, 256, 0, stream>>>(ssrc, sdst, col, cdst, ew);
    k_agg<20, 16><<<(N_NODES + 3) / 4, 256, 0, stream>>>(hbuf, ew, rowptr, col, b1, obuf);
    k_bnstats<320><<<PB, 320, 0, stream>>>(obuf, psum, psumsq);
    k_bnfinal<<<1, 512, 0, stream>>>(psum, psumsq, g1, be1, scA, shA, 320);
    k_lin<320, 16, 4><<<LB, 256, 0, stream>>>(obuf, lw1, lb1, scA, shA, xbuf);
    k_bnstats<16><<<PB, 256, 0, stream>>>(xbuf, psum, psumsq);
    k_bnfinal<<<1, 512, 0, stream>>>(psum, psumsq, gl1, bel1, scB, shB, 16);

    // ---- layer 2: GAT(16 -> 16x32) ----
    k_gemm<16, 512, true><<<GB, 256, 0, stream>>>(xbuf, W2, scB, shB, hbuf);
    k_scores<16, 32><<<(N_NODES * 16 + 255) / 256, 256, 0, stream>>>(hbuf, as2, ad2, ssrc, sdst);
    k_ew<16><<<(TOT_E * 16 + 255) / 256, 256, 0, stream>>>(ssrc, sdst, col, cdst, ew);
    k_agg<16, 32><<<(N_NODES + 3) / 4, 256, 0, stream>>>(hbuf, ew, rowptr, col, b2, obuf);
    k_bnstats<512><<<PB, 512, 0, stream>>>(obuf, psum, psumsq);
    k_bnfinal<<<1, 512, 0, stream>>>(psum, psumsq, g2, be2, scA, shA, 512);
    k_lin<512, 32, 4><<<LB, 256, 0, stream>>>(obuf, lw2, lb2, scA, shA, xbuf);
    k_bnstats<32><<<PB, 256, 0, stream>>>(xbuf, psum, psumsq);
    k_bnfinal<<<1, 512, 0, stream>>>(psum, psumsq, gl2, bel2, scB, shB, 32);

    // ---- layer 3: GAT(32 -> 8x48) ----
    k_gemm<32, 384, true><<<GB, 256, 0, stream>>>(xbuf, W3, scB, shB, hbuf);
    k_scores<8, 48><<<(N_NODES * 8 + 255) / 256, 256, 0, stream>>>(hbuf, as3, ad3, ssrc, sdst);
    k_ew<8><<<(TOT_E * 8 + 255) / 256, 256, 0, stream>>>(ssrc, sdst, col, cdst, ew);
    k_agg<8, 48><<<(N_NODES + 3) / 4, 256, 0, stream>>>(hbuf, ew, rowptr, col, b3, obuf);
    k_bnstats<384><<<PB, 384, 0, stream>>>(obuf, psum, psumsq);
    k_bnfinal<<<1, 512, 0, stream>>>(psum, psumsq, g3, be3, scA, shA, 384);

    // ---- pool + classifier ----
    k_bhist<<<(N_NODES + 255) / 256, 256, 0, stream>>>(batch, cnt);
    k_pool<<<512, 384, 0, stream>>>(obuf, batch, scA, shA, pooled);
    k_final<<<1, 640, 0, stream>>>(pooled, cnt, lwf, lbf, out);
}

// Round 9
// 1154.752 us; speedup vs baseline: 1.3271x; 1.3271x over previous
//
#include <hip/hip_runtime.h>
#include <cstdint>
#include <cstddef>

#define N_NODES 50000
#define N_EDGES 400000
#define TOT_E   450000
#define G_GRAPHS 64
#define PB 256  // partial blocks for bnstats

typedef unsigned short u16;
typedef unsigned int u32;

__device__ __forceinline__ float b2f(u16 v) {
    union { u32 u; float f; } x; x.u = ((u32)v) << 16; return x.f;
}
__device__ __forceinline__ float lo2f(u32 u) {
    union { u32 u; float f; } x; x.u = u << 16; return x.f;
}
__device__ __forceinline__ float hi2f(u32 u) {
    union { u32 u; float f; } x; x.u = u & 0xffff0000u; return x.f;
}
__device__ __forceinline__ u16 f2b(float f) {
    union { float f; u32 u; } x; x.f = f;
    u32 r = x.u + 0x7fffu + ((x.u >> 16) & 1u);  // round-nearest-even
    return (u16)(r >> 16);
}

// ---------------- graph build ----------------
__global__ void k_init_deg(int* __restrict__ deg) {
    int i = blockIdx.x * blockDim.x + threadIdx.x;
    if (i < N_NODES) deg[i] = 1;  // self loop
}

__global__ void k_hist(const int* __restrict__ ei, int* __restrict__ deg) {
    int e = blockIdx.x * blockDim.x + threadIdx.x;
    if (e < N_EDGES) atomicAdd(&deg[ei[N_EDGES + e]], 1);
}

__global__ void k_scan(const int* __restrict__ deg, int* __restrict__ rowptr,
                       int* __restrict__ cursor) {
    __shared__ int buf[1024];
    __shared__ int carry_s;
    int tid = threadIdx.x;
    if (tid == 0) carry_s = 0;
    __syncthreads();
    for (int base = 0; base < N_NODES; base += 1024) {
        int i = base + tid;
        int v = (i < N_NODES) ? deg[i] : 0;
        buf[tid] = v;
        __syncthreads();
        for (int off = 1; off < 1024; off <<= 1) {
            int t = (tid >= off) ? buf[tid - off] : 0;
            __syncthreads();
            buf[tid] += t;
            __syncthreads();
        }
        int excl = buf[tid] - v;
        int carry = carry_s;
        if (i < N_NODES) { rowptr[i] = carry + excl; cursor[i] = carry + excl; }
        __syncthreads();
        if (tid == 1023) carry_s += buf[1023];
        __syncthreads();
    }
    if (tid == 0) rowptr[N_NODES] = carry_s;
}

__global__ void k_scatter(const int* __restrict__ ei, int* __restrict__ cursor,
                          int* __restrict__ col, int* __restrict__ cdst) {
    int e = blockIdx.x * blockDim.x + threadIdx.x;
    if (e < N_EDGES) {
        int s = ei[e], d = ei[N_EDGES + e];
        int p = atomicAdd(&cursor[d], 1);
        col[p] = s;
        cdst[p] = d;
    } else if (e < TOT_E) {
        int i = e - N_EDGES;
        int p = atomicAdd(&cursor[i], 1);
        col[p] = i;
        cdst[p] = i;
    }
}

// ---------------- register-tiled GEMM: Y[N,NO] = xform(X)[N,K] @ W[K,NO], bf16 out ----
// 32 rows x NO cols per block; 256 threads = 64 cols x 4 row-groups; each thread
// 8 rows x CPT cols. xs reads are wave-broadcast (same addr across lanes).
// __launch_bounds__(256,2): 2 waves/EU min -> up to 256 VGPRs, keeps acc/xv/w
// in registers (round-8 regression: default 8-wave target = 64 VGPRs = scratch
// spill, FETCH 670 MB/dispatch).
template<int K, int NO, bool XFORM>
__global__ __launch_bounds__(256, 2)
void k_gemm(const float* __restrict__ X, const float* __restrict__ W,
            const float* __restrict__ scale, const float* __restrict__ shift,
            u16* __restrict__ Y) {
    constexpr int TM = 32;
    constexpr int CPT = NO / 64;
    __shared__ float xs[TM][K + 4];
    int tid = threadIdx.x;
    int r0 = blockIdx.x * TM;
    constexpr int NV = TM * K / 4;
    for (int i = tid; i < NV; i += 256) {
        int rr = (i * 4) / K, kk = (i * 4) % K;
        float4 v = make_float4(0.f, 0.f, 0.f, 0.f);
        if (r0 + rr < N_NODES) {
            v = *(const float4*)&X[(size_t)(r0 + rr) * K + kk];
            if (XFORM) {
                v.x = fmaxf(v.x * scale[kk] + shift[kk], 0.f);
                v.y = fmaxf(v.y * scale[kk + 1] + shift[kk + 1], 0.f);
                v.z = fmaxf(v.z * scale[kk + 2] + shift[kk + 2], 0.f);
                v.w = fmaxf(v.w * scale[kk + 3] + shift[kk + 3], 0.f);
            }
        }
        *(float4*)&xs[rr][kk] = v;
    }
    __syncthreads();
    int c = tid & 63;
    int rbase = (tid >> 6) * 8;
    float acc[8][CPT];
#pragma unroll
    for (int r = 0; r < 8; r++)
#pragma unroll
        for (int j = 0; j < CPT; j++) acc[r][j] = 0.f;

    for (int kq = 0; kq < K; kq += 4) {
        float4 xv[8];
#pragma unroll
        for (int r = 0; r < 8; r++) xv[r] = *(const float4*)&xs[rbase + r][kq];
#pragma unroll
        for (int kk = 0; kk < 4; kk++) {
            float w[CPT];
#pragma unroll
            for (int j = 0; j < CPT; j++) w[j] = W[(size_t)(kq + kk) * NO + c + 64 * j];
#pragma unroll
            for (int r = 0; r < 8; r++) {
                float xk = (kk == 0) ? xv[r].x : (kk == 1) ? xv[r].y : (kk == 2) ? xv[r].z : xv[r].w;
#pragma unroll
                for (int j = 0; j < CPT; j++) acc[r][j] = fmaf(xk, w[j], acc[r][j]);
            }
        }
    }
#pragma unroll
    for (int r = 0; r < 8; r++) {
        int grow = r0 + rbase + r;
        if (grow < N_NODES) {
#pragma unroll
            for (int j = 0; j < CPT; j++)
                Y[(size_t)grow * NO + c + 64 * j] = f2b(acc[r][j]);
        }
    }
}

// ---------------- attention scores (bf16 input, uint-packed reads) ----------------
template<int H, int C>
__global__ void k_scores(const u16* __restrict__ Hm, const float* __restrict__ asrc,
                         const float* __restrict__ adst, float* __restrict__ ssrc,
                         float* __restrict__ sdst) {
    int t = blockIdx.x * blockDim.x + threadIdx.x;
    if (t >= N_NODES * H) return;
    int i = t / H, h = t - i * H;
    const u32* row = (const u32*)(Hm + (size_t)i * H * C + h * C);
    float s1 = 0.f, s2 = 0.f;
#pragma unroll
    for (int c2 = 0; c2 < C / 2; c2++) {
        u32 u = row[c2];
        float v0 = lo2f(u), v1 = hi2f(u);
        int c = c2 * 2;
        s1 = fmaf(v0, asrc[h * C + c], fmaf(v1, asrc[h * C + c + 1], s1));
        s2 = fmaf(v0, adst[h * C + c], fmaf(v1, adst[h * C + c + 1], s2));
    }
    ssrc[t] = s1;
    sdst[t] = s2;
}

// ---------------- edge weights: w[p,h] = exp(leaky(ssrc[src]+sdst[dst])) ----------------
template<int H>
__global__ void k_ew(const float* __restrict__ ssrc, const float* __restrict__ sdst,
                     const int* __restrict__ col, const int* __restrict__ cdst,
                     float* __restrict__ w) {
    int t = blockIdx.x * blockDim.x + threadIdx.x;
    if (t >= TOT_E * H) return;
    int p = t / H, h = t - p * H;
    int s = col[p], d = cdst[p];
    float v = ssrc[(size_t)s * H + h] + sdst[(size_t)d * H + h];
    v = (v > 0.f) ? v : 0.2f * v;
    w[t] = __expf(v);
}

// ---------------- fused softmax-denominator + aggregation (bf16 gather) ----------------
template<int H, int C>
__global__ void k_agg(const u16* __restrict__ Hm, const float* __restrict__ w,
                      const int* __restrict__ rowptr, const int* __restrict__ col,
                      const float* __restrict__ bias, float* __restrict__ out) {
    constexpr int HC = H * C;
    constexpr int K = HC / 64;
    int wid = (int)((blockIdx.x * blockDim.x + threadIdx.x) >> 6);
    int lane = threadIdx.x & 63;
    if (wid >= N_NODES) return;
    float acc[K];
    int hidx[K];
#pragma unroll
    for (int k = 0; k < K; k++) { acc[k] = 0.f; hidx[k] = (lane + 64 * k) / C; }
    float z = 0.f;
    int beg = rowptr[wid], end = rowptr[wid + 1];
    for (int base = beg; base < end; base += 64) {
        int nmax = min(64, end - base);
        int myc = (base + lane < end) ? col[base + lane] : 0;
        int j = 0;
        for (; j + 4 <= nmax; j += 4) {
            int s0 = __shfl(myc, j), s1 = __shfl(myc, j + 1);
            int s2 = __shfl(myc, j + 2), s3 = __shfl(myc, j + 3);
            float w0 = 0.f, w1 = 0.f, w2 = 0.f, w3 = 0.f;
            if (lane < H) {
                w0 = w[(size_t)(base + j) * H + lane];
                w1 = w[(size_t)(base + j + 1) * H + lane];
                w2 = w[(size_t)(base + j + 2) * H + lane];
                w3 = w[(size_t)(base + j + 3) * H + lane];
                z += (w0 + w1) + (w2 + w3);
            }
            const u16* r0 = Hm + (size_t)s0 * HC;
            const u16* r1 = Hm + (size_t)s1 * HC;
            const u16* r2 = Hm + (size_t)s2 * HC;
            const u16* r3 = Hm + (size_t)s3 * HC;
#pragma unroll
            for (int k = 0; k < K; k++) {
                int el = lane + 64 * k;
                float a0 = b2f(r0[el]), a1 = b2f(r1[el]);
                float a2 = b2f(r2[el]), a3 = b2f(r3[el]);
                acc[k] = fmaf(__shfl(w0, hidx[k]), a0, acc[k]);
                acc[k] = fmaf(__shfl(w1, hidx[k]), a1, acc[k]);
                acc[k] = fmaf(__shfl(w2, hidx[k]), a2, acc[k]);
                acc[k] = fmaf(__shfl(w3, hidx[k]), a3, acc[k]);
            }
        }
        for (; j < nmax; j++) {
            int s0 = __shfl(myc, j);
            float w0 = 0.f;
            if (lane < H) { w0 = w[(size_t)(base + j) * H + lane]; z += w0; }
            const u16* r0 = Hm + (size_t)s0 * HC;
#pragma unroll
            for (int k = 0; k < K; k++)
                acc[k] = fmaf(__shfl(w0, hidx[k]), b2f(r0[lane + 64 * k]), acc[k]);
        }
    }
#pragma unroll
    for (int k = 0; k < K; k++) {
        float zk = __shfl(z, hidx[k]);
        int el = lane + 64 * k;
        out[(size_t)wid * HC + el] = acc[k] / (zk + 1e-16f) + bias[el];
    }
}

// ---------------- small linear: Y[N,NO] = relu(bn(X))[N,K] @ W[K,NO] + b ----------------
template<int K, int NO, int TPR>
__global__ void k_lin(const float* __restrict__ X, const float* __restrict__ W,
                      const float* __restrict__ wb, const float* __restrict__ scale,
                      const float* __restrict__ shift, float* __restrict__ Y) {
    constexpr int KS = K / TPR;  // k per wave-slice
    __shared__ float red[TPR][64][NO];
    int lane = threadIdx.x & 63;
    int wv = __builtin_amdgcn_readfirstlane(threadIdx.x >> 6);  // wave-uniform slice id
    int row = blockIdx.x * 64 + lane;
    int k0 = wv * KS;
    float acc[NO];
#pragma unroll
    for (int c = 0; c < NO; c++) acc[c] = 0.f;
    if (row < N_NODES) {
        const float* xr = X + (size_t)row * K + k0;
        for (int kk = 0; kk < KS; kk += 4) {
            float4 xv = *(const float4*)&xr[kk];
            int k = k0 + kk;
            float x0 = fmaxf(xv.x * scale[k] + shift[k], 0.f);
            float x1 = fmaxf(xv.y * scale[k + 1] + shift[k + 1], 0.f);
            float x2 = fmaxf(xv.z * scale[k + 2] + shift[k + 2], 0.f);
            float x3 = fmaxf(xv.w * scale[k + 3] + shift[k + 3], 0.f);
#pragma unroll
            for (int c = 0; c < NO; c++) {
                acc[c] = fmaf(x0, W[(size_t)k * NO + c],
                         fmaf(x1, W[(size_t)(k + 1) * NO + c],
                         fmaf(x2, W[(size_t)(k + 2) * NO + c],
                         fmaf(x3, W[(size_t)(k + 3) * NO + c], acc[c]))));
            }
        }
    }
#pragma unroll
    for (int c = 0; c < NO; c++) red[wv][lane][c] = acc[c];
    __syncthreads();
    for (int i = threadIdx.x; i < 64 * NO; i += 64 * TPR) {
        int r = i / NO, c = i - r * NO;
        float s = wb[c];
#pragma unroll
        for (int t = 0; t < TPR; t++) s += red[t][r][c];
        int grow = blockIdx.x * 64 + r;
        if (grow < N_NODES) Y[(size_t)grow * NO + c] = s;
    }
}

// ---------------- batchnorm stats: atomic-free per-block partials ----------------
template<int NO>
__global__ void k_bnstats(const float* __restrict__ X, float* __restrict__ psum,
                          float* __restrict__ psumsq) {
    constexpr int BS = (NO >= 256) ? NO : 256;
    constexpr int RPS = BS / NO;
    __shared__ float ls[BS], ls2[BS];
    int c = threadIdx.x % NO;
    int rsub = threadIdx.x / NO;
    constexpr int chunk = (N_NODES + PB - 1) / PB;
    int r0 = blockIdx.x * chunk;
    int r1 = min(N_NODES, r0 + chunk);
    float s = 0.f, s2 = 0.f;
    for (int r = r0 + rsub; r < r1; r += RPS) {
        float v = X[(size_t)r * NO + c];
        s += v;
        s2 += v * v;
    }
    if (RPS > 1) {
        ls[threadIdx.x] = s;
        ls2[threadIdx.x] = s2;
        __syncthreads();
        for (int off = BS / 2; off >= NO; off >>= 1) {
            if (threadIdx.x < off) {
                ls[threadIdx.x] += ls[threadIdx.x + off];
                ls2[threadIdx.x] += ls2[threadIdx.x + off];
            }
            __syncthreads();
        }
        s = ls[threadIdx.x];
        s2 = ls2[threadIdx.x];
    }
    if (rsub == 0) {
        psum[(size_t)blockIdx.x * NO + c] = s;
        psumsq[(size_t)blockIdx.x * NO + c] = s2;
    }
}

__global__ void k_bnfinal(const float* __restrict__ psum, const float* __restrict__ psumsq,
                          const float* __restrict__ g, const float* __restrict__ be,
                          float* __restrict__ scale, float* __restrict__ shift, int NO) {
    int t = threadIdx.x;
    if (t >= NO) return;
    float s = 0.f, s2 = 0.f;
    for (int b = 0; b < PB; b++) {
        s += psum[(size_t)b * NO + t];
        s2 += psumsq[(size_t)b * NO + t];
    }
    float mu = s / (float)N_NODES;
    float var = s2 / (float)N_NODES - mu * mu;
    float sc = g[t] * rsqrtf(var + 1e-5f);
    scale[t] = sc;
    shift[t] = be[t] - mu * sc;
}

// ---------------- pooling ----------------
__global__ void k_bhist(const int* __restrict__ batch, int* __restrict__ cnt) {
    __shared__ int h[G_GRAPHS];
    int tid = threadIdx.x;
    if (tid < G_GRAPHS) h[tid] = 0;
    __syncthreads();
    int i = blockIdx.x * blockDim.x + tid;
    if (i < N_NODES) atomicAdd(&h[batch[i]], 1);
    __syncthreads();
    if (tid < G_GRAPHS) atomicAdd(&cnt[tid], h[tid]);
}

__global__ void k_pool(const float* __restrict__ X, const int* __restrict__ batch,
                       const float* __restrict__ sc, const float* __restrict__ sh,
                       float* __restrict__ pooled) {
    int t = threadIdx.x;  // 384
    const int chunk = (N_NODES + 511) / 512;
    int r0 = blockIdx.x * chunk;
    int r1 = min(N_NODES, r0 + chunk);
    if (r0 >= N_NODES) return;
    float acc = 0.f;
    int cur = batch[r0];
    for (int r = r0; r < r1; r++) {
        int gid = batch[r];
        if (gid != cur) {
            atomicAdd(&pooled[(size_t)cur * 384 + t], acc);
            acc = 0.f;
            cur = gid;
        }
        float v = X[(size_t)r * 384 + t] * sc[t] + sh[t];
        acc += fmaxf(v, 0.f);
    }
    atomicAdd(&pooled[(size_t)cur * 384 + t], acc);
}

__global__ void k_final(const float* __restrict__ pooled, const int* __restrict__ cnt,
                        const float* __restrict__ lwf, const float* __restrict__ lbf,
                        float* __restrict__ out) {
    int t = threadIdx.x;  // 640
    if (t >= G_GRAPHS * 10) return;
    int g = t / 10, c = t - g * 10;
    float inv = 1.0f / fmaxf((float)cnt[g], 1.0f);
    float acc = lbf[c];
    for (int k = 0; k < 384; k++)
        acc = fmaf(pooled[(size_t)g * 384 + k] * inv, lwf[k * 10 + c], acc);
    out[t] = acc;
}

extern "C" void kernel_launch(void* const* d_in, const int* in_sizes, int n_in,
                              void* d_out, int out_size, void* d_ws, size_t ws_size,
                              hipStream_t stream) {
    const float* x    = (const float*)d_in[0];
    const int*   ei   = (const int*)d_in[1];
    const int*   batch= (const int*)d_in[2];
    const float* W1   = (const float*)d_in[3];
    const float* as1  = (const float*)d_in[4];
    const float* ad1  = (const float*)d_in[5];
    const float* b1   = (const float*)d_in[6];
    const float* g1   = (const float*)d_in[7];
    const float* be1  = (const float*)d_in[8];
    const float* lw1  = (const float*)d_in[9];
    const float* lb1  = (const float*)d_in[10];
    const float* gl1  = (const float*)d_in[11];
    const float* bel1 = (const float*)d_in[12];
    const float* W2   = (const float*)d_in[13];
    const float* as2  = (const float*)d_in[14];
    const float* ad2  = (const float*)d_in[15];
    const float* b2   = (const float*)d_in[16];
    const float* g2   = (const float*)d_in[17];
    const float* be2  = (const float*)d_in[18];
    const float* lw2  = (const float*)d_in[19];
    const float* lb2  = (const float*)d_in[20];
    const float* gl2  = (const float*)d_in[21];
    const float* bel2 = (const float*)d_in[22];
    const float* W3   = (const float*)d_in[23];
    const float* as3  = (const float*)d_in[24];
    const float* ad3  = (const float*)d_in[25];
    const float* b3   = (const float*)d_in[26];
    const float* g3   = (const float*)d_in[27];
    const float* be3  = (const float*)d_in[28];
    const float* lwf  = (const float*)d_in[29];
    const float* lbf  = (const float*)d_in[30];
    float* out = (float*)d_out;

    // ---- workspace carve ----
    char* p = (char*)d_ws;
    auto alloc = [&](size_t bytes) {
        char* r = p;
        p += (bytes + 255) & ~(size_t)255;
        return r;
    };
    int*   rowptr = (int*)alloc(4 * (size_t)(N_NODES + 1));
    int*   cursor = (int*)alloc(4 * (size_t)N_NODES);
    int*   deg    = (int*)alloc(4 * (size_t)N_NODES);
    int*   col    = (int*)alloc(4 * (size_t)TOT_E);
    int*   cdst   = (int*)alloc(4 * (size_t)TOT_E);
    float* ssrc   = (float*)alloc(4 * (size_t)N_NODES * 20);
    float* sdst   = (float*)alloc(4 * (size_t)N_NODES * 20);
    float* ew     = (float*)alloc(4 * (size_t)TOT_E * 20);
    u16*   hbuf   = (u16*)alloc(2 * (size_t)N_NODES * 512);
    float* obuf   = (float*)alloc(4 * (size_t)N_NODES * 512);
    float* xbuf   = (float*)alloc(4 * (size_t)N_NODES * 32);
    float* psum   = (float*)alloc(4 * (size_t)PB * 512);
    float* psumsq = (float*)alloc(4 * (size_t)PB * 512);
    float* scA    = (float*)alloc(4 * 512);
    float* shA    = (float*)alloc(4 * 512);
    float* scB    = (float*)alloc(4 * 64);
    float* shB    = (float*)alloc(4 * 64);
    float* pooled = (float*)alloc(4 * (size_t)G_GRAPHS * 384);
    int*   cnt    = (int*)alloc(4 * G_GRAPHS);

    const int LB = (N_NODES + 63) / 64;   // 782 row-tiles for k_lin
    const int GB = (N_NODES + 31) / 32;   // 1563 row-tiles for k_gemm

    // ---- graph build (reused by all 3 layers) ----
    k_init_deg<<<(N_NODES + 255) / 256, 256, 0, stream>>>(deg);
    k_hist<<<(N_EDGES + 255) / 256, 256, 0, stream>>>(ei, deg);
    k_scan<<<1, 1024, 0, stream>>>(deg, rowptr, cursor);
    k_scatter<<<(TOT_E + 255) / 256, 256, 0, stream>>>(ei, cursor, col, cdst);
    hipMemsetAsync(pooled, 0, 4 * (size_t)G_GRAPHS * 384 + 256, stream);  // pooled + cnt

    // ---- layer 1: GAT(128 -> 20x16) ----
    k_gemm<128, 320, false><<<GB, 256, 0, stream>>>(x, W1, nullptr, nullptr, hbuf);
    k_scores<20, 16><<<(N_NODES * 20 + 255) / 256, 256, 0, stream>>>(hbuf, as1, ad1, ssrc, sdst);
    k_ew<20><<<(TOT_E * 20 + 255) / 256, 256, 0, stream>>>(ssrc, sdst, col, cdst, ew);
    k_agg<20, 16><<<(N_NODES + 3) / 4, 256, 0, stream>>>(hbuf, ew, rowptr, col, b1, obuf);
    k_bnstats<320><<<PB, 320, 0, stream>>>(obuf, psum, psumsq);
    k_bnfinal<<<1, 512, 0, stream>>>(psum, psumsq, g1, be1, scA, shA, 320);
    k_lin<320, 16, 4><<<LB, 256, 0, stream>>>(obuf, lw1, lb1, scA, shA, xbuf);
    k_bnstats<16><<<PB, 256, 0, stream>>>(xbuf, psum, psumsq);
    k_bnfinal<<<1, 512, 0, stream>>>(psum, psumsq, gl1, bel1, scB, shB, 16);

    // ---- layer 2: GAT(16 -> 16x32) ----
    k_gemm<16, 512, true><<<GB, 256, 0, stream>>>(xbuf, W2, scB, shB, hbuf);
    k_scores<16, 32><<<(N_NODES * 16 + 255) / 256, 256, 0, stream>>>(hbuf, as2, ad2, ssrc, sdst);
    k_ew<16><<<(TOT_E * 16 + 255) / 256, 256, 0, stream>>>(ssrc, sdst, col, cdst, ew);
    k_agg<16, 32><<<(N_NODES + 3) / 4, 256, 0, stream>>>(hbuf, ew, rowptr, col, b2, obuf);
    k_bnstats<512><<<PB, 512, 0, stream>>>(obuf, psum, psumsq);
    k_bnfinal<<<1, 512, 0, stream>>>(psum, psumsq, g2, be2, scA, shA, 512);
    k_lin<512, 32, 4><<<LB, 256, 0, stream>>>(obuf, lw2, lb2, scA, shA, xbuf);
    k_bnstats<32><<<PB, 256, 0, stream>>>(xbuf, psum, psumsq);
    k_bnfinal<<<1, 512, 0, stream>>>(psum, psumsq, gl2, bel2, scB, shB, 32);

    // ---- layer 3: GAT(32 -> 8x48) ----
    k_gemm<32, 384, true><<<GB, 256, 0, stream>>>(xbuf, W3, scB, shB, hbuf);
    k_scores<8, 48><<<(N_NODES * 8 + 255) / 256, 256, 0, stream>>>(hbuf, as3, ad3, ssrc, sdst);
    k_ew<8><<<(TOT_E * 8 + 255) / 256, 256, 0, stream>>>(ssrc, sdst, col, cdst, ew);
    k_agg<8, 48><<<(N_NODES + 3) / 4, 256, 0, stream>>>(hbuf, ew, rowptr, col, b3, obuf);
    k_bnstats<384><<<PB, 384, 0, stream>>>(obuf, psum, psumsq);
    k_bnfinal<<<1, 512, 0, stream>>>(psum, psumsq, g3, be3, scA, shA, 384);

    // ---- pool + classifier ----
    k_bhist<<<(N_NODES + 255) / 256, 256, 0, stream>>>(batch, cnt);
    k_pool<<<512, 384, 0, stream>>>(obuf, batch, scA, shA, pooled);
    k_final<<<1, 640, 0, stream>>>(pooled, cnt, lwf, lbf, out);
}

// Round 10
// 1073.915 us; speedup vs baseline: 1.4270x; 1.0753x over previous
//
#include <hip/hip_runtime.h>
#include <cstdint>
#include <cstddef>

#define N_NODES 50000
#define N_EDGES 400000
#define TOT_E   450000
#define G_GRAPHS 64
#define PB 256   // partial blocks for bnstats
#define SCAN_B 98  // scan blocks of 512 (98*512 = 50176 >= N_NODES)

typedef unsigned short u16;
typedef unsigned int u32;

__device__ __forceinline__ float b2f(u16 v) {
    union { u32 u; float f; } x; x.u = ((u32)v) << 16; return x.f;
}
__device__ __forceinline__ float lo2f(u32 u) {
    union { u32 u; float f; } x; x.u = u << 16; return x.f;
}
__device__ __forceinline__ float hi2f(u32 u) {
    union { u32 u; float f; } x; x.u = u & 0xffff0000u; return x.f;
}
__device__ __forceinline__ u16 f2b(float f) {
    union { float f; u32 u; } x; x.f = f;
    u32 r = x.u + 0x7fffu + ((x.u >> 16) & 1u);  // round-nearest-even
    return (u16)(r >> 16);
}

// ---------------- graph build ----------------
__global__ void k_init_deg(int* __restrict__ deg) {
    int i = blockIdx.x * blockDim.x + threadIdx.x;
    if (i < N_NODES) deg[i] = 1;  // self loop
}

__global__ void k_hist(const int* __restrict__ ei, int* __restrict__ deg) {
    int e = blockIdx.x * blockDim.x + threadIdx.x;
    if (e < N_EDGES) atomicAdd(&deg[ei[N_EDGES + e]], 1);
}

// phase 1: block-local exclusive scan, block totals to bsum
__global__ void k_scan1(const int* __restrict__ deg, int* __restrict__ rowptr,
                        int* __restrict__ bsum) {
    __shared__ int buf[512];
    int tid = threadIdx.x;
    int i = blockIdx.x * 512 + tid;
    int v = (i < N_NODES) ? deg[i] : 0;
    buf[tid] = v;
    __syncthreads();
    for (int off = 1; off < 512; off <<= 1) {
        int t = (tid >= off) ? buf[tid - off] : 0;
        __syncthreads();
        buf[tid] += t;
        __syncthreads();
    }
    if (i < N_NODES) rowptr[i] = buf[tid] - v;  // block-local exclusive
    if (tid == 511) bsum[blockIdx.x] = buf[511];
}

// phase 2: exclusive scan of the 98 block sums (single 128-thread block)
__global__ void k_scan2(int* __restrict__ bsum) {
    __shared__ int buf[128];
    int tid = threadIdx.x;
    int v = (tid < SCAN_B) ? bsum[tid] : 0;
    buf[tid] = v;
    __syncthreads();
    for (int off = 1; off < 128; off <<= 1) {
        int t = (tid >= off) ? buf[tid - off] : 0;
        __syncthreads();
        buf[tid] += t;
        __syncthreads();
    }
    if (tid < SCAN_B) bsum[tid] = buf[tid] - v;  // exclusive
}

// phase 3: add block offsets; write cursor; rowptr[N] = TOT_E (statically known)
__global__ void k_scan3(int* __restrict__ rowptr, int* __restrict__ cursor,
                        const int* __restrict__ bsum) {
    int i = blockIdx.x * blockDim.x + threadIdx.x;
    if (i < N_NODES) {
        int v = rowptr[i] + bsum[i >> 9];
        rowptr[i] = v;
        cursor[i] = v;
    }
    if (i == 0) rowptr[N_NODES] = TOT_E;
}

__global__ void k_scatter(const int* __restrict__ ei, int* __restrict__ cursor,
                          int* __restrict__ col, int* __restrict__ cdst) {
    int e = blockIdx.x * blockDim.x + threadIdx.x;
    if (e < N_EDGES) {
        int s = ei[e], d = ei[N_EDGES + e];
        int p = atomicAdd(&cursor[d], 1);
        col[p] = s;
        cdst[p] = d;
    } else if (e < TOT_E) {
        int i = e - N_EDGES;
        int p = atomicAdd(&cursor[i], 1);
        col[p] = i;
        cdst[p] = i;
    }
}

// ---------------- register-tiled GEMM: Y[N,NO] = xform(X)[N,K] @ W[K,NO], bf16 out ----
// __launch_bounds__(256,2): 2 waves/EU -> 256 VGPRs, keeps acc/xv/w in registers
// (round-8 regression: default occupancy target spilled the acc tile).
template<int K, int NO, bool XFORM>
__global__ __launch_bounds__(256, 2)
void k_gemm(const float* __restrict__ X, const float* __restrict__ W,
            const float* __restrict__ scale, const float* __restrict__ shift,
            u16* __restrict__ Y) {
    constexpr int TM = 32;
    constexpr int CPT = NO / 64;
    __shared__ float xs[TM][K + 4];
    int tid = threadIdx.x;
    int r0 = blockIdx.x * TM;
    constexpr int NV = TM * K / 4;
    for (int i = tid; i < NV; i += 256) {
        int rr = (i * 4) / K, kk = (i * 4) % K;
        float4 v = make_float4(0.f, 0.f, 0.f, 0.f);
        if (r0 + rr < N_NODES) {
            v = *(const float4*)&X[(size_t)(r0 + rr) * K + kk];
            if (XFORM) {
                v.x = fmaxf(v.x * scale[kk] + shift[kk], 0.f);
                v.y = fmaxf(v.y * scale[kk + 1] + shift[kk + 1], 0.f);
                v.z = fmaxf(v.z * scale[kk + 2] + shift[kk + 2], 0.f);
                v.w = fmaxf(v.w * scale[kk + 3] + shift[kk + 3], 0.f);
            }
        }
        *(float4*)&xs[rr][kk] = v;
    }
    __syncthreads();
    int c = tid & 63;
    int rbase = (tid >> 6) * 8;
    float acc[8][CPT];
#pragma unroll
    for (int r = 0; r < 8; r++)
#pragma unroll
        for (int j = 0; j < CPT; j++) acc[r][j] = 0.f;

    for (int kq = 0; kq < K; kq += 4) {
        float4 xv[8];
#pragma unroll
        for (int r = 0; r < 8; r++) xv[r] = *(const float4*)&xs[rbase + r][kq];
#pragma unroll
        for (int kk = 0; kk < 4; kk++) {
            float w[CPT];
#pragma unroll
            for (int j = 0; j < CPT; j++) w[j] = W[(size_t)(kq + kk) * NO + c + 64 * j];
#pragma unroll
            for (int r = 0; r < 8; r++) {
                float xk = (kk == 0) ? xv[r].x : (kk == 1) ? xv[r].y : (kk == 2) ? xv[r].z : xv[r].w;
#pragma unroll
                for (int j = 0; j < CPT; j++) acc[r][j] = fmaf(xk, w[j], acc[r][j]);
            }
        }
    }
#pragma unroll
    for (int r = 0; r < 8; r++) {
        int grow = r0 + rbase + r;
        if (grow < N_NODES) {
#pragma unroll
            for (int j = 0; j < CPT; j++)
                Y[(size_t)grow * NO + c + 64 * j] = f2b(acc[r][j]);
        }
    }
}

// ---------------- attention scores (bf16 input, uint-packed reads) ----------------
template<int H, int C>
__global__ void k_scores(const u16* __restrict__ Hm, const float* __restrict__ asrc,
                         const float* __restrict__ adst, float* __restrict__ ssrc,
                         float* __restrict__ sdst) {
    int t = blockIdx.x * blockDim.x + threadIdx.x;
    if (t >= N_NODES * H) return;
    int i = t / H, h = t - i * H;
    const u32* row = (const u32*)(Hm + (size_t)i * H * C + h * C);
    float s1 = 0.f, s2 = 0.f;
#pragma unroll
    for (int c2 = 0; c2 < C / 2; c2++) {
        u32 u = row[c2];
        float v0 = lo2f(u), v1 = hi2f(u);
        int c = c2 * 2;
        s1 = fmaf(v0, asrc[h * C + c], fmaf(v1, asrc[h * C + c + 1], s1));
        s2 = fmaf(v0, adst[h * C + c], fmaf(v1, adst[h * C + c + 1], s2));
    }
    ssrc[t] = s1;
    sdst[t] = s2;
}

// ---------------- edge weights: w[p,h] = exp(leaky(ssrc[src]+sdst[dst])) ----------------
template<int H>
__global__ void k_ew(const float* __restrict__ ssrc, const float* __restrict__ sdst,
                     const int* __restrict__ col, const int* __restrict__ cdst,
                     float* __restrict__ w) {
    int t = blockIdx.x * blockDim.x + threadIdx.x;
    if (t >= TOT_E * H) return;
    int p = t / H, h = t - p * H;
    int s = col[p], d = cdst[p];
    float v = ssrc[(size_t)s * H + h] + sdst[(size_t)d * H + h];
    v = (v > 0.f) ? v : 0.2f * v;
    w[t] = __expf(v);
}

// ---------------- fused softmax-denominator + aggregation (bf16 gather) ----------------
template<int H, int C>
__global__ void k_agg(const u16* __restrict__ Hm, const float* __restrict__ w,
                      const int* __restrict__ rowptr, const int* __restrict__ col,
                      const float* __restrict__ bias, float* __restrict__ out) {
    constexpr int HC = H * C;
    constexpr int K = HC / 64;
    int wid = (int)((blockIdx.x * blockDim.x + threadIdx.x) >> 6);
    int lane = threadIdx.x & 63;
    if (wid >= N_NODES) return;
    float acc[K];
    int hidx[K];
#pragma unroll
    for (int k = 0; k < K; k++) { acc[k] = 0.f; hidx[k] = (lane + 64 * k) / C; }
    float z = 0.f;
    int beg = rowptr[wid], end = rowptr[wid + 1];
    for (int base = beg; base < end; base += 64) {
        int nmax = min(64, end - base);
        int myc = (base + lane < end) ? col[base + lane] : 0;
        int j = 0;
        for (; j + 4 <= nmax; j += 4) {
            int s0 = __shfl(myc, j), s1 = __shfl(myc, j + 1);
            int s2 = __shfl(myc, j + 2), s3 = __shfl(myc, j + 3);
            float w0 = 0.f, w1 = 0.f, w2 = 0.f, w3 = 0.f;
            if (lane < H) {
                w0 = w[(size_t)(base + j) * H + lane];
                w1 = w[(size_t)(base + j + 1) * H + lane];
                w2 = w[(size_t)(base + j + 2) * H + lane];
                w3 = w[(size_t)(base + j + 3) * H + lane];
                z += (w0 + w1) + (w2 + w3);
            }
            const u16* r0 = Hm + (size_t)s0 * HC;
            const u16* r1 = Hm + (size_t)s1 * HC;
            const u16* r2 = Hm + (size_t)s2 * HC;
            const u16* r3 = Hm + (size_t)s3 * HC;
#pragma unroll
            for (int k = 0; k < K; k++) {
                int el = lane + 64 * k;
                float a0 = b2f(r0[el]), a1 = b2f(r1[el]);
                float a2 = b2f(r2[el]), a3 = b2f(r3[el]);
                acc[k] = fmaf(__shfl(w0, hidx[k]), a0, acc[k]);
                acc[k] = fmaf(__shfl(w1, hidx[k]), a1, acc[k]);
                acc[k] = fmaf(__shfl(w2, hidx[k]), a2, acc[k]);
                acc[k] = fmaf(__shfl(w3, hidx[k]), a3, acc[k]);
            }
        }
        for (; j < nmax; j++) {
            int s0 = __shfl(myc, j);
            float w0 = 0.f;
            if (lane < H) { w0 = w[(size_t)(base + j) * H + lane]; z += w0; }
            const u16* r0 = Hm + (size_t)s0 * HC;
#pragma unroll
            for (int k = 0; k < K; k++)
                acc[k] = fmaf(__shfl(w0, hidx[k]), b2f(r0[lane + 64 * k]), acc[k]);
        }
    }
#pragma unroll
    for (int k = 0; k < K; k++) {
        float zk = __shfl(z, hidx[k]);
        int el = lane + 64 * k;
        out[(size_t)wid * HC + el] = acc[k] / (zk + 1e-16f) + bias[el];
    }
}

// ---------------- small linear: Y[N,NO] = relu(bn(X))[N,K] @ W[K,NO] + b ----------------
template<int K, int NO, int TPR>
__global__ void k_lin(const float* __restrict__ X, const float* __restrict__ W,
                      const float* __restrict__ wb, const float* __restrict__ scale,
                      const float* __restrict__ shift, float* __restrict__ Y) {
    constexpr int KS = K / TPR;  // k per wave-slice
    __shared__ float red[TPR][64][NO];
    int lane = threadIdx.x & 63;
    int wv = __builtin_amdgcn_readfirstlane(threadIdx.x >> 6);  // wave-uniform slice id
    int row = blockIdx.x * 64 + lane;
    int k0 = wv * KS;
    float acc[NO];
#pragma unroll
    for (int c = 0; c < NO; c++) acc[c] = 0.f;
    if (row < N_NODES) {
        const float* xr = X + (size_t)row * K + k0;
        for (int kk = 0; kk < KS; kk += 4) {
            float4 xv = *(const float4*)&xr[kk];
            int k = k0 + kk;
            float x0 = fmaxf(xv.x * scale[k] + shift[k], 0.f);
            float x1 = fmaxf(xv.y * scale[k + 1] + shift[k + 1], 0.f);
            float x2 = fmaxf(xv.z * scale[k + 2] + shift[k + 2], 0.f);
            float x3 = fmaxf(xv.w * scale[k + 3] + shift[k + 3], 0.f);
#pragma unroll
            for (int c = 0; c < NO; c++) {
                acc[c] = fmaf(x0, W[(size_t)k * NO + c],
                         fmaf(x1, W[(size_t)(k + 1) * NO + c],
                         fmaf(x2, W[(size_t)(k + 2) * NO + c],
                         fmaf(x3, W[(size_t)(k + 3) * NO + c], acc[c]))));
            }
        }
    }
#pragma unroll
    for (int c = 0; c < NO; c++) red[wv][lane][c] = acc[c];
    __syncthreads();
    for (int i = threadIdx.x; i < 64 * NO; i += 64 * TPR) {
        int r = i / NO, c = i - r * NO;
        float s = wb[c];
#pragma unroll
        for (int t = 0; t < TPR; t++) s += red[t][r][c];
        int grow = blockIdx.x * 64 + r;
        if (grow < N_NODES) Y[(size_t)grow * NO + c] = s;
    }
}

// ---------------- batchnorm stats: atomic-free per-block partials ----------------
template<int NO>
__global__ void k_bnstats(const float* __restrict__ X, float* __restrict__ psum,
                          float* __restrict__ psumsq) {
    constexpr int BS = (NO >= 256) ? NO : 256;
    constexpr int RPS = BS / NO;
    __shared__ float ls[BS], ls2[BS];
    int c = threadIdx.x % NO;
    int rsub = threadIdx.x / NO;
    constexpr int chunk = (N_NODES + PB - 1) / PB;
    int r0 = blockIdx.x * chunk;
    int r1 = min(N_NODES, r0 + chunk);
    float s = 0.f, s2 = 0.f;
    for (int r = r0 + rsub; r < r1; r += RPS) {
        float v = X[(size_t)r * NO + c];
        s += v;
        s2 += v * v;
    }
    if (RPS > 1) {
        ls[threadIdx.x] = s;
        ls2[threadIdx.x] = s2;
        __syncthreads();
        for (int off = BS / 2; off >= NO; off >>= 1) {
            if (threadIdx.x < off) {
                ls[threadIdx.x] += ls[threadIdx.x + off];
                ls2[threadIdx.x] += ls2[threadIdx.x + off];
            }
            __syncthreads();
        }
        s = ls[threadIdx.x];
        s2 = ls2[threadIdx.x];
    }
    if (rsub == 0) {
        psum[(size_t)blockIdx.x * NO + c] = s;
        psumsq[(size_t)blockIdx.x * NO + c] = s2;
    }
}

__global__ void k_bnfinal(const float* __restrict__ psum, const float* __restrict__ psumsq,
                          const float* __restrict__ g, const float* __restrict__ be,
                          float* __restrict__ scale, float* __restrict__ shift, int NO) {
    int t = threadIdx.x;
    if (t >= NO) return;
    float s = 0.f, s2 = 0.f;
    for (int b = 0; b < PB; b++) {
        s += psum[(size_t)b * NO + t];
        s2 += psumsq[(size_t)b * NO + t];
    }
    float mu = s / (float)N_NODES;
    float var = s2 / (float)N_NODES - mu * mu;
    float sc = g[t] * rsqrtf(var + 1e-5f);
    scale[t] = sc;
    shift[t] = be[t] - mu * sc;
}

// ---------------- pooling ----------------
__global__ void k_bhist(const int* __restrict__ batch, int* __restrict__ cnt) {
    __shared__ int h[G_GRAPHS];
    int tid = threadIdx.x;
    if (tid < G_GRAPHS) h[tid] = 0;
    __syncthreads();
    int i = blockIdx.x * blockDim.x + tid;
    if (i < N_NODES) atomicAdd(&h[batch[i]], 1);
    __syncthreads();
    if (tid < G_GRAPHS) atomicAdd(&cnt[tid], h[tid]);
}

__global__ void k_pool(const float* __restrict__ X, const int* __restrict__ batch,
                       const float* __restrict__ sc, const float* __restrict__ sh,
                       float* __restrict__ pooled) {
    int t = threadIdx.x;  // 384
    const int chunk = (N_NODES + 511) / 512;
    int r0 = blockIdx.x * chunk;
    int r1 = min(N_NODES, r0 + chunk);
    if (r0 >= N_NODES) return;
    float acc = 0.f;
    int cur = batch[r0];
    for (int r = r0; r < r1; r++) {
        int gid = batch[r];
        if (gid != cur) {
            atomicAdd(&pooled[(size_t)cur * 384 + t], acc);
            acc = 0.f;
            cur = gid;
        }
        float v = X[(size_t)r * 384 + t] * sc[t] + sh[t];
        acc += fmaxf(v, 0.f);
    }
    atomicAdd(&pooled[(size_t)cur * 384 + t], acc);
}

__global__ void k_final(const float* __restrict__ pooled, const int* __restrict__ cnt,
                        const float* __restrict__ lwf, const float* __restrict__ lbf,
                        float* __restrict__ out) {
    int t = threadIdx.x;  // 640
    if (t >= G_GRAPHS * 10) return;
    int g = t / 10, c = t - g * 10;
    float inv = 1.0f / fmaxf((float)cnt[g], 1.0f);
    float acc = lbf[c];
    for (int k = 0; k < 384; k++)
        acc = fmaf(pooled[(size_t)g * 384 + k] * inv, lwf[k * 10 + c], acc);
    out[t] = acc;
}

extern "C" void kernel_launch(void* const* d_in, const int* in_sizes, int n_in,
                              void* d_out, int out_size, void* d_ws, size_t ws_size,
                              hipStream_t stream) {
    const float* x    = (const float*)d_in[0];
    const int*   ei   = (const int*)d_in[1];
    const int*   batch= (const int*)d_in[2];
    const float* W1   = (const float*)d_in[3];
    const float* as1  = (const float*)d_in[4];
    const float* ad1  = (const float*)d_in[5];
    const float* b1   = (const float*)d_in[6];
    const float* g1   = (const float*)d_in[7];
    const float* be1  = (const float*)d_in[8];
    const float* lw1  = (const float*)d_in[9];
    const float* lb1  = (const float*)d_in[10];
    const float* gl1  = (const float*)d_in[11];
    const float* bel1 = (const float*)d_in[12];
    const float* W2   = (const float*)d_in[13];
    const float* as2  = (const float*)d_in[14];
    const float* ad2  = (const float*)d_in[15];
    const float* b2   = (const float*)d_in[16];
    const float* g2   = (const float*)d_in[17];
    const float* be2  = (const float*)d_in[18];
    const float* lw2  = (const float*)d_in[19];
    const float* lb2  = (const float*)d_in[20];
    const float* gl2  = (const float*)d_in[21];
    const float* bel2 = (const float*)d_in[22];
    const float* W3   = (const float*)d_in[23];
    const float* as3  = (const float*)d_in[24];
    const float* ad3  = (const float*)d_in[25];
    const float* b3   = (const float*)d_in[26];
    const float* g3   = (const float*)d_in[27];
    const float* be3  = (const float*)d_in[28];
    const float* lwf  = (const float*)d_in[29];
    const float* lbf  = (const float*)d_in[30];
    float* out = (float*)d_out;

    // ---- workspace carve ----
    char* p = (char*)d_ws;
    auto alloc = [&](size_t bytes) {
        char* r = p;
        p += (bytes + 255) & ~(size_t)255;
        return r;
    };
    int*   rowptr = (int*)alloc(4 * (size_t)(N_NODES + 1));
    int*   cursor = (int*)alloc(4 * (size_t)N_NODES);
    int*   deg    = (int*)alloc(4 * (size_t)N_NODES);
    int*   bsum   = (int*)alloc(4 * (size_t)(SCAN_B + 1));
    int*   col    = (int*)alloc(4 * (size_t)TOT_E);
    int*   cdst   = (int*)alloc(4 * (size_t)TOT_E);
    float* ssrc   = (float*)alloc(4 * (size_t)N_NODES * 20);
    float* sdst   = (float*)alloc(4 * (size_t)N_NODES * 20);
    float* ew     = (float*)alloc(4 * (size_t)TOT_E * 20);
    u16*   hbuf   = (u16*)alloc(2 * (size_t)N_NODES * 512);
    float* obuf   = (float*)alloc(4 * (size_t)N_NODES * 512);
    float* xbuf   = (float*)alloc(4 * (size_t)N_NODES * 32);
    float* psum   = (float*)alloc(4 * (size_t)PB * 512);
    float* psumsq = (float*)alloc(4 * (size_t)PB * 512);
    float* scA    = (float*)alloc(4 * 512);
    float* shA    = (float*)alloc(4 * 512);
    float* scB    = (float*)alloc(4 * 64);
    float* shB    = (float*)alloc(4 * 64);
    float* pooled = (float*)alloc(4 * (size_t)G_GRAPHS * 384);
    int*   cnt    = (int*)alloc(4 * G_GRAPHS);

    const int LB = (N_NODES + 63) / 64;   // 782 row-tiles for k_lin
    const int GB = (N_NODES + 31) / 32;   // 1563 row-tiles for k_gemm

    // ---- graph build (reused by all 3 layers) ----
    k_init_deg<<<(N_NODES + 255) / 256, 256, 0, stream>>>(deg);
    k_hist<<<(N_EDGES + 255) / 256, 256, 0, stream>>>(ei, deg);
    k_scan1<<<SCAN_B, 512, 0, stream>>>(deg, rowptr, bsum);
    k_scan2<<<1, 128, 0, stream>>>(bsum);
    k_scan3<<<(N_NODES + 255) / 256, 256, 0, stream>>>(rowptr, cursor, bsum);
    k_scatter<<<(TOT_E + 255) / 256, 256, 0, stream>>>(ei, cursor, col, cdst);
    hipMemsetAsync(pooled, 0, 4 * (size_t)G_GRAPHS * 384 + 256, stream);  // pooled + cnt

    // ---- layer 1: GAT(128 -> 20x16) ----
    k_gemm<128, 320, false><<<GB, 256, 0, stream>>>(x, W1, nullptr, nullptr, hbuf);
    k_scores<20, 16><<<(N_NODES * 20 + 255) / 256, 256, 0, stream>>>(hbuf, as1, ad1, ssrc, sdst);
    k_ew<20><<<(TOT_E * 20 + 255) / 256, 256, 0, stream>>>(ssrc, sdst, col, cdst, ew);
    k_agg<20, 16><<<(N_NODES + 3) / 4, 256, 0, stream>>>(hbuf, ew, rowptr, col, b1, obuf);
    k_bnstats<320><<<PB, 320, 0, stream>>>(obuf, psum, psumsq);
    k_bnfinal<<<1, 512, 0, stream>>>(psum, psumsq, g1, be1, scA, shA, 320);
    k_lin<320, 16, 4><<<LB, 256, 0, stream>>>(obuf, lw1, lb1, scA, shA, xbuf);
    k_bnstats<16><<<PB, 256, 0, stream>>>(xbuf, psum, psumsq);
    k_bnfinal<<<1, 512, 0, stream>>>(psum, psumsq, gl1, bel1, scB, shB, 16);

    // ---- layer 2: GAT(16 -> 16x32) ----
    k_gemm<16, 512, true><<<GB, 256, 0, stream>>>(xbuf, W2, scB, shB, hbuf);
    k_scores<16, 32><<<(N_NODES * 16 + 255) / 256, 256, 0, stream>>>(hbuf, as2, ad2, ssrc, sdst);
    k_ew<16><<<(TOT_E * 16 + 255) / 256, 256, 0, stream>>>(ssrc, sdst, col, cdst, ew);
    k_agg<16, 32><<<(N_NODES + 3) / 4, 256, 0, stream>>>(hbuf, ew, rowptr, col, b2, obuf);
    k_bnstats<512><<<PB, 512, 0, stream>>>(obuf, psum, psumsq);
    k_bnfinal<<<1, 512, 0, stream>>>(psum, psumsq, g2, be2, scA, shA, 512);
    k_lin<512, 32, 4><<<LB, 256, 0, stream>>>(obuf, lw2, lb2, scA, shA, xbuf);
    k_bnstats<32><<<PB, 256, 0, stream>>>(xbuf, psum, psumsq);
    k_bnfinal<<<1, 512, 0, stream>>>(psum, psumsq, gl2, bel2, scB, shB, 32);

    // ---- layer 3: GAT(32 -> 8x48) ----
    k_gemm<32, 384, true><<<GB, 256, 0, stream>>>(xbuf, W3, scB, shB, hbuf);
    k_scores<8, 48><<<(N_NODES * 8 + 255) / 256, 256, 0, stream>>>(hbuf, as3, ad3, ssrc, sdst);
    k_ew<8><<<(TOT_E * 8 + 255) / 256, 256, 0, stream>>>(ssrc, sdst, col, cdst, ew);
    k_agg<8, 48><<<(N_NODES + 3) / 4, 256, 0, stream>>>(hbuf, ew, rowptr, col, b3, obuf);
    k_bnstats<384><<<PB, 384, 0, stream>>>(obuf, psum, psumsq);
    k_bnfinal<<<1, 512, 0, stream>>>(psum, psumsq, g3, be3, scA, shA, 384);

    // ---- pool + classifier ----
    k_bhist<<<(N_NODES + 255) / 256, 256, 0, stream>>>(batch, cnt);
    k_pool<<<512, 384, 0, stream>>>(obuf, batch, scA, shA, pooled);
    k_final<<<1, 640, 0, stream>>>(pooled, cnt, lwf, lbf, out);
}

// Round 11
// 1034.504 us; speedup vs baseline: 1.4814x; 1.0381x over previous
//
#include <hip/hip_runtime.h>
#include <cstdint>
#include <cstddef>

#define N_NODES 50000
#define N_EDGES 400000
#define TOT_E   450000
#define G_GRAPHS 64
#define PB 256   // partial blocks for bnstats
#define SCAN_B 98  // scan blocks of 512 (98*512 = 50176 >= N_NODES)

typedef unsigned short u16;
typedef unsigned int u32;

__device__ __forceinline__ float b2f(u16 v) {
    union { u32 u; float f; } x; x.u = ((u32)v) << 16; return x.f;
}
__device__ __forceinline__ float lo2f(u32 u) {
    union { u32 u; float f; } x; x.u = u << 16; return x.f;
}
__device__ __forceinline__ float hi2f(u32 u) {
    union { u32 u; float f; } x; x.u = u & 0xffff0000u; return x.f;
}
__device__ __forceinline__ u16 f2b(float f) {
    union { float f; u32 u; } x; x.f = f;
    u32 r = x.u + 0x7fffu + ((x.u >> 16) & 1u);  // round-nearest-even
    return (u16)(r >> 16);
}

// ---------------- graph build ----------------
__global__ void k_init_deg(int* __restrict__ deg) {
    int i = blockIdx.x * blockDim.x + threadIdx.x;
    if (i < N_NODES) deg[i] = 1;  // self loop
}

__global__ void k_hist(const int* __restrict__ ei, int* __restrict__ deg) {
    int e = blockIdx.x * blockDim.x + threadIdx.x;
    if (e < N_EDGES) atomicAdd(&deg[ei[N_EDGES + e]], 1);
}

// phase 1: block-local exclusive scan, block totals to bsum
__global__ void k_scan1(const int* __restrict__ deg, int* __restrict__ rowptr,
                        int* __restrict__ bsum) {
    __shared__ int buf[512];
    int tid = threadIdx.x;
    int i = blockIdx.x * 512 + tid;
    int v = (i < N_NODES) ? deg[i] : 0;
    buf[tid] = v;
    __syncthreads();
    for (int off = 1; off < 512; off <<= 1) {
        int t = (tid >= off) ? buf[tid - off] : 0;
        __syncthreads();
        buf[tid] += t;
        __syncthreads();
    }
    if (i < N_NODES) rowptr[i] = buf[tid] - v;  // block-local exclusive
    if (tid == 511) bsum[blockIdx.x] = buf[511];
}

// phase 2: exclusive scan of the 98 block sums (single 128-thread block)
__global__ void k_scan2(int* __restrict__ bsum) {
    __shared__ int buf[128];
    int tid = threadIdx.x;
    int v = (tid < SCAN_B) ? bsum[tid] : 0;
    buf[tid] = v;
    __syncthreads();
    for (int off = 1; off < 128; off <<= 1) {
        int t = (tid >= off) ? buf[tid - off] : 0;
        __syncthreads();
        buf[tid] += t;
        __syncthreads();
    }
    if (tid < SCAN_B) bsum[tid] = buf[tid] - v;  // exclusive
}

// phase 3: add block offsets; write cursor; rowptr[N] = TOT_E (statically known)
__global__ void k_scan3(int* __restrict__ rowptr, int* __restrict__ cursor,
                        const int* __restrict__ bsum) {
    int i = blockIdx.x * blockDim.x + threadIdx.x;
    if (i < N_NODES) {
        int v = rowptr[i] + bsum[i >> 9];
        rowptr[i] = v;
        cursor[i] = v;
    }
    if (i == 0) rowptr[N_NODES] = TOT_E;
}

__global__ void k_scatter(const int* __restrict__ ei, int* __restrict__ cursor,
                          int* __restrict__ col, int* __restrict__ cdst) {
    int e = blockIdx.x * blockDim.x + threadIdx.x;
    if (e < N_EDGES) {
        int s = ei[e], d = ei[N_EDGES + e];
        int p = atomicAdd(&cursor[d], 1);
        col[p] = s;
        cdst[p] = d;
    } else if (e < TOT_E) {
        int i = e - N_EDGES;
        int p = atomicAdd(&cursor[i], 1);
        col[p] = i;
        cdst[p] = i;
    }
}

// ---------------- register-tiled GEMM: Y[N,NO] = xform(X)[N,K] @ W[K,NO], bf16 out ----
// __launch_bounds__(256,2): 2 waves/EU -> 256 VGPRs, keeps acc/xv/w in registers
// (round-8 regression: default occupancy target spilled the acc tile).
template<int K, int NO, bool XFORM>
__global__ __launch_bounds__(256, 2)
void k_gemm(const float* __restrict__ X, const float* __restrict__ W,
            const float* __restrict__ scale, const float* __restrict__ shift,
            u16* __restrict__ Y) {
    constexpr int TM = 32;
    constexpr int CPT = NO / 64;
    __shared__ float xs[TM][K + 4];
    int tid = threadIdx.x;
    int r0 = blockIdx.x * TM;
    constexpr int NV = TM * K / 4;
    for (int i = tid; i < NV; i += 256) {
        int rr = (i * 4) / K, kk = (i * 4) % K;
        float4 v = make_float4(0.f, 0.f, 0.f, 0.f);
        if (r0 + rr < N_NODES) {
            v = *(const float4*)&X[(size_t)(r0 + rr) * K + kk];
            if (XFORM) {
                v.x = fmaxf(v.x * scale[kk] + shift[kk], 0.f);
                v.y = fmaxf(v.y * scale[kk + 1] + shift[kk + 1], 0.f);
                v.z = fmaxf(v.z * scale[kk + 2] + shift[kk + 2], 0.f);
                v.w = fmaxf(v.w * scale[kk + 3] + shift[kk + 3], 0.f);
            }
        }
        *(float4*)&xs[rr][kk] = v;
    }
    __syncthreads();
    int c = tid & 63;
    int rbase = (tid >> 6) * 8;
    float acc[8][CPT];
#pragma unroll
    for (int r = 0; r < 8; r++)
#pragma unroll
        for (int j = 0; j < CPT; j++) acc[r][j] = 0.f;

    for (int kq = 0; kq < K; kq += 4) {
        float4 xv[8];
#pragma unroll
        for (int r = 0; r < 8; r++) xv[r] = *(const float4*)&xs[rbase + r][kq];
#pragma unroll
        for (int kk = 0; kk < 4; kk++) {
            float w[CPT];
#pragma unroll
            for (int j = 0; j < CPT; j++) w[j] = W[(size_t)(kq + kk) * NO + c + 64 * j];
#pragma unroll
            for (int r = 0; r < 8; r++) {
                float xk = (kk == 0) ? xv[r].x : (kk == 1) ? xv[r].y : (kk == 2) ? xv[r].z : xv[r].w;
#pragma unroll
                for (int j = 0; j < CPT; j++) acc[r][j] = fmaf(xk, w[j], acc[r][j]);
            }
        }
    }
#pragma unroll
    for (int r = 0; r < 8; r++) {
        int grow = r0 + rbase + r;
        if (grow < N_NODES) {
#pragma unroll
            for (int j = 0; j < CPT; j++)
                Y[(size_t)grow * NO + c + 64 * j] = f2b(acc[r][j]);
        }
    }
}

// ---------------- attention scores (bf16 input, uint-packed reads) ----------------
template<int H, int C>
__global__ void k_scores(const u16* __restrict__ Hm, const float* __restrict__ asrc,
                         const float* __restrict__ adst, float* __restrict__ ssrc,
                         float* __restrict__ sdst) {
    int t = blockIdx.x * blockDim.x + threadIdx.x;
    if (t >= N_NODES * H) return;
    int i = t / H, h = t - i * H;
    const u32* row = (const u32*)(Hm + (size_t)i * H * C + h * C);
    float s1 = 0.f, s2 = 0.f;
#pragma unroll
    for (int c2 = 0; c2 < C / 2; c2++) {
        u32 u = row[c2];
        float v0 = lo2f(u), v1 = hi2f(u);
        int c = c2 * 2;
        s1 = fmaf(v0, asrc[h * C + c], fmaf(v1, asrc[h * C + c + 1], s1));
        s2 = fmaf(v0, adst[h * C + c], fmaf(v1, adst[h * C + c + 1], s2));
    }
    ssrc[t] = s1;
    sdst[t] = s2;
}

// ---------------- fused edge-softmax + aggregation (bf16 gather, in-place exp) --------
// Edge weights computed in-registers from ssrc gathers (k_ew kernel eliminated):
// w = exp(leaky(ssrc[s]+sdst[dst])). Same gather pattern as the old ew load.
template<int H, int C>
__global__ void k_agg(const u16* __restrict__ Hm, const float* __restrict__ ssrc,
                      const float* __restrict__ sdst, const int* __restrict__ rowptr,
                      const int* __restrict__ col, const float* __restrict__ bias,
                      float* __restrict__ out) {
    constexpr int HC = H * C;
    constexpr int K = HC / 64;
    int wid = (int)((blockIdx.x * blockDim.x + threadIdx.x) >> 6);
    int lane = threadIdx.x & 63;
    if (wid >= N_NODES) return;
    float sd = (lane < H) ? sdst[(size_t)wid * H + lane] : 0.f;
    float acc[K];
    int hidx[K];
#pragma unroll
    for (int k = 0; k < K; k++) { acc[k] = 0.f; hidx[k] = (lane + 64 * k) / C; }
    float z = 0.f;
    int beg = rowptr[wid], end = rowptr[wid + 1];
    for (int base = beg; base < end; base += 64) {
        int nmax = min(64, end - base);
        int myc = (base + lane < end) ? col[base + lane] : 0;
        int j = 0;
        for (; j + 4 <= nmax; j += 4) {
            int s0 = __shfl(myc, j), s1 = __shfl(myc, j + 1);
            int s2 = __shfl(myc, j + 2), s3 = __shfl(myc, j + 3);
            float w0 = 0.f, w1 = 0.f, w2 = 0.f, w3 = 0.f;
            if (lane < H) {
                float v0 = ssrc[(size_t)s0 * H + lane] + sd;
                float v1 = ssrc[(size_t)s1 * H + lane] + sd;
                float v2 = ssrc[(size_t)s2 * H + lane] + sd;
                float v3 = ssrc[(size_t)s3 * H + lane] + sd;
                v0 = (v0 > 0.f) ? v0 : 0.2f * v0;
                v1 = (v1 > 0.f) ? v1 : 0.2f * v1;
                v2 = (v2 > 0.f) ? v2 : 0.2f * v2;
                v3 = (v3 > 0.f) ? v3 : 0.2f * v3;
                w0 = __expf(v0); w1 = __expf(v1);
                w2 = __expf(v2); w3 = __expf(v3);
                z += (w0 + w1) + (w2 + w3);
            }
            const u16* r0 = Hm + (size_t)s0 * HC;
            const u16* r1 = Hm + (size_t)s1 * HC;
            const u16* r2 = Hm + (size_t)s2 * HC;
            const u16* r3 = Hm + (size_t)s3 * HC;
#pragma unroll
            for (int k = 0; k < K; k++) {
                int el = lane + 64 * k;
                float a0 = b2f(r0[el]), a1 = b2f(r1[el]);
                float a2 = b2f(r2[el]), a3 = b2f(r3[el]);
                acc[k] = fmaf(__shfl(w0, hidx[k]), a0, acc[k]);
                acc[k] = fmaf(__shfl(w1, hidx[k]), a1, acc[k]);
                acc[k] = fmaf(__shfl(w2, hidx[k]), a2, acc[k]);
                acc[k] = fmaf(__shfl(w3, hidx[k]), a3, acc[k]);
            }
        }
        for (; j < nmax; j++) {
            int s0 = __shfl(myc, j);
            float w0 = 0.f;
            if (lane < H) {
                float v = ssrc[(size_t)s0 * H + lane] + sd;
                v = (v > 0.f) ? v : 0.2f * v;
                w0 = __expf(v);
                z += w0;
            }
            const u16* r0 = Hm + (size_t)s0 * HC;
#pragma unroll
            for (int k = 0; k < K; k++)
                acc[k] = fmaf(__shfl(w0, hidx[k]), b2f(r0[lane + 64 * k]), acc[k]);
        }
    }
#pragma unroll
    for (int k = 0; k < K; k++) {
        float zk = __shfl(z, hidx[k]);
        int el = lane + 64 * k;
        out[(size_t)wid * HC + el] = acc[k] / (zk + 1e-16f) + bias[el];
    }
}

// ---------------- small linear: Y[N,NO] = relu(bn(X))[N,K] @ W[K,NO] + b ----------------
template<int K, int NO, int TPR>
__global__ void k_lin(const float* __restrict__ X, const float* __restrict__ W,
                      const float* __restrict__ wb, const float* __restrict__ scale,
                      const float* __restrict__ shift, float* __restrict__ Y) {
    constexpr int KS = K / TPR;  // k per wave-slice
    __shared__ float red[TPR][64][NO];
    int lane = threadIdx.x & 63;
    int wv = __builtin_amdgcn_readfirstlane(threadIdx.x >> 6);  // wave-uniform slice id
    int row = blockIdx.x * 64 + lane;
    int k0 = wv * KS;
    float acc[NO];
#pragma unroll
    for (int c = 0; c < NO; c++) acc[c] = 0.f;
    if (row < N_NODES) {
        const float* xr = X + (size_t)row * K + k0;
        for (int kk = 0; kk < KS; kk += 4) {
            float4 xv = *(const float4*)&xr[kk];
            int k = k0 + kk;
            float x0 = fmaxf(xv.x * scale[k] + shift[k], 0.f);
            float x1 = fmaxf(xv.y * scale[k + 1] + shift[k + 1], 0.f);
            float x2 = fmaxf(xv.z * scale[k + 2] + shift[k + 2], 0.f);
            float x3 = fmaxf(xv.w * scale[k + 3] + shift[k + 3], 0.f);
#pragma unroll
            for (int c = 0; c < NO; c++) {
                acc[c] = fmaf(x0, W[(size_t)k * NO + c],
                         fmaf(x1, W[(size_t)(k + 1) * NO + c],
                         fmaf(x2, W[(size_t)(k + 2) * NO + c],
                         fmaf(x3, W[(size_t)(k + 3) * NO + c], acc[c]))));
            }
        }
    }
#pragma unroll
    for (int c = 0; c < NO; c++) red[wv][lane][c] = acc[c];
    __syncthreads();
    for (int i = threadIdx.x; i < 64 * NO; i += 64 * TPR) {
        int r = i / NO, c = i - r * NO;
        float s = wb[c];
#pragma unroll
        for (int t = 0; t < TPR; t++) s += red[t][r][c];
        int grow = blockIdx.x * 64 + r;
        if (grow < N_NODES) Y[(size_t)grow * NO + c] = s;
    }
}

// ---------------- batchnorm stats: atomic-free per-block partials ----------------
template<int NO>
__global__ void k_bnstats(const float* __restrict__ X, float* __restrict__ psum,
                          float* __restrict__ psumsq) {
    constexpr int BS = (NO >= 256) ? NO : 256;
    constexpr int RPS = BS / NO;
    __shared__ float ls[BS], ls2[BS];
    int c = threadIdx.x % NO;
    int rsub = threadIdx.x / NO;
    constexpr int chunk = (N_NODES + PB - 1) / PB;
    int r0 = blockIdx.x * chunk;
    int r1 = min(N_NODES, r0 + chunk);
    float s = 0.f, s2 = 0.f;
    for (int r = r0 + rsub; r < r1; r += RPS) {
        float v = X[(size_t)r * NO + c];
        s += v;
        s2 += v * v;
    }
    if (RPS > 1) {
        ls[threadIdx.x] = s;
        ls2[threadIdx.x] = s2;
        __syncthreads();
        for (int off = BS / 2; off >= NO; off >>= 1) {
            if (threadIdx.x < off) {
                ls[threadIdx.x] += ls[threadIdx.x + off];
                ls2[threadIdx.x] += ls2[threadIdx.x + off];
            }
            __syncthreads();
        }
        s = ls[threadIdx.x];
        s2 = ls2[threadIdx.x];
    }
    if (rsub == 0) {
        psum[(size_t)blockIdx.x * NO + c] = s;
        psumsq[(size_t)blockIdx.x * NO + c] = s2;
    }
}

__global__ void k_bnfinal(const float* __restrict__ psum, const float* __restrict__ psumsq,
                          const float* __restrict__ g, const float* __restrict__ be,
                          float* __restrict__ scale, float* __restrict__ shift, int NO) {
    int t = threadIdx.x;
    if (t >= NO) return;
    float s = 0.f, s2 = 0.f;
    for (int b = 0; b < PB; b++) {
        s += psum[(size_t)b * NO + t];
        s2 += psumsq[(size_t)b * NO + t];
    }
    float mu = s / (float)N_NODES;
    float var = s2 / (float)N_NODES - mu * mu;
    float sc = g[t] * rsqrtf(var + 1e-5f);
    scale[t] = sc;
    shift[t] = be[t] - mu * sc;
}

// ---------------- pooling ----------------
__global__ void k_bhist(const int* __restrict__ batch, int* __restrict__ cnt) {
    __shared__ int h[G_GRAPHS];
    int tid = threadIdx.x;
    if (tid < G_GRAPHS) h[tid] = 0;
    __syncthreads();
    int i = blockIdx.x * blockDim.x + tid;
    if (i < N_NODES) atomicAdd(&h[batch[i]], 1);
    __syncthreads();
    if (tid < G_GRAPHS) atomicAdd(&cnt[tid], h[tid]);
}

__global__ void k_pool(const float* __restrict__ X, const int* __restrict__ batch,
                       const float* __restrict__ sc, const float* __restrict__ sh,
                       float* __restrict__ pooled) {
    int t = threadIdx.x;  // 384
    const int chunk = (N_NODES + 511) / 512;
    int r0 = blockIdx.x * chunk;
    int r1 = min(N_NODES, r0 + chunk);
    if (r0 >= N_NODES) return;
    float acc = 0.f;
    int cur = batch[r0];
    for (int r = r0; r < r1; r++) {
        int gid = batch[r];
        if (gid != cur) {
            atomicAdd(&pooled[(size_t)cur * 384 + t], acc);
            acc = 0.f;
            cur = gid;
        }
        float v = X[(size_t)r * 384 + t] * sc[t] + sh[t];
        acc += fmaxf(v, 0.f);
    }
    atomicAdd(&pooled[(size_t)cur * 384 + t], acc);
}

__global__ void k_final(const float* __restrict__ pooled, const int* __restrict__ cnt,
                        const float* __restrict__ lwf, const float* __restrict__ lbf,
                        float* __restrict__ out) {
    int t = threadIdx.x;  // 640
    if (t >= G_GRAPHS * 10) return;
    int g = t / 10, c = t - g * 10;
    float inv = 1.0f / fmaxf((float)cnt[g], 1.0f);
    float acc = lbf[c];
    for (int k = 0; k < 384; k++)
        acc = fmaf(pooled[(size_t)g * 384 + k] * inv, lwf[k * 10 + c], acc);
    out[t] = acc;
}

extern "C" void kernel_launch(void* const* d_in, const int* in_sizes, int n_in,
                              void* d_out, int out_size, void* d_ws, size_t ws_size,
                              hipStream_t stream) {
    const float* x    = (const float*)d_in[0];
    const int*   ei   = (const int*)d_in[1];
    const int*   batch= (const int*)d_in[2];
    const float* W1   = (const float*)d_in[3];
    const float* as1  = (const float*)d_in[4];
    const float* ad1  = (const float*)d_in[5];
    const float* b1   = (const float*)d_in[6];
    const float* g1   = (const float*)d_in[7];
    const float* be1  = (const float*)d_in[8];
    const float* lw1  = (const float*)d_in[9];
    const float* lb1  = (const float*)d_in[10];
    const float* gl1  = (const float*)d_in[11];
    const float* bel1 = (const float*)d_in[12];
    const float* W2   = (const float*)d_in[13];
    const float* as2  = (const float*)d_in[14];
    const float* ad2  = (const float*)d_in[15];
    const float* b2   = (const float*)d_in[16];
    const float* g2   = (const float*)d_in[17];
    const float* be2  = (const float*)d_in[18];
    const float* lw2  = (const float*)d_in[19];
    const float* lb2  = (const float*)d_in[20];
    const float* gl2  = (const float*)d_in[21];
    const float* bel2 = (const float*)d_in[22];
    const float* W3   = (const float*)d_in[23];
    const float* as3  = (const float*)d_in[24];
    const float* ad3  = (const float*)d_in[25];
    const float* b3   = (const float*)d_in[26];
    const float* g3   = (const float*)d_in[27];
    const float* be3  = (const float*)d_in[28];
    const float* lwf  = (const float*)d_in[29];
    const float* lbf  = (const float*)d_in[30];
    float* out = (float*)d_out;

    // ---- workspace carve ----
    char* p = (char*)d_ws;
    auto alloc = [&](size_t bytes) {
        char* r = p;
        p += (bytes + 255) & ~(size_t)255;
        return r;
    };
    int*   rowptr = (int*)alloc(4 * (size_t)(N_NODES + 1));
    int*   cursor = (int*)alloc(4 * (size_t)N_NODES);
    int*   deg    = (int*)alloc(4 * (size_t)N_NODES);
    int*   bsum   = (int*)alloc(4 * (size_t)(SCAN_B + 1));
    int*   col    = (int*)alloc(4 * (size_t)TOT_E);
    int*   cdst   = (int*)alloc(4 * (size_t)TOT_E);
    float* ssrc   = (float*)alloc(4 * (size_t)N_NODES * 20);
    float* sdst   = (float*)alloc(4 * (size_t)N_NODES * 20);
    u16*   hbuf   = (u16*)alloc(2 * (size_t)N_NODES * 512);
    float* obuf   = (float*)alloc(4 * (size_t)N_NODES * 512);
    float* xbuf   = (float*)alloc(4 * (size_t)N_NODES * 32);
    float* psum   = (float*)alloc(4 * (size_t)PB * 512);
    float* psumsq = (float*)alloc(4 * (size_t)PB * 512);
    float* scA    = (float*)alloc(4 * 512);
    float* shA    = (float*)alloc(4 * 512);
    float* scB    = (float*)alloc(4 * 64);
    float* shB    = (float*)alloc(4 * 64);
    float* pooled = (float*)alloc(4 * (size_t)G_GRAPHS * 384);
    int*   cnt    = (int*)alloc(4 * G_GRAPHS);

    const int LB = (N_NODES + 63) / 64;   // 782 row-tiles for k_lin
    const int GB = (N_NODES + 31) / 32;   // 1563 row-tiles for k_gemm

    // ---- graph build (reused by all 3 layers) ----
    k_init_deg<<<(N_NODES + 255) / 256, 256, 0, stream>>>(deg);
    k_hist<<<(N_EDGES + 255) / 256, 256, 0, stream>>>(ei, deg);
    k_scan1<<<SCAN_B, 512, 0, stream>>>(deg, rowptr, bsum);
    k_scan2<<<1, 128, 0, stream>>>(bsum);
    k_scan3<<<(N_NODES + 255) / 256, 256, 0, stream>>>(rowptr, cursor, bsum);
    k_scatter<<<(TOT_E + 255) / 256, 256, 0, stream>>>(ei, cursor, col, cdst);
    hipMemsetAsync(pooled, 0, 4 * (size_t)G_GRAPHS * 384 + 256, stream);  // pooled + cnt

    // ---- layer 1: GAT(128 -> 20x16) ----
    k_gemm<128, 320, false><<<GB, 256, 0, stream>>>(x, W1, nullptr, nullptr, hbuf);
    k_scores<20, 16><<<(N_NODES * 20 + 255) / 256, 256, 0, stream>>>(hbuf, as1, ad1, ssrc, sdst);
    k_agg<20, 16><<<(N_NODES + 3) / 4, 256, 0, stream>>>(hbuf, ssrc, sdst, rowptr, col, b1, obuf);
    k_bnstats<320><<<PB, 320, 0, stream>>>(obuf, psum, psumsq);
    k_bnfinal<<<1, 512, 0, stream>>>(psum, psumsq, g1, be1, scA, shA, 320);
    k_lin<320, 16, 4><<<LB, 256, 0, stream>>>(obuf, lw1, lb1, scA, shA, xbuf);
    k_bnstats<16><<<PB, 256, 0, stream>>>(xbuf, psum, psumsq);
    k_bnfinal<<<1, 512, 0, stream>>>(psum, psumsq, gl1, bel1, scB, shB, 16);

    // ---- layer 2: GAT(16 -> 16x32) ----
    k_gemm<16, 512, true><<<GB, 256, 0, stream>>>(xbuf, W2, scB, shB, hbuf);
    k_scores<16, 32><<<(N_NODES * 16 + 255) / 256, 256, 0, stream>>>(hbuf, as2, ad2, ssrc, sdst);
    k_agg<16, 32><<<(N_NODES + 3) / 4, 256, 0, stream>>>(hbuf, ssrc, sdst, rowptr, col, b2, obuf);
    k_bnstats<512><<<PB, 512, 0, stream>>>(obuf, psum, psumsq);
    k_bnfinal<<<1, 512, 0, stream>>>(psum, psumsq, g2, be2, scA, shA, 512);
    k_lin<512, 32, 4><<<LB, 256, 0, stream>>>(obuf, lw2, lb2, scA, shA, xbuf);
    k_bnstats<32><<<PB, 256, 0, stream>>>(xbuf, psum, psumsq);
    k_bnfinal<<<1, 512, 0, stream>>>(psum, psumsq, gl2, bel2, scB, shB, 32);

    // ---- layer 3: GAT(32 -> 8x48) ----
    k_gemm<32, 384, true><<<GB, 256, 0, stream>>>(xbuf, W3, scB, shB, hbuf);
    k_scores<8, 48><<<(N_NODES * 8 + 255) / 256, 256, 0, stream>>>(hbuf, as3, ad3, ssrc, sdst);
    k_agg<8, 48><<<(N_NODES + 3) / 4, 256, 0, stream>>>(hbuf, ssrc, sdst, rowptr, col, b3, obuf);
    k_bnstats<384><<<PB, 384, 0, stream>>>(obuf, psum, psumsq);
    k_bnfinal<<<1, 512, 0, stream>>>(psum, psumsq, g3, be3, scA, shA, 384);

    // ---- pool + classifier ----
    k_bhist<<<(N_NODES + 255) / 256, 256, 0, stream>>>(batch, cnt);
    k_pool<<<512, 384, 0, stream>>>(obuf, batch, scA, shA, pooled);
    k_final<<<1, 640, 0, stream>>>(pooled, cnt, lwf, lbf, out);
}

// Round 12
// 1009.053 us; speedup vs baseline: 1.5188x; 1.0252x over previous
//
#include <hip/hip_runtime.h>
#include <cstdint>
#include <cstddef>

#define N_NODES 50000
#define N_EDGES 400000
#define TOT_E   450000
#define G_GRAPHS 64
#define PB 256   // partial blocks for bnstats
#define SCAN_B 98  // scan blocks of 512 (98*512 = 50176 >= N_NODES)

typedef unsigned short u16;
typedef unsigned int u32;

__device__ __forceinline__ float b2f(u16 v) {
    union { u32 u; float f; } x; x.u = ((u32)v) << 16; return x.f;
}
__device__ __forceinline__ float lo2f(u32 u) {
    union { u32 u; float f; } x; x.u = u << 16; return x.f;
}
__device__ __forceinline__ float hi2f(u32 u) {
    union { u32 u; float f; } x; x.u = u & 0xffff0000u; return x.f;
}
__device__ __forceinline__ u16 f2b(float f) {
    union { float f; u32 u; } x; x.f = f;
    u32 r = x.u + 0x7fffu + ((x.u >> 16) & 1u);  // round-nearest-even
    return (u16)(r >> 16);
}

// ---------------- graph build ----------------
__global__ void k_init_deg(int* __restrict__ deg) {
    int i = blockIdx.x * blockDim.x + threadIdx.x;
    if (i < N_NODES) deg[i] = 1;  // self loop
}

__global__ void k_hist(const int* __restrict__ ei, int* __restrict__ deg) {
    int e = blockIdx.x * blockDim.x + threadIdx.x;
    if (e < N_EDGES) atomicAdd(&deg[ei[N_EDGES + e]], 1);
}

// phase 1: block-local exclusive scan, block totals to bsum
__global__ void k_scan1(const int* __restrict__ deg, int* __restrict__ rowptr,
                        int* __restrict__ bsum) {
    __shared__ int buf[512];
    int tid = threadIdx.x;
    int i = blockIdx.x * 512 + tid;
    int v = (i < N_NODES) ? deg[i] : 0;
    buf[tid] = v;
    __syncthreads();
    for (int off = 1; off < 512; off <<= 1) {
        int t = (tid >= off) ? buf[tid - off] : 0;
        __syncthreads();
        buf[tid] += t;
        __syncthreads();
    }
    if (i < N_NODES) rowptr[i] = buf[tid] - v;  // block-local exclusive
    if (tid == 511) bsum[blockIdx.x] = buf[511];
}

// phase 2: exclusive scan of the 98 block sums (single 128-thread block)
__global__ void k_scan2(int* __restrict__ bsum) {
    __shared__ int buf[128];
    int tid = threadIdx.x;
    int v = (tid < SCAN_B) ? bsum[tid] : 0;
    buf[tid] = v;
    __syncthreads();
    for (int off = 1; off < 128; off <<= 1) {
        int t = (tid >= off) ? buf[tid - off] : 0;
        __syncthreads();
        buf[tid] += t;
        __syncthreads();
    }
    if (tid < SCAN_B) bsum[tid] = buf[tid] - v;  // exclusive
}

// phase 3: add block offsets; write cursor; rowptr[N] = TOT_E (statically known)
__global__ void k_scan3(int* __restrict__ rowptr, int* __restrict__ cursor,
                        const int* __restrict__ bsum) {
    int i = blockIdx.x * blockDim.x + threadIdx.x;
    if (i < N_NODES) {
        int v = rowptr[i] + bsum[i >> 9];
        rowptr[i] = v;
        cursor[i] = v;
    }
    if (i == 0) rowptr[N_NODES] = TOT_E;
}

__global__ void k_scatter(const int* __restrict__ ei, int* __restrict__ cursor,
                          int* __restrict__ col, int* __restrict__ cdst) {
    int e = blockIdx.x * blockDim.x + threadIdx.x;
    if (e < N_EDGES) {
        int s = ei[e], d = ei[N_EDGES + e];
        int p = atomicAdd(&cursor[d], 1);
        col[p] = s;
        cdst[p] = d;
    } else if (e < TOT_E) {
        int i = e - N_EDGES;
        int p = atomicAdd(&cursor[i], 1);
        col[p] = i;
        cdst[p] = i;
    }
}

// ---------------- register-tiled GEMM: Y[N,NO] = xform(X)[N,K] @ W[K,NO], bf16 out ----
// __launch_bounds__(256,2): 2 waves/EU -> 256 VGPRs, keeps acc/xv/w in registers
// (round-8 regression: default occupancy target spilled the acc tile).
template<int K, int NO, bool XFORM>
__global__ __launch_bounds__(256, 2)
void k_gemm(const float* __restrict__ X, const float* __restrict__ W,
            const float* __restrict__ scale, const float* __restrict__ shift,
            u16* __restrict__ Y) {
    constexpr int TM = 32;
    constexpr int CPT = NO / 64;
    __shared__ float xs[TM][K + 4];
    int tid = threadIdx.x;
    int r0 = blockIdx.x * TM;
    constexpr int NV = TM * K / 4;
    for (int i = tid; i < NV; i += 256) {
        int rr = (i * 4) / K, kk = (i * 4) % K;
        float4 v = make_float4(0.f, 0.f, 0.f, 0.f);
        if (r0 + rr < N_NODES) {
            v = *(const float4*)&X[(size_t)(r0 + rr) * K + kk];
            if (XFORM) {
                v.x = fmaxf(v.x * scale[kk] + shift[kk], 0.f);
                v.y = fmaxf(v.y * scale[kk + 1] + shift[kk + 1], 0.f);
                v.z = fmaxf(v.z * scale[kk + 2] + shift[kk + 2], 0.f);
                v.w = fmaxf(v.w * scale[kk + 3] + shift[kk + 3], 0.f);
            }
        }
        *(float4*)&xs[rr][kk] = v;
    }
    __syncthreads();
    int c = tid & 63;
    int rbase = (tid >> 6) * 8;
    float acc[8][CPT];
#pragma unroll
    for (int r = 0; r < 8; r++)
#pragma unroll
        for (int j = 0; j < CPT; j++) acc[r][j] = 0.f;

    for (int kq = 0; kq < K; kq += 4) {
        float4 xv[8];
#pragma unroll
        for (int r = 0; r < 8; r++) xv[r] = *(const float4*)&xs[rbase + r][kq];
#pragma unroll
        for (int kk = 0; kk < 4; kk++) {
            float w[CPT];
#pragma unroll
            for (int j = 0; j < CPT; j++) w[j] = W[(size_t)(kq + kk) * NO + c + 64 * j];
#pragma unroll
            for (int r = 0; r < 8; r++) {
                float xk = (kk == 0) ? xv[r].x : (kk == 1) ? xv[r].y : (kk == 2) ? xv[r].z : xv[r].w;
#pragma unroll
                for (int j = 0; j < CPT; j++) acc[r][j] = fmaf(xk, w[j], acc[r][j]);
            }
        }
    }
#pragma unroll
    for (int r = 0; r < 8; r++) {
        int grow = r0 + rbase + r;
        if (grow < N_NODES) {
#pragma unroll
            for (int j = 0; j < CPT; j++)
                Y[(size_t)grow * NO + c + 64 * j] = f2b(acc[r][j]);
        }
    }
}

// ---------------- attention scores (bf16 input, uint-packed reads) ----------------
template<int H, int C>
__global__ void k_scores(const u16* __restrict__ Hm, const float* __restrict__ asrc,
                         const float* __restrict__ adst, float* __restrict__ ssrc,
                         float* __restrict__ sdst) {
    int t = blockIdx.x * blockDim.x + threadIdx.x;
    if (t >= N_NODES * H) return;
    int i = t / H, h = t - i * H;
    const u32* row = (const u32*)(Hm + (size_t)i * H * C + h * C);
    float s1 = 0.f, s2 = 0.f;
#pragma unroll
    for (int c2 = 0; c2 < C / 2; c2++) {
        u32 u = row[c2];
        float v0 = lo2f(u), v1 = hi2f(u);
        int c = c2 * 2;
        s1 = fmaf(v0, asrc[h * C + c], fmaf(v1, asrc[h * C + c + 1], s1));
        s2 = fmaf(v0, adst[h * C + c], fmaf(v1, adst[h * C + c + 1], s2));
    }
    ssrc[t] = s1;
    sdst[t] = s2;
}

// ---------------- fused edge-softmax + aggregation (u32-packed bf16 gather) ----------
// Each u32 word = 2 bf16 elements in the SAME head (C even) -> one load + one shfl
// feeds 2 FMAs. Halves gather and shuffle instruction counts vs u16 version.
template<int H, int C>
__global__ void k_agg(const u16* __restrict__ Hm, const float* __restrict__ ssrc,
                      const float* __restrict__ sdst, const int* __restrict__ rowptr,
                      const int* __restrict__ col, const float* __restrict__ bias,
                      float* __restrict__ out) {
    constexpr int HC = H * C;
    constexpr int HW = HC / 2;            // u32 words per row
    constexpr int KU = HW / 64;           // full word rounds
    constexpr int REM = HW % 64;          // remainder words (lane < REM valid)
    constexpr int KT = KU + (REM ? 1 : 0);
    int wid = (int)((blockIdx.x * blockDim.x + threadIdx.x) >> 6);
    int lane = threadIdx.x & 63;
    if (wid >= N_NODES) return;
    float sd = (lane < H) ? sdst[(size_t)wid * H + lane] : 0.f;
    float2 acc[KT];
    int hidx[KT];
#pragma unroll
    for (int k = 0; k < KT; k++) {
        acc[k] = make_float2(0.f, 0.f);
        hidx[k] = (2 * (lane + 64 * k)) / C;  // head of both packed elements
    }
    float z = 0.f;
    int beg = rowptr[wid], end = rowptr[wid + 1];
    for (int base = beg; base < end; base += 64) {
        int nmax = min(64, end - base);
        int myc = (base + lane < end) ? col[base + lane] : 0;
        int j = 0;
        for (; j + 4 <= nmax; j += 4) {
            int s0 = __shfl(myc, j), s1 = __shfl(myc, j + 1);
            int s2 = __shfl(myc, j + 2), s3 = __shfl(myc, j + 3);
            float w0 = 0.f, w1 = 0.f, w2 = 0.f, w3 = 0.f;
            if (lane < H) {
                float v0 = ssrc[(size_t)s0 * H + lane] + sd;
                float v1 = ssrc[(size_t)s1 * H + lane] + sd;
                float v2 = ssrc[(size_t)s2 * H + lane] + sd;
                float v3 = ssrc[(size_t)s3 * H + lane] + sd;
                v0 = (v0 > 0.f) ? v0 : 0.2f * v0;
                v1 = (v1 > 0.f) ? v1 : 0.2f * v1;
                v2 = (v2 > 0.f) ? v2 : 0.2f * v2;
                v3 = (v3 > 0.f) ? v3 : 0.2f * v3;
                w0 = __expf(v0); w1 = __expf(v1);
                w2 = __expf(v2); w3 = __expf(v3);
                z += (w0 + w1) + (w2 + w3);
            }
            const u32* r0 = (const u32*)(Hm + (size_t)s0 * HC);
            const u32* r1 = (const u32*)(Hm + (size_t)s1 * HC);
            const u32* r2 = (const u32*)(Hm + (size_t)s2 * HC);
            const u32* r3 = (const u32*)(Hm + (size_t)s3 * HC);
#pragma unroll
            for (int k = 0; k < KT; k++) {
                int idx = lane + 64 * k;  // rem round may over-read within pitch: safe
                u32 a0 = r0[idx], a1 = r1[idx], a2 = r2[idx], a3 = r3[idx];
                float wk0 = __shfl(w0, hidx[k]);
                float wk1 = __shfl(w1, hidx[k]);
                float wk2 = __shfl(w2, hidx[k]);
                float wk3 = __shfl(w3, hidx[k]);
                acc[k].x = fmaf(wk0, lo2f(a0), acc[k].x);
                acc[k].y = fmaf(wk0, hi2f(a0), acc[k].y);
                acc[k].x = fmaf(wk1, lo2f(a1), acc[k].x);
                acc[k].y = fmaf(wk1, hi2f(a1), acc[k].y);
                acc[k].x = fmaf(wk2, lo2f(a2), acc[k].x);
                acc[k].y = fmaf(wk2, hi2f(a2), acc[k].y);
                acc[k].x = fmaf(wk3, lo2f(a3), acc[k].x);
                acc[k].y = fmaf(wk3, hi2f(a3), acc[k].y);
            }
        }
        for (; j < nmax; j++) {
            int s0 = __shfl(myc, j);
            float w0 = 0.f;
            if (lane < H) {
                float v = ssrc[(size_t)s0 * H + lane] + sd;
                v = (v > 0.f) ? v : 0.2f * v;
                w0 = __expf(v);
                z += w0;
            }
            const u32* r0 = (const u32*)(Hm + (size_t)s0 * HC);
#pragma unroll
            for (int k = 0; k < KT; k++) {
                int idx = lane + 64 * k;
                u32 a0 = r0[idx];
                float wk0 = __shfl(w0, hidx[k]);
                acc[k].x = fmaf(wk0, lo2f(a0), acc[k].x);
                acc[k].y = fmaf(wk0, hi2f(a0), acc[k].y);
            }
        }
    }
    const float2* bias2 = (const float2*)bias;
    float2* orow = (float2*)(out + (size_t)wid * HC);
#pragma unroll
    for (int k = 0; k < KT; k++) {
        float zk = __shfl(z, hidx[k]);  // all lanes execute shfl
        if (k < KU || lane < REM) {
            int idx = lane + 64 * k;
            float2 b = bias2[idx];
            float inv = 1.0f / (zk + 1e-16f);
            orow[idx] = make_float2(fmaf(acc[k].x, inv, b.x), fmaf(acc[k].y, inv, b.y));
        }
    }
}

// ---------------- small linear: Y[N,NO] = relu(bn(X))[N,K] @ W[K,NO] + b ----------------
template<int K, int NO, int TPR>
__global__ void k_lin(const float* __restrict__ X, const float* __restrict__ W,
                      const float* __restrict__ wb, const float* __restrict__ scale,
                      const float* __restrict__ shift, float* __restrict__ Y) {
    constexpr int KS = K / TPR;  // k per wave-slice
    __shared__ float red[TPR][64][NO];
    int lane = threadIdx.x & 63;
    int wv = __builtin_amdgcn_readfirstlane(threadIdx.x >> 6);  // wave-uniform slice id
    int row = blockIdx.x * 64 + lane;
    int k0 = wv * KS;
    float acc[NO];
#pragma unroll
    for (int c = 0; c < NO; c++) acc[c] = 0.f;
    if (row < N_NODES) {
        const float* xr = X + (size_t)row * K + k0;
        for (int kk = 0; kk < KS; kk += 4) {
            float4 xv = *(const float4*)&xr[kk];
            int k = k0 + kk;
            float x0 = fmaxf(xv.x * scale[k] + shift[k], 0.f);
            float x1 = fmaxf(xv.y * scale[k + 1] + shift[k + 1], 0.f);
            float x2 = fmaxf(xv.z * scale[k + 2] + shift[k + 2], 0.f);
            float x3 = fmaxf(xv.w * scale[k + 3] + shift[k + 3], 0.f);
#pragma unroll
            for (int c = 0; c < NO; c++) {
                acc[c] = fmaf(x0, W[(size_t)k * NO + c],
                         fmaf(x1, W[(size_t)(k + 1) * NO + c],
                         fmaf(x2, W[(size_t)(k + 2) * NO + c],
                         fmaf(x3, W[(size_t)(k + 3) * NO + c], acc[c]))));
            }
        }
    }
#pragma unroll
    for (int c = 0; c < NO; c++) red[wv][lane][c] = acc[c];
    __syncthreads();
    for (int i = threadIdx.x; i < 64 * NO; i += 64 * TPR) {
        int r = i / NO, c = i - r * NO;
        float s = wb[c];
#pragma unroll
        for (int t = 0; t < TPR; t++) s += red[t][r][c];
        int grow = blockIdx.x * 64 + r;
        if (grow < N_NODES) Y[(size_t)grow * NO + c] = s;
    }
}

// ---------------- batchnorm stats: atomic-free per-block partials ----------------
template<int NO>
__global__ void k_bnstats(const float* __restrict__ X, float* __restrict__ psum,
                          float* __restrict__ psumsq) {
    constexpr int BS = (NO >= 256) ? NO : 256;
    constexpr int RPS = BS / NO;
    __shared__ float ls[BS], ls2[BS];
    int c = threadIdx.x % NO;
    int rsub = threadIdx.x / NO;
    constexpr int chunk = (N_NODES + PB - 1) / PB;
    int r0 = blockIdx.x * chunk;
    int r1 = min(N_NODES, r0 + chunk);
    float s = 0.f, s2 = 0.f;
    for (int r = r0 + rsub; r < r1; r += RPS) {
        float v = X[(size_t)r * NO + c];
        s += v;
        s2 += v * v;
    }
    if (RPS > 1) {
        ls[threadIdx.x] = s;
        ls2[threadIdx.x] = s2;
        __syncthreads();
        for (int off = BS / 2; off >= NO; off >>= 1) {
            if (threadIdx.x < off) {
                ls[threadIdx.x] += ls[threadIdx.x + off];
                ls2[threadIdx.x] += ls2[threadIdx.x + off];
            }
            __syncthreads();
        }
        s = ls[threadIdx.x];
        s2 = ls2[threadIdx.x];
    }
    if (rsub == 0) {
        psum[(size_t)blockIdx.x * NO + c] = s;
        psumsq[(size_t)blockIdx.x * NO + c] = s2;
    }
}

__global__ void k_bnfinal(const float* __restrict__ psum, const float* __restrict__ psumsq,
                          const float* __restrict__ g, const float* __restrict__ be,
                          float* __restrict__ scale, float* __restrict__ shift, int NO) {
    int t = threadIdx.x;
    if (t >= NO) return;
    float s = 0.f, s2 = 0.f;
    for (int b = 0; b < PB; b++) {
        s += psum[(size_t)b * NO + t];
        s2 += psumsq[(size_t)b * NO + t];
    }
    float mu = s / (float)N_NODES;
    float var = s2 / (float)N_NODES - mu * mu;
    float sc = g[t] * rsqrtf(var + 1e-5f);
    scale[t] = sc;
    shift[t] = be[t] - mu * sc;
}

// ---------------- pooling ----------------
__global__ void k_bhist(const int* __restrict__ batch, int* __restrict__ cnt) {
    __shared__ int h[G_GRAPHS];
    int tid = threadIdx.x;
    if (tid < G_GRAPHS) h[tid] = 0;
    __syncthreads();
    int i = blockIdx.x * blockDim.x + tid;
    if (i < N_NODES) atomicAdd(&h[batch[i]], 1);
    __syncthreads();
    if (tid < G_GRAPHS) atomicAdd(&cnt[tid], h[tid]);
}

__global__ void k_pool(const float* __restrict__ X, const int* __restrict__ batch,
                       const float* __restrict__ sc, const float* __restrict__ sh,
                       float* __restrict__ pooled) {
    int t = threadIdx.x;  // 384
    const int chunk = (N_NODES + 511) / 512;
    int r0 = blockIdx.x * chunk;
    int r1 = min(N_NODES, r0 + chunk);
    if (r0 >= N_NODES) return;
    float acc = 0.f;
    int cur = batch[r0];
    for (int r = r0; r < r1; r++) {
        int gid = batch[r];
        if (gid != cur) {
            atomicAdd(&pooled[(size_t)cur * 384 + t], acc);
            acc = 0.f;
            cur = gid;
        }
        float v = X[(size_t)r * 384 + t] * sc[t] + sh[t];
        acc += fmaxf(v, 0.f);
    }
    atomicAdd(&pooled[(size_t)cur * 384 + t], acc);
}

__global__ void k_final(const float* __restrict__ pooled, const int* __restrict__ cnt,
                        const float* __restrict__ lwf, const float* __restrict__ lbf,
                        float* __restrict__ out) {
    int t = threadIdx.x;  // 640
    if (t >= G_GRAPHS * 10) return;
    int g = t / 10, c = t - g * 10;
    float inv = 1.0f / fmaxf((float)cnt[g], 1.0f);
    float acc = lbf[c];
    for (int k = 0; k < 384; k++)
        acc = fmaf(pooled[(size_t)g * 384 + k] * inv, lwf[k * 10 + c], acc);
    out[t] = acc;
}

extern "C" void kernel_launch(void* const* d_in, const int* in_sizes, int n_in,
                              void* d_out, int out_size, void* d_ws, size_t ws_size,
                              hipStream_t stream) {
    const float* x    = (const float*)d_in[0];
    const int*   ei   = (const int*)d_in[1];
    const int*   batch= (const int*)d_in[2];
    const float* W1   = (const float*)d_in[3];
    const float* as1  = (const float*)d_in[4];
    const float* ad1  = (const float*)d_in[5];
    const float* b1   = (const float*)d_in[6];
    const float* g1   = (const float*)d_in[7];
    const float* be1  = (const float*)d_in[8];
    const float* lw1  = (const float*)d_in[9];
    const float* lb1  = (const float*)d_in[10];
    const float* gl1  = (const float*)d_in[11];
    const float* bel1 = (const float*)d_in[12];
    const float* W2   = (const float*)d_in[13];
    const float* as2  = (const float*)d_in[14];
    const float* ad2  = (const float*)d_in[15];
    const float* b2   = (const float*)d_in[16];
    const float* g2   = (const float*)d_in[17];
    const float* be2  = (const float*)d_in[18];
    const float* lw2  = (const float*)d_in[19];
    const float* lb2  = (const float*)d_in[20];
    const float* gl2  = (const float*)d_in[21];
    const float* bel2 = (const float*)d_in[22];
    const float* W3   = (const float*)d_in[23];
    const float* as3  = (const float*)d_in[24];
    const float* ad3  = (const float*)d_in[25];
    const float* b3   = (const float*)d_in[26];
    const float* g3   = (const float*)d_in[27];
    const float* be3  = (const float*)d_in[28];
    const float* lwf  = (const float*)d_in[29];
    const float* lbf  = (const float*)d_in[30];
    float* out = (float*)d_out;

    // ---- workspace carve ----
    char* p = (char*)d_ws;
    auto alloc = [&](size_t bytes) {
        char* r = p;
        p += (bytes + 255) & ~(size_t)255;
        return r;
    };
    int*   rowptr = (int*)alloc(4 * (size_t)(N_NODES + 1));
    int*   cursor = (int*)alloc(4 * (size_t)N_NODES);
    int*   deg    = (int*)alloc(4 * (size_t)N_NODES);
    int*   bsum   = (int*)alloc(4 * (size_t)(SCAN_B + 1));
    int*   col    = (int*)alloc(4 * (size_t)TOT_E);
    int*   cdst   = (int*)alloc(4 * (size_t)TOT_E);
    float* ssrc   = (float*)alloc(4 * (size_t)N_NODES * 20);
    float* sdst   = (float*)alloc(4 * (size_t)N_NODES * 20);
    u16*   hbuf   = (u16*)alloc(2 * (size_t)N_NODES * 512);
    float* obuf   = (float*)alloc(4 * (size_t)N_NODES * 512);
    float* xbuf   = (float*)alloc(4 * (size_t)N_NODES * 32);
    float* psum   = (float*)alloc(4 * (size_t)PB * 512);
    float* psumsq = (float*)alloc(4 * (size_t)PB * 512);
    float* scA    = (float*)alloc(4 * 512);
    float* shA    = (float*)alloc(4 * 512);
    float* scB    = (float*)alloc(4 * 64);
    float* shB    = (float*)alloc(4 * 64);
    float* pooled = (float*)alloc(4 * (size_t)G_GRAPHS * 384);
    int*   cnt    = (int*)alloc(4 * G_GRAPHS);

    const int LB = (N_NODES + 63) / 64;   // 782 row-tiles for k_lin
    const int GB = (N_NODES + 31) / 32;   // 1563 row-tiles for k_gemm

    // ---- graph build (reused by all 3 layers) ----
    k_init_deg<<<(N_NODES + 255) / 256, 256, 0, stream>>>(deg);
    k_hist<<<(N_EDGES + 255) / 256, 256, 0, stream>>>(ei, deg);
    k_scan1<<<SCAN_B, 512, 0, stream>>>(deg, rowptr, bsum);
    k_scan2<<<1, 128, 0, stream>>>(bsum);
    k_scan3<<<(N_NODES + 255) / 256, 256, 0, stream>>>(rowptr, cursor, bsum);
    k_scatter<<<(TOT_E + 255) / 256, 256, 0, stream>>>(ei, cursor, col, cdst);
    hipMemsetAsync(pooled, 0, 4 * (size_t)G_GRAPHS * 384 + 256, stream);  // pooled + cnt

    // ---- layer 1: GAT(128 -> 20x16) ----
    k_gemm<128, 320, false><<<GB, 256, 0, stream>>>(x, W1, nullptr, nullptr, hbuf);
    k_scores<20, 16><<<(N_NODES * 20 + 255) / 256, 256, 0, stream>>>(hbuf, as1, ad1, ssrc, sdst);
    k_agg<20, 16><<<(N_NODES + 3) / 4, 256, 0, stream>>>(hbuf, ssrc, sdst, rowptr, col, b1, obuf);
    k_bnstats<320><<<PB, 320, 0, stream>>>(obuf, psum, psumsq);
    k_bnfinal<<<1, 512, 0, stream>>>(psum, psumsq, g1, be1, scA, shA, 320);
    k_lin<320, 16, 4><<<LB, 256, 0, stream>>>(obuf, lw1, lb1, scA, shA, xbuf);
    k_bnstats<16><<<PB, 256, 0, stream>>>(xbuf, psum, psumsq);
    k_bnfinal<<<1, 512, 0, stream>>>(psum, psumsq, gl1, bel1, scB, shB, 16);

    // ---- layer 2: GAT(16 -> 16x32) ----
    k_gemm<16, 512, true><<<GB, 256, 0, stream>>>(xbuf, W2, scB, shB, hbuf);
    k_scores<16, 32><<<(N_NODES * 16 + 255) / 256, 256, 0, stream>>>(hbuf, as2, ad2, ssrc, sdst);
    k_agg<16, 32><<<(N_NODES + 3) / 4, 256, 0, stream>>>(hbuf, ssrc, sdst, rowptr, col, b2, obuf);
    k_bnstats<512><<<PB, 512, 0, stream>>>(obuf, psum, psumsq);
    k_bnfinal<<<1, 512, 0, stream>>>(psum, psumsq, g2, be2, scA, shA, 512);
    k_lin<512, 32, 4><<<LB, 256, 0, stream>>>(obuf, lw2, lb2, scA, shA, xbuf);
    k_bnstats<32><<<PB, 256, 0, stream>>>(xbuf, psum, psumsq);
    k_bnfinal<<<1, 512, 0, stream>>>(psum, psumsq, gl2, bel2, scB, shB, 32);

    // ---- layer 3: GAT(32 -> 8x48) ----
    k_gemm<32, 384, true><<<GB, 256, 0, stream>>>(xbuf, W3, scB, shB, hbuf);
    k_scores<8, 48><<<(N_NODES * 8 + 255) / 256, 256, 0, stream>>>(hbuf, as3, ad3, ssrc, sdst);
    k_agg<8, 48><<<(N_NODES + 3) / 4, 256, 0, stream>>>(hbuf, ssrc, sdst, rowptr, col, b3, obuf);
    k_bnstats<384><<<PB, 384, 0, stream>>>(obuf, psum, psumsq);
    k_bnfinal<<<1, 512, 0, stream>>>(psum, psumsq, g3, be3, scA, shA, 384);

    // ---- pool + classifier ----
    k_bhist<<<(N_NODES + 255) / 256, 256, 0, stream>>>(batch, cnt);
    k_pool<<<512, 384, 0, stream>>>(obuf, batch, scA, shA, pooled);
    k_final<<<1, 640, 0, stream>>>(pooled, cnt, lwf, lbf, out);
}

// Round 13
// 1006.777 us; speedup vs baseline: 1.5222x; 1.0023x over previous
//
#include <hip/hip_runtime.h>
#include <cstdint>
#include <cstddef>

#define N_NODES 50000
#define N_EDGES 400000
#define TOT_E   450000
#define G_GRAPHS 64
#define PB 256   // partial blocks for bnstats
#define SCAN_B 98  // scan blocks of 512 (98*512 = 50176 >= N_NODES)

typedef unsigned short u16;
typedef unsigned int u32;

__device__ __forceinline__ float b2f(u16 v) {
    union { u32 u; float f; } x; x.u = ((u32)v) << 16; return x.f;
}
__device__ __forceinline__ float lo2f(u32 u) {
    union { u32 u; float f; } x; x.u = u << 16; return x.f;
}
__device__ __forceinline__ float hi2f(u32 u) {
    union { u32 u; float f; } x; x.u = u & 0xffff0000u; return x.f;
}
__device__ __forceinline__ u16 f2b(float f) {
    union { float f; u32 u; } x; x.f = f;
    u32 r = x.u + 0x7fffu + ((x.u >> 16) & 1u);  // round-nearest-even
    return (u16)(r >> 16);
}

// ---------------- graph build ----------------
__global__ void k_init_deg(int* __restrict__ deg) {
    int i = blockIdx.x * blockDim.x + threadIdx.x;
    if (i < N_NODES) deg[i] = 1;  // self loop
}

__global__ void k_hist(const int* __restrict__ ei, int* __restrict__ deg) {
    int e = blockIdx.x * blockDim.x + threadIdx.x;
    if (e < N_EDGES) atomicAdd(&deg[ei[N_EDGES + e]], 1);
}

// phase 1: block-local exclusive scan, block totals to bsum
__global__ void k_scan1(const int* __restrict__ deg, int* __restrict__ rowptr,
                        int* __restrict__ bsum) {
    __shared__ int buf[512];
    int tid = threadIdx.x;
    int i = blockIdx.x * 512 + tid;
    int v = (i < N_NODES) ? deg[i] : 0;
    buf[tid] = v;
    __syncthreads();
    for (int off = 1; off < 512; off <<= 1) {
        int t = (tid >= off) ? buf[tid - off] : 0;
        __syncthreads();
        buf[tid] += t;
        __syncthreads();
    }
    if (i < N_NODES) rowptr[i] = buf[tid] - v;  // block-local exclusive
    if (tid == 511) bsum[blockIdx.x] = buf[511];
}

// phase 2: exclusive scan of the 98 block sums (single 128-thread block)
__global__ void k_scan2(int* __restrict__ bsum) {
    __shared__ int buf[128];
    int tid = threadIdx.x;
    int v = (tid < SCAN_B) ? bsum[tid] : 0;
    buf[tid] = v;
    __syncthreads();
    for (int off = 1; off < 128; off <<= 1) {
        int t = (tid >= off) ? buf[tid - off] : 0;
        __syncthreads();
        buf[tid] += t;
        __syncthreads();
    }
    if (tid < SCAN_B) bsum[tid] = buf[tid] - v;  // exclusive
}

// phase 3: add block offsets; write cursor; rowptr[N] = TOT_E (statically known)
__global__ void k_scan3(int* __restrict__ rowptr, int* __restrict__ cursor,
                        const int* __restrict__ bsum) {
    int i = blockIdx.x * blockDim.x + threadIdx.x;
    if (i < N_NODES) {
        int v = rowptr[i] + bsum[i >> 9];
        rowptr[i] = v;
        cursor[i] = v;
    }
    if (i == 0) rowptr[N_NODES] = TOT_E;
}

__global__ void k_scatter(const int* __restrict__ ei, int* __restrict__ cursor,
                          int* __restrict__ col, int* __restrict__ cdst) {
    int e = blockIdx.x * blockDim.x + threadIdx.x;
    if (e < N_EDGES) {
        int s = ei[e], d = ei[N_EDGES + e];
        int p = atomicAdd(&cursor[d], 1);
        col[p] = s;
        cdst[p] = d;
    } else if (e < TOT_E) {
        int i = e - N_EDGES;
        int p = atomicAdd(&cursor[i], 1);
        col[p] = i;
        cdst[p] = i;
    }
}

// ---------------- scalar-X GEMM: Y[N,NO] = xform(X)[N,K] @ W[K,NO], bf16 out ----------
// Each wave owns 8 rows; X addresses are wave-uniform (readfirstlane-forced) so the
// X path uses the scalar pipe (s_load) — no LDS staging, no syncthreads, no ds_read.
// Inner loop: v_fma (SGPR x) with coalesced W loads. Lanes = 64 columns, CPT=NO/64.
template<int K, int NO, bool XFORM>
__global__ __launch_bounds__(256, 2)
void k_gemm(const float* __restrict__ X, const float* __restrict__ W,
            const float* __restrict__ scale, const float* __restrict__ shift,
            u16* __restrict__ Y) {
    constexpr int CPT = NO / 64;
    constexpr int WR = 8;  // rows per wave
    int lane = threadIdx.x & 63;
    int wv = __builtin_amdgcn_readfirstlane((int)(threadIdx.x >> 6));  // wave-uniform
    int rbase = blockIdx.x * 32 + wv * WR;
    float acc[WR][CPT];
#pragma unroll
    for (int r = 0; r < WR; r++)
#pragma unroll
        for (int j = 0; j < CPT; j++) acc[r][j] = 0.f;

    const float* xr[WR];
#pragma unroll
    for (int r = 0; r < WR; r++) {
        int row = rbase + r;
        if (row >= N_NODES) row = N_NODES - 1;  // clamp: bounds-safe uniform loads
        xr[r] = X + (size_t)row * K;
    }

    for (int k = 0; k < K; k += 4) {
        float4 xk[WR];
#pragma unroll
        for (int r = 0; r < WR; r++) xk[r] = *(const float4*)&xr[r][k];
        if (XFORM) {
            float4 sc = *(const float4*)&scale[k];
            float4 sh = *(const float4*)&shift[k];
#pragma unroll
            for (int r = 0; r < WR; r++) {
                xk[r].x = fmaxf(xk[r].x * sc.x + sh.x, 0.f);
                xk[r].y = fmaxf(xk[r].y * sc.y + sh.y, 0.f);
                xk[r].z = fmaxf(xk[r].z * sc.z + sh.z, 0.f);
                xk[r].w = fmaxf(xk[r].w * sc.w + sh.w, 0.f);
            }
        }
#pragma unroll
        for (int kk = 0; kk < 4; kk++) {
            float w[CPT];
#pragma unroll
            for (int j = 0; j < CPT; j++) w[j] = W[(size_t)(k + kk) * NO + lane + 64 * j];
#pragma unroll
            for (int r = 0; r < WR; r++) {
                float xv = (kk == 0) ? xk[r].x : (kk == 1) ? xk[r].y : (kk == 2) ? xk[r].z : xk[r].w;
#pragma unroll
                for (int j = 0; j < CPT; j++) acc[r][j] = fmaf(xv, w[j], acc[r][j]);
            }
        }
    }
#pragma unroll
    for (int r = 0; r < WR; r++) {
        int grow = rbase + r;
        if (grow < N_NODES) {
#pragma unroll
            for (int j = 0; j < CPT; j++)
                Y[(size_t)grow * NO + lane + 64 * j] = f2b(acc[r][j]);
        }
    }
}

// ---------------- attention scores (bf16 input, uint-packed reads) ----------------
template<int H, int C>
__global__ void k_scores(const u16* __restrict__ Hm, const float* __restrict__ asrc,
                         const float* __restrict__ adst, float* __restrict__ ssrc,
                         float* __restrict__ sdst) {
    int t = blockIdx.x * blockDim.x + threadIdx.x;
    if (t >= N_NODES * H) return;
    int i = t / H, h = t - i * H;
    const u32* row = (const u32*)(Hm + (size_t)i * H * C + h * C);
    float s1 = 0.f, s2 = 0.f;
#pragma unroll
    for (int c2 = 0; c2 < C / 2; c2++) {
        u32 u = row[c2];
        float v0 = lo2f(u), v1 = hi2f(u);
        int c = c2 * 2;
        s1 = fmaf(v0, asrc[h * C + c], fmaf(v1, asrc[h * C + c + 1], s1));
        s2 = fmaf(v0, adst[h * C + c], fmaf(v1, adst[h * C + c + 1], s2));
    }
    ssrc[t] = s1;
    sdst[t] = s2;
}

// ---------------- fused edge-softmax + aggregation (u32-packed bf16 gather) ----------
template<int H, int C>
__global__ void k_agg(const u16* __restrict__ Hm, const float* __restrict__ ssrc,
                      const float* __restrict__ sdst, const int* __restrict__ rowptr,
                      const int* __restrict__ col, const float* __restrict__ bias,
                      float* __restrict__ out) {
    constexpr int HC = H * C;
    constexpr int HW = HC / 2;            // u32 words per row
    constexpr int KU = HW / 64;           // full word rounds
    constexpr int REM = HW % 64;          // remainder words (lane < REM valid)
    constexpr int KT = KU + (REM ? 1 : 0);
    int wid = (int)((blockIdx.x * blockDim.x + threadIdx.x) >> 6);
    int lane = threadIdx.x & 63;
    if (wid >= N_NODES) return;
    float sd = (lane < H) ? sdst[(size_t)wid * H + lane] : 0.f;
    float2 acc[KT];
    int hidx[KT];
#pragma unroll
    for (int k = 0; k < KT; k++) {
        acc[k] = make_float2(0.f, 0.f);
        hidx[k] = (2 * (lane + 64 * k)) / C;  // head of both packed elements
    }
    float z = 0.f;
    int beg = rowptr[wid], end = rowptr[wid + 1];
    for (int base = beg; base < end; base += 64) {
        int nmax = min(64, end - base);
        int myc = (base + lane < end) ? col[base + lane] : 0;
        int j = 0;
        for (; j + 4 <= nmax; j += 4) {
            int s0 = __shfl(myc, j), s1 = __shfl(myc, j + 1);
            int s2 = __shfl(myc, j + 2), s3 = __shfl(myc, j + 3);
            float w0 = 0.f, w1 = 0.f, w2 = 0.f, w3 = 0.f;
            if (lane < H) {
                float v0 = ssrc[(size_t)s0 * H + lane] + sd;
                float v1 = ssrc[(size_t)s1 * H + lane] + sd;
                float v2 = ssrc[(size_t)s2 * H + lane] + sd;
                float v3 = ssrc[(size_t)s3 * H + lane] + sd;
                v0 = (v0 > 0.f) ? v0 : 0.2f * v0;
                v1 = (v1 > 0.f) ? v1 : 0.2f * v1;
                v2 = (v2 > 0.f) ? v2 : 0.2f * v2;
                v3 = (v3 > 0.f) ? v3 : 0.2f * v3;
                w0 = __expf(v0); w1 = __expf(v1);
                w2 = __expf(v2); w3 = __expf(v3);
                z += (w0 + w1) + (w2 + w3);
            }
            const u32* r0 = (const u32*)(Hm + (size_t)s0 * HC);
            const u32* r1 = (const u32*)(Hm + (size_t)s1 * HC);
            const u32* r2 = (const u32*)(Hm + (size_t)s2 * HC);
            const u32* r3 = (const u32*)(Hm + (size_t)s3 * HC);
#pragma unroll
            for (int k = 0; k < KT; k++) {
                int idx = lane + 64 * k;  // rem round may over-read within pitch: safe
                u32 a0 = r0[idx], a1 = r1[idx], a2 = r2[idx], a3 = r3[idx];
                float wk0 = __shfl(w0, hidx[k]);
                float wk1 = __shfl(w1, hidx[k]);
                float wk2 = __shfl(w2, hidx[k]);
                float wk3 = __shfl(w3, hidx[k]);
                acc[k].x = fmaf(wk0, lo2f(a0), acc[k].x);
                acc[k].y = fmaf(wk0, hi2f(a0), acc[k].y);
                acc[k].x = fmaf(wk1, lo2f(a1), acc[k].x);
                acc[k].y = fmaf(wk1, hi2f(a1), acc[k].y);
                acc[k].x = fmaf(wk2, lo2f(a2), acc[k].x);
                acc[k].y = fmaf(wk2, hi2f(a2), acc[k].y);
                acc[k].x = fmaf(wk3, lo2f(a3), acc[k].x);
                acc[k].y = fmaf(wk3, hi2f(a3), acc[k].y);
            }
        }
        for (; j < nmax; j++) {
            int s0 = __shfl(myc, j);
            float w0 = 0.f;
            if (lane < H) {
                float v = ssrc[(size_t)s0 * H + lane] + sd;
                v = (v > 0.f) ? v : 0.2f * v;
                w0 = __expf(v);
                z += w0;
            }
            const u32* r0 = (const u32*)(Hm + (size_t)s0 * HC);
#pragma unroll
            for (int k = 0; k < KT; k++) {
                int idx = lane + 64 * k;
                u32 a0 = r0[idx];
                float wk0 = __shfl(w0, hidx[k]);
                acc[k].x = fmaf(wk0, lo2f(a0), acc[k].x);
                acc[k].y = fmaf(wk0, hi2f(a0), acc[k].y);
            }
        }
    }
    const float2* bias2 = (const float2*)bias;
    float2* orow = (float2*)(out + (size_t)wid * HC);
#pragma unroll
    for (int k = 0; k < KT; k++) {
        float zk = __shfl(z, hidx[k]);  // all lanes execute shfl
        if (k < KU || lane < REM) {
            int idx = lane + 64 * k;
            float2 b = bias2[idx];
            float inv = 1.0f / (zk + 1e-16f);
            orow[idx] = make_float2(fmaf(acc[k].x, inv, b.x), fmaf(acc[k].y, inv, b.y));
        }
    }
}

// ---------------- small linear: Y[N,NO] = relu(bn(X))[N,K] @ W[K,NO] + b ----------------
template<int K, int NO, int TPR>
__global__ void k_lin(const float* __restrict__ X, const float* __restrict__ W,
                      const float* __restrict__ wb, const float* __restrict__ scale,
                      const float* __restrict__ shift, float* __restrict__ Y) {
    constexpr int KS = K / TPR;  // k per wave-slice
    __shared__ float red[TPR][64][NO];
    int lane = threadIdx.x & 63;
    int wv = __builtin_amdgcn_readfirstlane(threadIdx.x >> 6);  // wave-uniform slice id
    int row = blockIdx.x * 64 + lane;
    int k0 = wv * KS;
    float acc[NO];
#pragma unroll
    for (int c = 0; c < NO; c++) acc[c] = 0.f;
    if (row < N_NODES) {
        const float* xr = X + (size_t)row * K + k0;
        for (int kk = 0; kk < KS; kk += 4) {
            float4 xv = *(const float4*)&xr[kk];
            int k = k0 + kk;
            float x0 = fmaxf(xv.x * scale[k] + shift[k], 0.f);
            float x1 = fmaxf(xv.y * scale[k + 1] + shift[k + 1], 0.f);
            float x2 = fmaxf(xv.z * scale[k + 2] + shift[k + 2], 0.f);
            float x3 = fmaxf(xv.w * scale[k + 3] + shift[k + 3], 0.f);
#pragma unroll
            for (int c = 0; c < NO; c++) {
                acc[c] = fmaf(x0, W[(size_t)k * NO + c],
                         fmaf(x1, W[(size_t)(k + 1) * NO + c],
                         fmaf(x2, W[(size_t)(k + 2) * NO + c],
                         fmaf(x3, W[(size_t)(k + 3) * NO + c], acc[c]))));
            }
        }
    }
#pragma unroll
    for (int c = 0; c < NO; c++) red[wv][lane][c] = acc[c];
    __syncthreads();
    for (int i = threadIdx.x; i < 64 * NO; i += 64 * TPR) {
        int r = i / NO, c = i - r * NO;
        float s = wb[c];
#pragma unroll
        for (int t = 0; t < TPR; t++) s += red[t][r][c];
        int grow = blockIdx.x * 64 + r;
        if (grow < N_NODES) Y[(size_t)grow * NO + c] = s;
    }
}

// ---------------- batchnorm stats: atomic-free per-block partials ----------------
template<int NO>
__global__ void k_bnstats(const float* __restrict__ X, float* __restrict__ psum,
                          float* __restrict__ psumsq) {
    constexpr int BS = (NO >= 256) ? NO : 256;
    constexpr int RPS = BS / NO;
    __shared__ float ls[BS], ls2[BS];
    int c = threadIdx.x % NO;
    int rsub = threadIdx.x / NO;
    constexpr int chunk = (N_NODES + PB - 1) / PB;
    int r0 = blockIdx.x * chunk;
    int r1 = min(N_NODES, r0 + chunk);
    float s = 0.f, s2 = 0.f;
    for (int r = r0 + rsub; r < r1; r += RPS) {
        float v = X[(size_t)r * NO + c];
        s += v;
        s2 += v * v;
    }
    if (RPS > 1) {
        ls[threadIdx.x] = s;
        ls2[threadIdx.x] = s2;
        __syncthreads();
        for (int off = BS / 2; off >= NO; off >>= 1) {
            if (threadIdx.x < off) {
                ls[threadIdx.x] += ls[threadIdx.x + off];
                ls2[threadIdx.x] += ls2[threadIdx.x + off];
            }
            __syncthreads();
        }
        s = ls[threadIdx.x];
        s2 = ls2[threadIdx.x];
    }
    if (rsub == 0) {
        psum[(size_t)blockIdx.x * NO + c] = s;
        psumsq[(size_t)blockIdx.x * NO + c] = s2;
    }
}

__global__ void k_bnfinal(const float* __restrict__ psum, const float* __restrict__ psumsq,
                          const float* __restrict__ g, const float* __restrict__ be,
                          float* __restrict__ scale, float* __restrict__ shift, int NO) {
    int t = threadIdx.x;
    if (t >= NO) return;
    float s = 0.f, s2 = 0.f;
    for (int b = 0; b < PB; b++) {
        s += psum[(size_t)b * NO + t];
        s2 += psumsq[(size_t)b * NO + t];
    }
    float mu = s / (float)N_NODES;
    float var = s2 / (float)N_NODES - mu * mu;
    float sc = g[t] * rsqrtf(var + 1e-5f);
    scale[t] = sc;
    shift[t] = be[t] - mu * sc;
}

// ---------------- pooling ----------------
__global__ void k_bhist(const int* __restrict__ batch, int* __restrict__ cnt) {
    __shared__ int h[G_GRAPHS];
    int tid = threadIdx.x;
    if (tid < G_GRAPHS) h[tid] = 0;
    __syncthreads();
    int i = blockIdx.x * blockDim.x + tid;
    if (i < N_NODES) atomicAdd(&h[batch[i]], 1);
    __syncthreads();
    if (tid < G_GRAPHS) atomicAdd(&cnt[tid], h[tid]);
}

__global__ void k_pool(const float* __restrict__ X, const int* __restrict__ batch,
                       const float* __restrict__ sc, const float* __restrict__ sh,
                       float* __restrict__ pooled) {
    int t = threadIdx.x;  // 384
    const int chunk = (N_NODES + 511) / 512;
    int r0 = blockIdx.x * chunk;
    int r1 = min(N_NODES, r0 + chunk);
    if (r0 >= N_NODES) return;
    float acc = 0.f;
    int cur = batch[r0];
    for (int r = r0; r < r1; r++) {
        int gid = batch[r];
        if (gid != cur) {
            atomicAdd(&pooled[(size_t)cur * 384 + t], acc);
            acc = 0.f;
            cur = gid;
        }
        float v = X[(size_t)r * 384 + t] * sc[t] + sh[t];
        acc += fmaxf(v, 0.f);
    }
    atomicAdd(&pooled[(size_t)cur * 384 + t], acc);
}

__global__ void k_final(const float* __restrict__ pooled, const int* __restrict__ cnt,
                        const float* __restrict__ lwf, const float* __restrict__ lbf,
                        float* __restrict__ out) {
    int t = threadIdx.x;  // 640
    if (t >= G_GRAPHS * 10) return;
    int g = t / 10, c = t - g * 10;
    float inv = 1.0f / fmaxf((float)cnt[g], 1.0f);
    float acc = lbf[c];
    for (int k = 0; k < 384; k++)
        acc = fmaf(pooled[(size_t)g * 384 + k] * inv, lwf[k * 10 + c], acc);
    out[t] = acc;
}

extern "C" void kernel_launch(void* const* d_in, const int* in_sizes, int n_in,
                              void* d_out, int out_size, void* d_ws, size_t ws_size,
                              hipStream_t stream) {
    const float* x    = (const float*)d_in[0];
    const int*   ei   = (const int*)d_in[1];
    const int*   batch= (const int*)d_in[2];
    const float* W1   = (const float*)d_in[3];
    const float* as1  = (const float*)d_in[4];
    const float* ad1  = (const float*)d_in[5];
    const float* b1   = (const float*)d_in[6];
    const float* g1   = (const float*)d_in[7];
    const float* be1  = (const float*)d_in[8];
    const float* lw1  = (const float*)d_in[9];
    const float* lb1  = (const float*)d_in[10];
    const float* gl1  = (const float*)d_in[11];
    const float* bel1 = (const float*)d_in[12];
    const float* W2   = (const float*)d_in[13];
    const float* as2  = (const float*)d_in[14];
    const float* ad2  = (const float*)d_in[15];
    const float* b2   = (const float*)d_in[16];
    const float* g2   = (const float*)d_in[17];
    const float* be2  = (const float*)d_in[18];
    const float* lw2  = (const float*)d_in[19];
    const float* lb2  = (const float*)d_in[20];
    const float* gl2  = (const float*)d_in[21];
    const float* bel2 = (const float*)d_in[22];
    const float* W3   = (const float*)d_in[23];
    const float* as3  = (const float*)d_in[24];
    const float* ad3  = (const float*)d_in[25];
    const float* b3   = (const float*)d_in[26];
    const float* g3   = (const float*)d_in[27];
    const float* be3  = (const float*)d_in[28];
    const float* lwf  = (const float*)d_in[29];
    const float* lbf  = (const float*)d_in[30];
    float* out = (float*)d_out;

    // ---- workspace carve ----
    char* p = (char*)d_ws;
    auto alloc = [&](size_t bytes) {
        char* r = p;
        p += (bytes + 255) & ~(size_t)255;
        return r;
    };
    int*   rowptr = (int*)alloc(4 * (size_t)(N_NODES + 1));
    int*   cursor = (int*)alloc(4 * (size_t)N_NODES);
    int*   deg    = (int*)alloc(4 * (size_t)N_NODES);
    int*   bsum   = (int*)alloc(4 * (size_t)(SCAN_B + 1));
    int*   col    = (int*)alloc(4 * (size_t)TOT_E);
    int*   cdst   = (int*)alloc(4 * (size_t)TOT_E);
    float* ssrc   = (float*)alloc(4 * (size_t)N_NODES * 20);
    float* sdst   = (float*)alloc(4 * (size_t)N_NODES * 20);
    u16*   hbuf   = (u16*)alloc(2 * (size_t)N_NODES * 512);
    float* obuf   = (float*)alloc(4 * (size_t)N_NODES * 512);
    float* xbuf   = (float*)alloc(4 * (size_t)N_NODES * 32);
    float* psum   = (float*)alloc(4 * (size_t)PB * 512);
    float* psumsq = (float*)alloc(4 * (size_t)PB * 512);
    float* scA    = (float*)alloc(4 * 512);
    float* shA    = (float*)alloc(4 * 512);
    float* scB    = (float*)alloc(4 * 64);
    float* shB    = (float*)alloc(4 * 64);
    float* pooled = (float*)alloc(4 * (size_t)G_GRAPHS * 384);
    int*   cnt    = (int*)alloc(4 * G_GRAPHS);

    const int LB = (N_NODES + 63) / 64;   // 782 row-tiles for k_lin
    const int GB = (N_NODES + 31) / 32;   // 1563 row-tiles for k_gemm

    // ---- graph build (reused by all 3 layers) ----
    k_init_deg<<<(N_NODES + 255) / 256, 256, 0, stream>>>(deg);
    k_hist<<<(N_EDGES + 255) / 256, 256, 0, stream>>>(ei, deg);
    k_scan1<<<SCAN_B, 512, 0, stream>>>(deg, rowptr, bsum);
    k_scan2<<<1, 128, 0, stream>>>(bsum);
    k_scan3<<<(N_NODES + 255) / 256, 256, 0, stream>>>(rowptr, cursor, bsum);
    k_scatter<<<(TOT_E + 255) / 256, 256, 0, stream>>>(ei, cursor, col, cdst);
    hipMemsetAsync(pooled, 0, 4 * (size_t)G_GRAPHS * 384 + 256, stream);  // pooled + cnt

    // ---- layer 1: GAT(128 -> 20x16) ----
    k_gemm<128, 320, false><<<GB, 256, 0, stream>>>(x, W1, nullptr, nullptr, hbuf);
    k_scores<20, 16><<<(N_NODES * 20 + 255) / 256, 256, 0, stream>>>(hbuf, as1, ad1, ssrc, sdst);
    k_agg<20, 16><<<(N_NODES + 3) / 4, 256, 0, stream>>>(hbuf, ssrc, sdst, rowptr, col, b1, obuf);
    k_bnstats<320><<<PB, 320, 0, stream>>>(obuf, psum, psumsq);
    k_bnfinal<<<1, 512, 0, stream>>>(psum, psumsq, g1, be1, scA, shA, 320);
    k_lin<320, 16, 4><<<LB, 256, 0, stream>>>(obuf, lw1, lb1, scA, shA, xbuf);
    k_bnstats<16><<<PB, 256, 0, stream>>>(xbuf, psum, psumsq);
    k_bnfinal<<<1, 512, 0, stream>>>(psum, psumsq, gl1, bel1, scB, shB, 16);

    // ---- layer 2: GAT(16 -> 16x32) ----
    k_gemm<16, 512, true><<<GB, 256, 0, stream>>>(xbuf, W2, scB, shB, hbuf);
    k_scores<16, 32><<<(N_NODES * 16 + 255) / 256, 256, 0, stream>>>(hbuf, as2, ad2, ssrc, sdst);
    k_agg<16, 32><<<(N_NODES + 3) / 4, 256, 0, stream>>>(hbuf, ssrc, sdst, rowptr, col, b2, obuf);
    k_bnstats<512><<<PB, 512, 0, stream>>>(obuf, psum, psumsq);
    k_bnfinal<<<1, 512, 0, stream>>>(psum, psumsq, g2, be2, scA, shA, 512);
    k_lin<512, 32, 4><<<LB, 256, 0, stream>>>(obuf, lw2, lb2, scA, shA, xbuf);
    k_bnstats<32><<<PB, 256, 0, stream>>>(xbuf, psum, psumsq);
    k_bnfinal<<<1, 512, 0, stream>>>(psum, psumsq, gl2, bel2, scB, shB, 32);

    // ---- layer 3: GAT(32 -> 8x48) ----
    k_gemm<32, 384, true><<<GB, 256, 0, stream>>>(xbuf, W3, scB, shB, hbuf);
    k_scores<8, 48><<<(N_NODES * 8 + 255) / 256, 256, 0, stream>>>(hbuf, as3, ad3, ssrc, sdst);
    k_agg<8, 48><<<(N_NODES + 3) / 4, 256, 0, stream>>>(hbuf, ssrc, sdst, rowptr, col, b3, obuf);
    k_bnstats<384><<<PB, 384, 0, stream>>>(obuf, psum, psumsq);
    k_bnfinal<<<1, 512, 0, stream>>>(psum, psumsq, g3, be3, scA, shA, 384);

    // ---- pool + classifier ----
    k_bhist<<<(N_NODES + 255) / 256, 256, 0, stream>>>(batch, cnt);
    k_pool<<<512, 384, 0, stream>>>(obuf, batch, scA, shA, pooled);
    k_final<<<1, 640, 0, stream>>>(pooled, cnt, lwf, lbf, out);
}

// Round 14
// 971.307 us; speedup vs baseline: 1.5778x; 1.0365x over previous
//
#include <hip/hip_runtime.h>
#include <cstdint>
#include <cstddef>

#define N_NODES 50000
#define N_EDGES 400000
#define TOT_E   450000
#define G_GRAPHS 64
#define PB 256   // partial blocks for bnstats
#define SCAN_B 98  // scan blocks of 512 (98*512 = 50176 >= N_NODES)

typedef unsigned short u16;
typedef unsigned int u32;

__device__ __forceinline__ float b2f(u16 v) {
    union { u32 u; float f; } x; x.u = ((u32)v) << 16; return x.f;
}
__device__ __forceinline__ float lo2f(u32 u) {
    union { u32 u; float f; } x; x.u = u << 16; return x.f;
}
__device__ __forceinline__ float hi2f(u32 u) {
    union { u32 u; float f; } x; x.u = u & 0xffff0000u; return x.f;
}
__device__ __forceinline__ u16 f2b(float f) {
    union { float f; u32 u; } x; x.f = f;
    u32 r = x.u + 0x7fffu + ((x.u >> 16) & 1u);  // round-nearest-even
    return (u16)(r >> 16);
}
__device__ __forceinline__ u32 pack2(float a, float b) {
    return (u32)f2b(a) | ((u32)f2b(b) << 16);
}

// ---------------- graph build ----------------
__global__ void k_init_deg(int* __restrict__ deg) {
    int i = blockIdx.x * blockDim.x + threadIdx.x;
    if (i < N_NODES) deg[i] = 1;  // self loop
}

__global__ void k_hist(const int* __restrict__ ei, int* __restrict__ deg) {
    int e = blockIdx.x * blockDim.x + threadIdx.x;
    if (e < N_EDGES) atomicAdd(&deg[ei[N_EDGES + e]], 1);
}

// phase 1: block-local exclusive scan, block totals to bsum
__global__ void k_scan1(const int* __restrict__ deg, int* __restrict__ rowptr,
                        int* __restrict__ bsum) {
    __shared__ int buf[512];
    int tid = threadIdx.x;
    int i = blockIdx.x * 512 + tid;
    int v = (i < N_NODES) ? deg[i] : 0;
    buf[tid] = v;
    __syncthreads();
    for (int off = 1; off < 512; off <<= 1) {
        int t = (tid >= off) ? buf[tid - off] : 0;
        __syncthreads();
        buf[tid] += t;
        __syncthreads();
    }
    if (i < N_NODES) rowptr[i] = buf[tid] - v;  // block-local exclusive
    if (tid == 511) bsum[blockIdx.x] = buf[511];
}

// phase 2: exclusive scan of the 98 block sums (single 128-thread block)
__global__ void k_scan2(int* __restrict__ bsum) {
    __shared__ int buf[128];
    int tid = threadIdx.x;
    int v = (tid < SCAN_B) ? bsum[tid] : 0;
    buf[tid] = v;
    __syncthreads();
    for (int off = 1; off < 128; off <<= 1) {
        int t = (tid >= off) ? buf[tid - off] : 0;
        __syncthreads();
        buf[tid] += t;
        __syncthreads();
    }
    if (tid < SCAN_B) bsum[tid] = buf[tid] - v;  // exclusive
}

// phase 3: add block offsets; write cursor; rowptr[N] = TOT_E (statically known)
__global__ void k_scan3(int* __restrict__ rowptr, int* __restrict__ cursor,
                        const int* __restrict__ bsum) {
    int i = blockIdx.x * blockDim.x + threadIdx.x;
    if (i < N_NODES) {
        int v = rowptr[i] + bsum[i >> 9];
        rowptr[i] = v;
        cursor[i] = v;
    }
    if (i == 0) rowptr[N_NODES] = TOT_E;
}

__global__ void k_scatter(const int* __restrict__ ei, int* __restrict__ cursor,
                          int* __restrict__ col, int* __restrict__ cdst) {
    int e = blockIdx.x * blockDim.x + threadIdx.x;
    if (e < N_EDGES) {
        int s = ei[e], d = ei[N_EDGES + e];
        int p = atomicAdd(&cursor[d], 1);
        col[p] = s;
        cdst[p] = d;
    } else if (e < TOT_E) {
        int i = e - N_EDGES;
        int p = atomicAdd(&cursor[i], 1);
        col[p] = i;
        cdst[p] = i;
    }
}

// ---------------- scalar-X GEMM: Y[N,NO] = xform(X)[N,K] @ W[K,NO], bf16 out ----------
template<int K, int NO, bool XFORM>
__global__ __launch_bounds__(256, 2)
void k_gemm(const float* __restrict__ X, const float* __restrict__ W,
            const float* __restrict__ scale, const float* __restrict__ shift,
            u16* __restrict__ Y) {
    constexpr int CPT = NO / 64;
    constexpr int WR = 8;  // rows per wave
    int lane = threadIdx.x & 63;
    int wv = __builtin_amdgcn_readfirstlane((int)(threadIdx.x >> 6));  // wave-uniform
    int rbase = blockIdx.x * 32 + wv * WR;
    float acc[WR][CPT];
#pragma unroll
    for (int r = 0; r < WR; r++)
#pragma unroll
        for (int j = 0; j < CPT; j++) acc[r][j] = 0.f;

    const float* xr[WR];
#pragma unroll
    for (int r = 0; r < WR; r++) {
        int row = rbase + r;
        if (row >= N_NODES) row = N_NODES - 1;  // clamp: bounds-safe uniform loads
        xr[r] = X + (size_t)row * K;
    }

    for (int k = 0; k < K; k += 4) {
        float4 xk[WR];
#pragma unroll
        for (int r = 0; r < WR; r++) xk[r] = *(const float4*)&xr[r][k];
        if (XFORM) {
            float4 sc = *(const float4*)&scale[k];
            float4 sh = *(const float4*)&shift[k];
#pragma unroll
            for (int r = 0; r < WR; r++) {
                xk[r].x = fmaxf(xk[r].x * sc.x + sh.x, 0.f);
                xk[r].y = fmaxf(xk[r].y * sc.y + sh.y, 0.f);
                xk[r].z = fmaxf(xk[r].z * sc.z + sh.z, 0.f);
                xk[r].w = fmaxf(xk[r].w * sc.w + sh.w, 0.f);
            }
        }
#pragma unroll
        for (int kk = 0; kk < 4; kk++) {
            float w[CPT];
#pragma unroll
            for (int j = 0; j < CPT; j++) w[j] = W[(size_t)(k + kk) * NO + lane + 64 * j];
#pragma unroll
            for (int r = 0; r < WR; r++) {
                float xv = (kk == 0) ? xk[r].x : (kk == 1) ? xk[r].y : (kk == 2) ? xk[r].z : xk[r].w;
#pragma unroll
                for (int j = 0; j < CPT; j++) acc[r][j] = fmaf(xv, w[j], acc[r][j]);
            }
        }
    }
#pragma unroll
    for (int r = 0; r < WR; r++) {
        int grow = rbase + r;
        if (grow < N_NODES) {
#pragma unroll
            for (int j = 0; j < CPT; j++)
                Y[(size_t)grow * NO + lane + 64 * j] = f2b(acc[r][j]);
        }
    }
}

// ---------------- attention scores (bf16 input, uint-packed reads) ----------------
template<int H, int C>
__global__ void k_scores(const u16* __restrict__ Hm, const float* __restrict__ asrc,
                         const float* __restrict__ adst, float* __restrict__ ssrc,
                         float* __restrict__ sdst) {
    int t = blockIdx.x * blockDim.x + threadIdx.x;
    if (t >= N_NODES * H) return;
    int i = t / H, h = t - i * H;
    const u32* row = (const u32*)(Hm + (size_t)i * H * C + h * C);
    float s1 = 0.f, s2 = 0.f;
#pragma unroll
    for (int c2 = 0; c2 < C / 2; c2++) {
        u32 u = row[c2];
        float v0 = lo2f(u), v1 = hi2f(u);
        int c = c2 * 2;
        s1 = fmaf(v0, asrc[h * C + c], fmaf(v1, asrc[h * C + c + 1], s1));
        s2 = fmaf(v0, adst[h * C + c], fmaf(v1, adst[h * C + c + 1], s2));
    }
    ssrc[t] = s1;
    sdst[t] = s2;
}

// ---------------- fused edge-softmax + aggregation (u32-packed bf16 gather) ----------
// Output now bf16 (u32-packed pair per store) — halves obuf write + downstream reads.
template<int H, int C>
__global__ void k_agg(const u16* __restrict__ Hm, const float* __restrict__ ssrc,
                      const float* __restrict__ sdst, const int* __restrict__ rowptr,
                      const int* __restrict__ col, const float* __restrict__ bias,
                      u16* __restrict__ out) {
    constexpr int HC = H * C;
    constexpr int HW = HC / 2;            // u32 words per row
    constexpr int KU = HW / 64;           // full word rounds
    constexpr int REM = HW % 64;          // remainder words (lane < REM valid)
    constexpr int KT = KU + (REM ? 1 : 0);
    int wid = (int)((blockIdx.x * blockDim.x + threadIdx.x) >> 6);
    int lane = threadIdx.x & 63;
    if (wid >= N_NODES) return;
    float sd = (lane < H) ? sdst[(size_t)wid * H + lane] : 0.f;
    float2 acc[KT];
    int hidx[KT];
#pragma unroll
    for (int k = 0; k < KT; k++) {
        acc[k] = make_float2(0.f, 0.f);
        hidx[k] = (2 * (lane + 64 * k)) / C;  // head of both packed elements
    }
    float z = 0.f;
    int beg = rowptr[wid], end = rowptr[wid + 1];
    for (int base = beg; base < end; base += 64) {
        int nmax = min(64, end - base);
        int myc = (base + lane < end) ? col[base + lane] : 0;
        int j = 0;
        for (; j + 4 <= nmax; j += 4) {
            int s0 = __shfl(myc, j), s1 = __shfl(myc, j + 1);
            int s2 = __shfl(myc, j + 2), s3 = __shfl(myc, j + 3);
            float w0 = 0.f, w1 = 0.f, w2 = 0.f, w3 = 0.f;
            if (lane < H) {
                float v0 = ssrc[(size_t)s0 * H + lane] + sd;
                float v1 = ssrc[(size_t)s1 * H + lane] + sd;
                float v2 = ssrc[(size_t)s2 * H + lane] + sd;
                float v3 = ssrc[(size_t)s3 * H + lane] + sd;
                v0 = (v0 > 0.f) ? v0 : 0.2f * v0;
                v1 = (v1 > 0.f) ? v1 : 0.2f * v1;
                v2 = (v2 > 0.f) ? v2 : 0.2f * v2;
                v3 = (v3 > 0.f) ? v3 : 0.2f * v3;
                w0 = __expf(v0); w1 = __expf(v1);
                w2 = __expf(v2); w3 = __expf(v3);
                z += (w0 + w1) + (w2 + w3);
            }
            const u32* r0 = (const u32*)(Hm + (size_t)s0 * HC);
            const u32* r1 = (const u32*)(Hm + (size_t)s1 * HC);
            const u32* r2 = (const u32*)(Hm + (size_t)s2 * HC);
            const u32* r3 = (const u32*)(Hm + (size_t)s3 * HC);
#pragma unroll
            for (int k = 0; k < KT; k++) {
                int idx = lane + 64 * k;  // rem round may over-read within pitch: safe
                u32 a0 = r0[idx], a1 = r1[idx], a2 = r2[idx], a3 = r3[idx];
                float wk0 = __shfl(w0, hidx[k]);
                float wk1 = __shfl(w1, hidx[k]);
                float wk2 = __shfl(w2, hidx[k]);
                float wk3 = __shfl(w3, hidx[k]);
                acc[k].x = fmaf(wk0, lo2f(a0), acc[k].x);
                acc[k].y = fmaf(wk0, hi2f(a0), acc[k].y);
                acc[k].x = fmaf(wk1, lo2f(a1), acc[k].x);
                acc[k].y = fmaf(wk1, hi2f(a1), acc[k].y);
                acc[k].x = fmaf(wk2, lo2f(a2), acc[k].x);
                acc[k].y = fmaf(wk2, hi2f(a2), acc[k].y);
                acc[k].x = fmaf(wk3, lo2f(a3), acc[k].x);
                acc[k].y = fmaf(wk3, hi2f(a3), acc[k].y);
            }
        }
        for (; j < nmax; j++) {
            int s0 = __shfl(myc, j);
            float w0 = 0.f;
            if (lane < H) {
                float v = ssrc[(size_t)s0 * H + lane] + sd;
                v = (v > 0.f) ? v : 0.2f * v;
                w0 = __expf(v);
                z += w0;
            }
            const u32* r0 = (const u32*)(Hm + (size_t)s0 * HC);
#pragma unroll
            for (int k = 0; k < KT; k++) {
                int idx = lane + 64 * k;
                u32 a0 = r0[idx];
                float wk0 = __shfl(w0, hidx[k]);
                acc[k].x = fmaf(wk0, lo2f(a0), acc[k].x);
                acc[k].y = fmaf(wk0, hi2f(a0), acc[k].y);
            }
        }
    }
    const float2* bias2 = (const float2*)bias;
    u32* orow = (u32*)(out + (size_t)wid * HC);
#pragma unroll
    for (int k = 0; k < KT; k++) {
        float zk = __shfl(z, hidx[k]);  // all lanes execute shfl
        if (k < KU || lane < REM) {
            int idx = lane + 64 * k;
            float2 b = bias2[idx];
            float inv = 1.0f / (zk + 1e-16f);
            orow[idx] = pack2(fmaf(acc[k].x, inv, b.x), fmaf(acc[k].y, inv, b.y));
        }
    }
}

// ---------------- small linear: Y[N,NO] = relu(bn(X))[N,K] @ W[K,NO] + b ----------------
// X is bf16 (u32-packed reads).
template<int K, int NO, int TPR>
__global__ void k_lin(const u16* __restrict__ X, const float* __restrict__ W,
                      const float* __restrict__ wb, const float* __restrict__ scale,
                      const float* __restrict__ shift, float* __restrict__ Y) {
    constexpr int KS = K / TPR;  // k per wave-slice (even)
    __shared__ float red[TPR][64][NO];
    int lane = threadIdx.x & 63;
    int wv = __builtin_amdgcn_readfirstlane(threadIdx.x >> 6);  // wave-uniform slice id
    int row = blockIdx.x * 64 + lane;
    int k0 = wv * KS;
    float acc[NO];
#pragma unroll
    for (int c = 0; c < NO; c++) acc[c] = 0.f;
    if (row < N_NODES) {
        const u32* xr = (const u32*)(X + (size_t)row * K) + (k0 >> 1);
        for (int kk = 0; kk < KS; kk += 4) {
            u32 a = xr[(kk >> 1)];
            u32 b = xr[(kk >> 1) + 1];
            int k = k0 + kk;
            float x0 = fmaxf(lo2f(a) * scale[k] + shift[k], 0.f);
            float x1 = fmaxf(hi2f(a) * scale[k + 1] + shift[k + 1], 0.f);
            float x2 = fmaxf(lo2f(b) * scale[k + 2] + shift[k + 2], 0.f);
            float x3 = fmaxf(hi2f(b) * scale[k + 3] + shift[k + 3], 0.f);
#pragma unroll
            for (int c = 0; c < NO; c++) {
                acc[c] = fmaf(x0, W[(size_t)k * NO + c],
                         fmaf(x1, W[(size_t)(k + 1) * NO + c],
                         fmaf(x2, W[(size_t)(k + 2) * NO + c],
                         fmaf(x3, W[(size_t)(k + 3) * NO + c], acc[c]))));
            }
        }
    }
#pragma unroll
    for (int c = 0; c < NO; c++) red[wv][lane][c] = acc[c];
    __syncthreads();
    for (int i = threadIdx.x; i < 64 * NO; i += 64 * TPR) {
        int r = i / NO, c = i - r * NO;
        float s = wb[c];
#pragma unroll
        for (int t = 0; t < TPR; t++) s += red[t][r][c];
        int grow = blockIdx.x * 64 + r;
        if (grow < N_NODES) Y[(size_t)grow * NO + c] = s;
    }
}

// ---------------- batchnorm stats over bf16 input: atomic-free per-block partials ----
template<int NO>
__global__ void k_bnstats(const u16* __restrict__ X, float* __restrict__ psum,
                          float* __restrict__ psumsq) {
    constexpr int BS = (NO >= 256) ? NO : 256;
    constexpr int RPS = BS / NO;
    __shared__ float ls[BS], ls2[BS];
    int c = threadIdx.x % NO;
    int rsub = threadIdx.x / NO;
    constexpr int chunk = (N_NODES + PB - 1) / PB;
    int r0 = blockIdx.x * chunk;
    int r1 = min(N_NODES, r0 + chunk);
    float s = 0.f, s2 = 0.f;
    for (int r = r0 + rsub; r < r1; r += RPS) {
        float v = b2f(X[(size_t)r * NO + c]);
        s += v;
        s2 += v * v;
    }
    if (RPS > 1) {
        ls[threadIdx.x] = s;
        ls2[threadIdx.x] = s2;
        __syncthreads();
        for (int off = BS / 2; off >= NO; off >>= 1) {
            if (threadIdx.x < off) {
                ls[threadIdx.x] += ls[threadIdx.x + off];
                ls2[threadIdx.x] += ls2[threadIdx.x + off];
            }
            __syncthreads();
        }
        s = ls[threadIdx.x];
        s2 = ls2[threadIdx.x];
    }
    if (rsub == 0) {
        psum[(size_t)blockIdx.x * NO + c] = s;
        psumsq[(size_t)blockIdx.x * NO + c] = s2;
    }
}

// fp32-input variant (for k_lin outputs)
template<int NO>
__global__ void k_bnstatsf(const float* __restrict__ X, float* __restrict__ psum,
                           float* __restrict__ psumsq) {
    constexpr int BS = (NO >= 256) ? NO : 256;
    constexpr int RPS = BS / NO;
    __shared__ float ls[BS], ls2[BS];
    int c = threadIdx.x % NO;
    int rsub = threadIdx.x / NO;
    constexpr int chunk = (N_NODES + PB - 1) / PB;
    int r0 = blockIdx.x * chunk;
    int r1 = min(N_NODES, r0 + chunk);
    float s = 0.f, s2 = 0.f;
    for (int r = r0 + rsub; r < r1; r += RPS) {
        float v = X[(size_t)r * NO + c];
        s += v;
        s2 += v * v;
    }
    if (RPS > 1) {
        ls[threadIdx.x] = s;
        ls2[threadIdx.x] = s2;
        __syncthreads();
        for (int off = BS / 2; off >= NO; off >>= 1) {
            if (threadIdx.x < off) {
                ls[threadIdx.x] += ls[threadIdx.x + off];
                ls2[threadIdx.x] += ls2[threadIdx.x + off];
            }
            __syncthreads();
        }
        s = ls[threadIdx.x];
        s2 = ls2[threadIdx.x];
    }
    if (rsub == 0) {
        psum[(size_t)blockIdx.x * NO + c] = s;
        psumsq[(size_t)blockIdx.x * NO + c] = s2;
    }
}

__global__ void k_bnfinal(const float* __restrict__ psum, const float* __restrict__ psumsq,
                          const float* __restrict__ g, const float* __restrict__ be,
                          float* __restrict__ scale, float* __restrict__ shift, int NO) {
    int t = threadIdx.x;
    if (t >= NO) return;
    float s = 0.f, s2 = 0.f;
    for (int b = 0; b < PB; b++) {
        s += psum[(size_t)b * NO + t];
        s2 += psumsq[(size_t)b * NO + t];
    }
    float mu = s / (float)N_NODES;
    float var = s2 / (float)N_NODES - mu * mu;
    float sc = g[t] * rsqrtf(var + 1e-5f);
    scale[t] = sc;
    shift[t] = be[t] - mu * sc;
}

// ---------------- pooling (bf16 input) ----------------
__global__ void k_bhist(const int* __restrict__ batch, int* __restrict__ cnt) {
    __shared__ int h[G_GRAPHS];
    int tid = threadIdx.x;
    if (tid < G_GRAPHS) h[tid] = 0;
    __syncthreads();
    int i = blockIdx.x * blockDim.x + tid;
    if (i < N_NODES) atomicAdd(&h[batch[i]], 1);
    __syncthreads();
    if (tid < G_GRAPHS) atomicAdd(&cnt[tid], h[tid]);
}

__global__ void k_pool(const u16* __restrict__ X, const int* __restrict__ batch,
                       const float* __restrict__ sc, const float* __restrict__ sh,
                       float* __restrict__ pooled) {
    int t = threadIdx.x;  // 384
    const int chunk = (N_NODES + 511) / 512;
    int r0 = blockIdx.x * chunk;
    int r1 = min(N_NODES, r0 + chunk);
    if (r0 >= N_NODES) return;
    float acc = 0.f;
    int cur = batch[r0];
    for (int r = r0; r < r1; r++) {
        int gid = batch[r];
        if (gid != cur) {
            atomicAdd(&pooled[(size_t)cur * 384 + t], acc);
            acc = 0.f;
            cur = gid;
        }
        float v = b2f(X[(size_t)r * 384 + t]) * sc[t] + sh[t];
        acc += fmaxf(v, 0.f);
    }
    atomicAdd(&pooled[(size_t)cur * 384 + t], acc);
}

__global__ void k_final(const float* __restrict__ pooled, const int* __restrict__ cnt,
                        const float* __restrict__ lwf, const float* __restrict__ lbf,
                        float* __restrict__ out) {
    int t = threadIdx.x;  // 640
    if (t >= G_GRAPHS * 10) return;
    int g = t / 10, c = t - g * 10;
    float inv = 1.0f / fmaxf((float)cnt[g], 1.0f);
    float acc = lbf[c];
    for (int k = 0; k < 384; k++)
        acc = fmaf(pooled[(size_t)g * 384 + k] * inv, lwf[k * 10 + c], acc);
    out[t] = acc;
}

extern "C" void kernel_launch(void* const* d_in, const int* in_sizes, int n_in,
                              void* d_out, int out_size, void* d_ws, size_t ws_size,
                              hipStream_t stream) {
    const float* x    = (const float*)d_in[0];
    const int*   ei   = (const int*)d_in[1];
    const int*   batch= (const int*)d_in[2];
    const float* W1   = (const float*)d_in[3];
    const float* as1  = (const float*)d_in[4];
    const float* ad1  = (const float*)d_in[5];
    const float* b1   = (const float*)d_in[6];
    const float* g1   = (const float*)d_in[7];
    const float* be1  = (const float*)d_in[8];
    const float* lw1  = (const float*)d_in[9];
    const float* lb1  = (const float*)d_in[10];
    const float* gl1  = (const float*)d_in[11];
    const float* bel1 = (const float*)d_in[12];
    const float* W2   = (const float*)d_in[13];
    const float* as2  = (const float*)d_in[14];
    const float* ad2  = (const float*)d_in[15];
    const float* b2   = (const float*)d_in[16];
    const float* g2   = (const float*)d_in[17];
    const float* be2  = (const float*)d_in[18];
    const float* lw2  = (const float*)d_in[19];
    const float* lb2  = (const float*)d_in[20];
    const float* gl2  = (const float*)d_in[21];
    const float* bel2 = (const float*)d_in[22];
    const float* W3   = (const float*)d_in[23];
    const float* as3  = (const float*)d_in[24];
    const float* ad3  = (const float*)d_in[25];
    const float* b3   = (const float*)d_in[26];
    const float* g3   = (const float*)d_in[27];
    const float* be3  = (const float*)d_in[28];
    const float* lwf  = (const float*)d_in[29];
    const float* lbf  = (const float*)d_in[30];
    float* out = (float*)d_out;

    // ---- workspace carve ----
    char* p = (char*)d_ws;
    auto alloc = [&](size_t bytes) {
        char* r = p;
        p += (bytes + 255) & ~(size_t)255;
        return r;
    };
    int*   rowptr = (int*)alloc(4 * (size_t)(N_NODES + 1));
    int*   cursor = (int*)alloc(4 * (size_t)N_NODES);
    int*   deg    = (int*)alloc(4 * (size_t)N_NODES);
    int*   bsum   = (int*)alloc(4 * (size_t)(SCAN_B + 1));
    int*   col    = (int*)alloc(4 * (size_t)TOT_E);
    int*   cdst   = (int*)alloc(4 * (size_t)TOT_E);
    float* ssrc   = (float*)alloc(4 * (size_t)N_NODES * 20);
    float* sdst   = (float*)alloc(4 * (size_t)N_NODES * 20);
    u16*   hbuf   = (u16*)alloc(2 * (size_t)N_NODES * 512);
    u16*   obuf   = (u16*)alloc(2 * (size_t)N_NODES * 512);
    float* xbuf   = (float*)alloc(4 * (size_t)N_NODES * 32);
    float* psum   = (float*)alloc(4 * (size_t)PB * 512);
    float* psumsq = (float*)alloc(4 * (size_t)PB * 512);
    float* scA    = (float*)alloc(4 * 512);
    float* shA    = (float*)alloc(4 * 512);
    float* scB    = (float*)alloc(4 * 64);
    float* shB    = (float*)alloc(4 * 64);
    float* pooled = (float*)alloc(4 * (size_t)G_GRAPHS * 384);
    int*   cnt    = (int*)alloc(4 * G_GRAPHS);

    const int LB = (N_NODES + 63) / 64;   // 782 row-tiles for k_lin
    const int GB = (N_NODES + 31) / 32;   // 1563 row-tiles for k_gemm

    // ---- graph build (reused by all 3 layers) ----
    k_init_deg<<<(N_NODES + 255) / 256, 256, 0, stream>>>(deg);
    k_hist<<<(N_EDGES + 255) / 256, 256, 0, stream>>>(ei, deg);
    k_scan1<<<SCAN_B, 512, 0, stream>>>(deg, rowptr, bsum);
    k_scan2<<<1, 128, 0, stream>>>(bsum);
    k_scan3<<<(N_NODES + 255) / 256, 256, 0, stream>>>(rowptr, cursor, bsum);
    k_scatter<<<(TOT_E + 255) / 256, 256, 0, stream>>>(ei, cursor, col, cdst);
    hipMemsetAsync(pooled, 0, 4 * (size_t)G_GRAPHS * 384 + 256, stream);  // pooled + cnt

    // ---- layer 1: GAT(128 -> 20x16) ----
    k_gemm<128, 320, false><<<GB, 256, 0, stream>>>(x, W1, nullptr, nullptr, hbuf);
    k_scores<20, 16><<<(N_NODES * 20 + 255) / 256, 256, 0, stream>>>(hbuf, as1, ad1, ssrc, sdst);
    k_agg<20, 16><<<(N_NODES + 3) / 4, 256, 0, stream>>>(hbuf, ssrc, sdst, rowptr, col, b1, obuf);
    k_bnstats<320><<<PB, 320, 0, stream>>>(obuf, psum, psumsq);
    k_bnfinal<<<1, 512, 0, stream>>>(psum, psumsq, g1, be1, scA, shA, 320);
    k_lin<320, 16, 4><<<LB, 256, 0, stream>>>(obuf, lw1, lb1, scA, shA, xbuf);
    k_bnstatsf<16><<<PB, 256, 0, stream>>>(xbuf, psum, psumsq);
    k_bnfinal<<<1, 512, 0, stream>>>(psum, psumsq, gl1, bel1, scB, shB, 16);

    // ---- layer 2: GAT(16 -> 16x32) ----
    k_gemm<16, 512, true><<<GB, 256, 0, stream>>>(xbuf, W2, scB, shB, hbuf);
    k_scores<16, 32><<<(N_NODES * 16 + 255) / 256, 256, 0, stream>>>(hbuf, as2, ad2, ssrc, sdst);
    k_agg<16, 32><<<(N_NODES + 3) / 4, 256, 0, stream>>>(hbuf, ssrc, sdst, rowptr, col, b2, obuf);
    k_bnstats<512><<<PB, 512, 0, stream>>>(obuf, psum, psumsq);
    k_bnfinal<<<1, 512, 0, stream>>>(psum, psumsq, g2, be2, scA, shA, 512);
    k_lin<512, 32, 4><<<LB, 256, 0, stream>>>(obuf, lw2, lb2, scA, shA, xbuf);
    k_bnstatsf<32><<<PB, 256, 0, stream>>>(xbuf, psum, psumsq);
    k_bnfinal<<<1, 512, 0, stream>>>(psum, psumsq, gl2, bel2, scB, shB, 32);

    // ---- layer 3: GAT(32 -> 8x48) ----
    k_gemm<32, 384, true><<<GB, 256, 0, stream>>>(xbuf, W3, scB, shB, hbuf);
    k_scores<8, 48><<<(N_NODES * 8 + 255) / 256, 256, 0, stream>>>(hbuf, as3, ad3, ssrc, sdst);
    k_agg<8, 48><<<(N_NODES + 3) / 4, 256, 0, stream>>>(hbuf, ssrc, sdst, rowptr, col, b3, obuf);
    k_bnstats<384><<<PB, 384, 0, stream>>>(obuf, psum, psumsq);
    k_bnfinal<<<1, 512, 0, stream>>>(psum, psumsq, g3, be3, scA, shA, 384);

    // ---- pool + classifier ----
    k_bhist<<<(N_NODES + 255) / 256, 256, 0, stream>>>(batch, cnt);
    k_pool<<<512, 384, 0, stream>>>(obuf, batch, scA, shA, pooled);
    k_final<<<1, 640, 0, stream>>>(pooled, cnt, lwf, lbf, out);
}

// Round 15
// 908.158 us; speedup vs baseline: 1.6875x; 1.0695x over previous
//
#include <hip/hip_runtime.h>
#include <cstdint>
#include <cstddef>

#define N_NODES 50000
#define N_EDGES 400000
#define TOT_E   450000
#define G_GRAPHS 64
#define PB 256   // partial blocks for bnstats
#define SCAN_B 98  // scan blocks of 512 (98*512 = 50176 >= N_NODES)

typedef unsigned short u16;
typedef unsigned int u32;
typedef __attribute__((ext_vector_type(8))) short s16x8;  // 8 bf16 (4 VGPRs)
typedef __attribute__((ext_vector_type(4))) float f32x4;  // MFMA accumulator

__device__ __forceinline__ float b2f(u16 v) {
    union { u32 u; float f; } x; x.u = ((u32)v) << 16; return x.f;
}
__device__ __forceinline__ float lo2f(u32 u) {
    union { u32 u; float f; } x; x.u = u << 16; return x.f;
}
__device__ __forceinline__ float hi2f(u32 u) {
    union { u32 u; float f; } x; x.u = u & 0xffff0000u; return x.f;
}
__device__ __forceinline__ u16 f2b(float f) {
    union { float f; u32 u; } x; x.f = f;
    u32 r = x.u + 0x7fffu + ((x.u >> 16) & 1u);  // round-nearest-even
    return (u16)(r >> 16);
}
__device__ __forceinline__ u32 pack2(float a, float b) {
    return (u32)f2b(a) | ((u32)f2b(b) << 16);
}

// ---------------- graph build ----------------
__global__ void k_init_deg(int* __restrict__ deg) {
    int i = blockIdx.x * blockDim.x + threadIdx.x;
    if (i < N_NODES) deg[i] = 1;  // self loop
}

__global__ void k_hist(const int* __restrict__ ei, int* __restrict__ deg) {
    int e = blockIdx.x * blockDim.x + threadIdx.x;
    if (e < N_EDGES) atomicAdd(&deg[ei[N_EDGES + e]], 1);
}

// phase 1: block-local exclusive scan, block totals to bsum
__global__ void k_scan1(const int* __restrict__ deg, int* __restrict__ rowptr,
                        int* __restrict__ bsum) {
    __shared__ int buf[512];
    int tid = threadIdx.x;
    int i = blockIdx.x * 512 + tid;
    int v = (i < N_NODES) ? deg[i] : 0;
    buf[tid] = v;
    __syncthreads();
    for (int off = 1; off < 512; off <<= 1) {
        int t = (tid >= off) ? buf[tid - off] : 0;
        __syncthreads();
        buf[tid] += t;
        __syncthreads();
    }
    if (i < N_NODES) rowptr[i] = buf[tid] - v;  // block-local exclusive
    if (tid == 511) bsum[blockIdx.x] = buf[511];
}

// phase 2: exclusive scan of the 98 block sums (single 128-thread block)
__global__ void k_scan2(int* __restrict__ bsum) {
    __shared__ int buf[128];
    int tid = threadIdx.x;
    int v = (tid < SCAN_B) ? bsum[tid] : 0;
    buf[tid] = v;
    __syncthreads();
    for (int off = 1; off < 128; off <<= 1) {
        int t = (tid >= off) ? buf[tid - off] : 0;
        __syncthreads();
        buf[tid] += t;
        __syncthreads();
    }
    if (tid < SCAN_B) bsum[tid] = buf[tid] - v;  // exclusive
}

// phase 3: add block offsets; write cursor; rowptr[N] = TOT_E (statically known)
__global__ void k_scan3(int* __restrict__ rowptr, int* __restrict__ cursor,
                        const int* __restrict__ bsum) {
    int i = blockIdx.x * blockDim.x + threadIdx.x;
    if (i < N_NODES) {
        int v = rowptr[i] + bsum[i >> 9];
        rowptr[i] = v;
        cursor[i] = v;
    }
    if (i == 0) rowptr[N_NODES] = TOT_E;
}

__global__ void k_scatter(const int* __restrict__ ei, int* __restrict__ cursor,
                          int* __restrict__ col, int* __restrict__ cdst) {
    int e = blockIdx.x * blockDim.x + threadIdx.x;
    if (e < N_EDGES) {
        int s = ei[e], d = ei[N_EDGES + e];
        int p = atomicAdd(&cursor[d], 1);
        col[p] = s;
        cdst[p] = d;
    } else if (e < TOT_E) {
        int i = e - N_EDGES;
        int p = atomicAdd(&cursor[i], 1);
        col[p] = i;
        cdst[p] = i;
    }
}

// ---------------- W pack: fp32 [K][NO] -> bf16 B-fragment layout ----------------
// Bp[((c*NT + t)*64 + lane)*8 + j] = W[c*32 + (lane>>4)*8 + j][t*16 + (lane&15)]
// (zero-padded for k >= K). One thread per (c,t,lane); writes 16 B contiguous.
template<int K, int NO>
__global__ void k_wpack(const float* __restrict__ W, u16* __restrict__ Bp) {
    constexpr int KC = (K + 31) / 32;
    constexpr int NT = NO / 16;
    int idx = blockIdx.x * 256 + threadIdx.x;
    if (idx >= KC * NT * 64) return;
    int lane = idx & 63;
    int t = (idx >> 6) % NT;
    int c = (idx >> 6) / NT;
    int n = t * 16 + (lane & 15);
    int kbase = c * 32 + (lane >> 4) * 8;
    u16 v[8];
#pragma unroll
    for (int j = 0; j < 8; j++) {
        int k = kbase + j;
        v[j] = (k < K) ? f2b(W[(size_t)k * NO + n]) : (u16)0;
    }
    *(uint4*)(Bp + (size_t)idx * 8) = *(const uint4*)v;
}

// ---------------- MFMA GEMM: Y[N,NO] = xform(X)[N,K] @ W[K,NO], bf16 out ------------
// 16x16x32 bf16 MFMA. Each wave: 16-row stripe x all NO cols; A frag built from
// fp32 X (XFORM fused) per verified layout A[m=lane&15][k=quad*8+j]; B frags from
// packed Bp (one 16B coalesced load each); C/D per m89 layout col=lane&15,
// row=quad*4+reg. K=16 zero-pads to one K=32 chunk.
template<int K, int NO, bool XFORM>
__global__ __launch_bounds__(256, 2)
void k_gemm(const float* __restrict__ X, const u16* __restrict__ Bp,
            const float* __restrict__ scale, const float* __restrict__ shift,
            u16* __restrict__ Y) {
    constexpr int KC = (K + 31) / 32;
    constexpr int NT = NO / 16;
    int lane = threadIdx.x & 63;
    int wv = __builtin_amdgcn_readfirstlane((int)(threadIdx.x >> 6));
    int rbase = blockIdx.x * 64 + wv * 16;
    int m = lane & 15, quad = lane >> 4;
    int arow = rbase + m;
    if (arow >= N_NODES) arow = N_NODES - 1;  // clamp; stores guarded
    const float* xr = X + (size_t)arow * K;

    f32x4 acc[NT];
#pragma unroll
    for (int t = 0; t < NT; t++) acc[t] = (f32x4){0.f, 0.f, 0.f, 0.f};

    for (int c = 0; c < KC; c++) {
        int kbase = c * 32 + quad * 8;
        float xv[8];
        if (kbase < K) {
            float4 va = *(const float4*)&xr[kbase];
            float4 vb = *(const float4*)&xr[kbase + 4];
            xv[0] = va.x; xv[1] = va.y; xv[2] = va.z; xv[3] = va.w;
            xv[4] = vb.x; xv[5] = vb.y; xv[6] = vb.z; xv[7] = vb.w;
            if (XFORM) {
                float4 sa = *(const float4*)&scale[kbase];
                float4 sb = *(const float4*)&scale[kbase + 4];
                float4 ha = *(const float4*)&shift[kbase];
                float4 hb = *(const float4*)&shift[kbase + 4];
                xv[0] = fmaxf(xv[0] * sa.x + ha.x, 0.f);
                xv[1] = fmaxf(xv[1] * sa.y + ha.y, 0.f);
                xv[2] = fmaxf(xv[2] * sa.z + ha.z, 0.f);
                xv[3] = fmaxf(xv[3] * sa.w + ha.w, 0.f);
                xv[4] = fmaxf(xv[4] * sb.x + hb.x, 0.f);
                xv[5] = fmaxf(xv[5] * sb.y + hb.y, 0.f);
                xv[6] = fmaxf(xv[6] * sb.z + hb.z, 0.f);
                xv[7] = fmaxf(xv[7] * sb.w + hb.w, 0.f);
            }
        } else {
#pragma unroll
            for (int j = 0; j < 8; j++) xv[j] = 0.f;
        }
        s16x8 a;
#pragma unroll
        for (int j = 0; j < 8; j++) a[j] = (short)f2b(xv[j]);

        const u16* bp = Bp + (size_t)(c * NT) * 64 * 8;
#pragma unroll
        for (int t = 0; t < NT; t++) {
            s16x8 b = *(const s16x8*)(bp + ((size_t)(t * 64 + lane)) * 8);
            acc[t] = __builtin_amdgcn_mfma_f32_16x16x32_bf16(a, b, acc[t], 0, 0, 0);
        }
    }

#pragma unroll
    for (int t = 0; t < NT; t++) {
        int colb = t * 16 + m;
#pragma unroll
        for (int i = 0; i < 4; i++) {
            int grow = rbase + quad * 4 + i;
            if (grow < N_NODES) Y[(size_t)grow * NO + colb] = f2b(acc[t][i]);
        }
    }
}

// ---------------- attention scores (bf16 input, uint-packed reads) ----------------
template<int H, int C>
__global__ void k_scores(const u16* __restrict__ Hm, const float* __restrict__ asrc,
                         const float* __restrict__ adst, float* __restrict__ ssrc,
                         float* __restrict__ sdst) {
    int t = blockIdx.x * blockDim.x + threadIdx.x;
    if (t >= N_NODES * H) return;
    int i = t / H, h = t - i * H;
    const u32* row = (const u32*)(Hm + (size_t)i * H * C + h * C);
    float s1 = 0.f, s2 = 0.f;
#pragma unroll
    for (int c2 = 0; c2 < C / 2; c2++) {
        u32 u = row[c2];
        float v0 = lo2f(u), v1 = hi2f(u);
        int c = c2 * 2;
        s1 = fmaf(v0, asrc[h * C + c], fmaf(v1, asrc[h * C + c + 1], s1));
        s2 = fmaf(v0, adst[h * C + c], fmaf(v1, adst[h * C + c + 1], s2));
    }
    ssrc[t] = s1;
    sdst[t] = s2;
}

// ---------------- fused edge-softmax + aggregation (u32-packed bf16 gather) ----------
template<int H, int C>
__global__ void k_agg(const u16* __restrict__ Hm, const float* __restrict__ ssrc,
                      const float* __restrict__ sdst, const int* __restrict__ rowptr,
                      const int* __restrict__ col, const float* __restrict__ bias,
                      u16* __restrict__ out) {
    constexpr int HC = H * C;
    constexpr int HW = HC / 2;            // u32 words per row
    constexpr int KU = HW / 64;           // full word rounds
    constexpr int REM = HW % 64;          // remainder words (lane < REM valid)
    constexpr int KT = KU + (REM ? 1 : 0);
    int wid = (int)((blockIdx.x * blockDim.x + threadIdx.x) >> 6);
    int lane = threadIdx.x & 63;
    if (wid >= N_NODES) return;
    float sd = (lane < H) ? sdst[(size_t)wid * H + lane] : 0.f;
    float2 acc[KT];
    int hidx[KT];
#pragma unroll
    for (int k = 0; k < KT; k++) {
        acc[k] = make_float2(0.f, 0.f);
        hidx[k] = (2 * (lane + 64 * k)) / C;  // head of both packed elements
    }
    float z = 0.f;
    int beg = rowptr[wid], end = rowptr[wid + 1];
    for (int base = beg; base < end; base += 64) {
        int nmax = min(64, end - base);
        int myc = (base + lane < end) ? col[base + lane] : 0;
        int j = 0;
        for (; j + 4 <= nmax; j += 4) {
            int s0 = __shfl(myc, j), s1 = __shfl(myc, j + 1);
            int s2 = __shfl(myc, j + 2), s3 = __shfl(myc, j + 3);
            float w0 = 0.f, w1 = 0.f, w2 = 0.f, w3 = 0.f;
            if (lane < H) {
                float v0 = ssrc[(size_t)s0 * H + lane] + sd;
                float v1 = ssrc[(size_t)s1 * H + lane] + sd;
                float v2 = ssrc[(size_t)s2 * H + lane] + sd;
                float v3 = ssrc[(size_t)s3 * H + lane] + sd;
                v0 = (v0 > 0.f) ? v0 : 0.2f * v0;
                v1 = (v1 > 0.f) ? v1 : 0.2f * v1;
                v2 = (v2 > 0.f) ? v2 : 0.2f * v2;
                v3 = (v3 > 0.f) ? v3 : 0.2f * v3;
                w0 = __expf(v0); w1 = __expf(v1);
                w2 = __expf(v2); w3 = __expf(v3);
                z += (w0 + w1) + (w2 + w3);
            }
            const u32* r0 = (const u32*)(Hm + (size_t)s0 * HC);
            const u32* r1 = (const u32*)(Hm + (size_t)s1 * HC);
            const u32* r2 = (const u32*)(Hm + (size_t)s2 * HC);
            const u32* r3 = (const u32*)(Hm + (size_t)s3 * HC);
#pragma unroll
            for (int k = 0; k < KT; k++) {
                int idx = lane + 64 * k;  // rem round may over-read within pitch: safe
                u32 a0 = r0[idx], a1 = r1[idx], a2 = r2[idx], a3 = r3[idx];
                float wk0 = __shfl(w0, hidx[k]);
                float wk1 = __shfl(w1, hidx[k]);
                float wk2 = __shfl(w2, hidx[k]);
                float wk3 = __shfl(w3, hidx[k]);
                acc[k].x = fmaf(wk0, lo2f(a0), acc[k].x);
                acc[k].y = fmaf(wk0, hi2f(a0), acc[k].y);
                acc[k].x = fmaf(wk1, lo2f(a1), acc[k].x);
                acc[k].y = fmaf(wk1, hi2f(a1), acc[k].y);
                acc[k].x = fmaf(wk2, lo2f(a2), acc[k].x);
                acc[k].y = fmaf(wk2, hi2f(a2), acc[k].y);
                acc[k].x = fmaf(wk3, lo2f(a3), acc[k].x);
                acc[k].y = fmaf(wk3, hi2f(a3), acc[k].y);
            }
        }
        for (; j < nmax; j++) {
            int s0 = __shfl(myc, j);
            float w0 = 0.f;
            if (lane < H) {
                float v = ssrc[(size_t)s0 * H + lane] + sd;
                v = (v > 0.f) ? v : 0.2f * v;
                w0 = __expf(v);
                z += w0;
            }
            const u32* r0 = (const u32*)(Hm + (size_t)s0 * HC);
#pragma unroll
            for (int k = 0; k < KT; k++) {
                int idx = lane + 64 * k;
                u32 a0 = r0[idx];
                float wk0 = __shfl(w0, hidx[k]);
                acc[k].x = fmaf(wk0, lo2f(a0), acc[k].x);
                acc[k].y = fmaf(wk0, hi2f(a0), acc[k].y);
            }
        }
    }
    const float2* bias2 = (const float2*)bias;
    u32* orow = (u32*)(out + (size_t)wid * HC);
#pragma unroll
    for (int k = 0; k < KT; k++) {
        float zk = __shfl(z, hidx[k]);  // all lanes execute shfl
        if (k < KU || lane < REM) {
            int idx = lane + 64 * k;
            float2 b = bias2[idx];
            float inv = 1.0f / (zk + 1e-16f);
            orow[idx] = pack2(fmaf(acc[k].x, inv, b.x), fmaf(acc[k].y, inv, b.y));
        }
    }
}

// ---------------- small linear: Y[N,NO] = relu(bn(X))[N,K] @ W[K,NO] + b ----------------
// X is bf16 (u32-packed reads).
template<int K, int NO, int TPR>
__global__ void k_lin(const u16* __restrict__ X, const float* __restrict__ W,
                      const float* __restrict__ wb, const float* __restrict__ scale,
                      const float* __restrict__ shift, float* __restrict__ Y) {
    constexpr int KS = K / TPR;  // k per wave-slice (even)
    __shared__ float red[TPR][64][NO];
    int lane = threadIdx.x & 63;
    int wv = __builtin_amdgcn_readfirstlane(threadIdx.x >> 6);  // wave-uniform slice id
    int row = blockIdx.x * 64 + lane;
    int k0 = wv * KS;
    float acc[NO];
#pragma unroll
    for (int c = 0; c < NO; c++) acc[c] = 0.f;
    if (row < N_NODES) {
        const u32* xr = (const u32*)(X + (size_t)row * K) + (k0 >> 1);
        for (int kk = 0; kk < KS; kk += 4) {
            u32 a = xr[(kk >> 1)];
            u32 b = xr[(kk >> 1) + 1];
            int k = k0 + kk;
            float x0 = fmaxf(lo2f(a) * scale[k] + shift[k], 0.f);
            float x1 = fmaxf(hi2f(a) * scale[k + 1] + shift[k + 1], 0.f);
            float x2 = fmaxf(lo2f(b) * scale[k + 2] + shift[k + 2], 0.f);
            float x3 = fmaxf(hi2f(b) * scale[k + 3] + shift[k + 3], 0.f);
#pragma unroll
            for (int c = 0; c < NO; c++) {
                acc[c] = fmaf(x0, W[(size_t)k * NO + c],
                         fmaf(x1, W[(size_t)(k + 1) * NO + c],
                         fmaf(x2, W[(size_t)(k + 2) * NO + c],
                         fmaf(x3, W[(size_t)(k + 3) * NO + c], acc[c]))));
            }
        }
    }
#pragma unroll
    for (int c = 0; c < NO; c++) red[wv][lane][c] = acc[c];
    __syncthreads();
    for (int i = threadIdx.x; i < 64 * NO; i += 64 * TPR) {
        int r = i / NO, c = i - r * NO;
        float s = wb[c];
#pragma unroll
        for (int t = 0; t < TPR; t++) s += red[t][r][c];
        int grow = blockIdx.x * 64 + r;
        if (grow < N_NODES) Y[(size_t)grow * NO + c] = s;
    }
}

// ---------------- batchnorm stats over bf16 input: atomic-free per-block partials ----
template<int NO>
__global__ void k_bnstats(const u16* __restrict__ X, float* __restrict__ psum,
                          float* __restrict__ psumsq) {
    constexpr int BS = (NO >= 256) ? NO : 256;
    constexpr int RPS = BS / NO;
    __shared__ float ls[BS], ls2[BS];
    int c = threadIdx.x % NO;
    int rsub = threadIdx.x / NO;
    constexpr int chunk = (N_NODES + PB - 1) / PB;
    int r0 = blockIdx.x * chunk;
    int r1 = min(N_NODES, r0 + chunk);
    float s = 0.f, s2 = 0.f;
    for (int r = r0 + rsub; r < r1; r += RPS) {
        float v = b2f(X[(size_t)r * NO + c]);
        s += v;
        s2 += v * v;
    }
    if (RPS > 1) {
        ls[threadIdx.x] = s;
        ls2[threadIdx.x] = s2;
        __syncthreads();
        for (int off = BS / 2; off >= NO; off >>= 1) {
            if (threadIdx.x < off) {
                ls[threadIdx.x] += ls[threadIdx.x + off];
                ls2[threadIdx.x] += ls2[threadIdx.x + off];
            }
            __syncthreads();
        }
        s = ls[threadIdx.x];
        s2 = ls2[threadIdx.x];
    }
    if (rsub == 0) {
        psum[(size_t)blockIdx.x * NO + c] = s;
        psumsq[(size_t)blockIdx.x * NO + c] = s2;
    }
}

// fp32-input variant (for k_lin outputs)
template<int NO>
__global__ void k_bnstatsf(const float* __restrict__ X, float* __restrict__ psum,
                           float* __restrict__ psumsq) {
    constexpr int BS = (NO >= 256) ? NO : 256;
    constexpr int RPS = BS / NO;
    __shared__ float ls[BS], ls2[BS];
    int c = threadIdx.x % NO;
    int rsub = threadIdx.x / NO;
    constexpr int chunk = (N_NODES + PB - 1) / PB;
    int r0 = blockIdx.x * chunk;
    int r1 = min(N_NODES, r0 + chunk);
    float s = 0.f, s2 = 0.f;
    for (int r = r0 + rsub; r < r1; r += RPS) {
        float v = X[(size_t)r * NO + c];
        s += v;
        s2 += v * v;
    }
    if (RPS > 1) {
        ls[threadIdx.x] = s;
        ls2[threadIdx.x] = s2;
        __syncthreads();
        for (int off = BS / 2; off >= NO; off >>= 1) {
            if (threadIdx.x < off) {
                ls[threadIdx.x] += ls[threadIdx.x + off];
                ls2[threadIdx.x] += ls2[threadIdx.x + off];
            }
            __syncthreads();
        }
        s = ls[threadIdx.x];
        s2 = ls2[threadIdx.x];
    }
    if (rsub == 0) {
        psum[(size_t)blockIdx.x * NO + c] = s;
        psumsq[(size_t)blockIdx.x * NO + c] = s2;
    }
}

__global__ void k_bnfinal(const float* __restrict__ psum, const float* __restrict__ psumsq,
                          const float* __restrict__ g, const float* __restrict__ be,
                          float* __restrict__ scale, float* __restrict__ shift, int NO) {
    int t = threadIdx.x;
    if (t >= NO) return;
    float s = 0.f, s2 = 0.f;
    for (int b = 0; b < PB; b++) {
        s += psum[(size_t)b * NO + t];
        s2 += psumsq[(size_t)b * NO + t];
    }
    float mu = s / (float)N_NODES;
    float var = s2 / (float)N_NODES - mu * mu;
    float sc = g[t] * rsqrtf(var + 1e-5f);
    scale[t] = sc;
    shift[t] = be[t] - mu * sc;
}

// ---------------- pooling (bf16 input) ----------------
__global__ void k_bhist(const int* __restrict__ batch, int* __restrict__ cnt) {
    __shared__ int h[G_GRAPHS];
    int tid = threadIdx.x;
    if (tid < G_GRAPHS) h[tid] = 0;
    __syncthreads();
    int i = blockIdx.x * blockDim.x + tid;
    if (i < N_NODES) atomicAdd(&h[batch[i]], 1);
    __syncthreads();
    if (tid < G_GRAPHS) atomicAdd(&cnt[tid], h[tid]);
}

__global__ void k_pool(const u16* __restrict__ X, const int* __restrict__ batch,
                       const float* __restrict__ sc, const float* __restrict__ sh,
                       float* __restrict__ pooled) {
    int t = threadIdx.x;  // 384
    const int chunk = (N_NODES + 511) / 512;
    int r0 = blockIdx.x * chunk;
    int r1 = min(N_NODES, r0 + chunk);
    if (r0 >= N_NODES) return;
    float acc = 0.f;
    int cur = batch[r0];
    for (int r = r0; r < r1; r++) {
        int gid = batch[r];
        if (gid != cur) {
            atomicAdd(&pooled[(size_t)cur * 384 + t], acc);
            acc = 0.f;
            cur = gid;
        }
        float v = b2f(X[(size_t)r * 384 + t]) * sc[t] + sh[t];
        acc += fmaxf(v, 0.f);
    }
    atomicAdd(&pooled[(size_t)cur * 384 + t], acc);
}

__global__ void k_final(const float* __restrict__ pooled, const int* __restrict__ cnt,
                        const float* __restrict__ lwf, const float* __restrict__ lbf,
                        float* __restrict__ out) {
    int t = threadIdx.x;  // 640
    if (t >= G_GRAPHS * 10) return;
    int g = t / 10, c = t - g * 10;
    float inv = 1.0f / fmaxf((float)cnt[g], 1.0f);
    float acc = lbf[c];
    for (int k = 0; k < 384; k++)
        acc = fmaf(pooled[(size_t)g * 384 + k] * inv, lwf[k * 10 + c], acc);
    out[t] = acc;
}

extern "C" void kernel_launch(void* const* d_in, const int* in_sizes, int n_in,
                              void* d_out, int out_size, void* d_ws, size_t ws_size,
                              hipStream_t stream) {
    const float* x    = (const float*)d_in[0];
    const int*   ei   = (const int*)d_in[1];
    const int*   batch= (const int*)d_in[2];
    const float* W1   = (const float*)d_in[3];
    const float* as1  = (const float*)d_in[4];
    const float* ad1  = (const float*)d_in[5];
    const float* b1   = (const float*)d_in[6];
    const float* g1   = (const float*)d_in[7];
    const float* be1  = (const float*)d_in[8];
    const float* lw1  = (const float*)d_in[9];
    const float* lb1  = (const float*)d_in[10];
    const float* gl1  = (const float*)d_in[11];
    const float* bel1 = (const float*)d_in[12];
    const float* W2   = (const float*)d_in[13];
    const float* as2  = (const float*)d_in[14];
    const float* ad2  = (const float*)d_in[15];
    const float* b2   = (const float*)d_in[16];
    const float* g2   = (const float*)d_in[17];
    const float* be2  = (const float*)d_in[18];
    const float* lw2  = (const float*)d_in[19];
    const float* lb2  = (const float*)d_in[20];
    const float* gl2  = (const float*)d_in[21];
    const float* bel2 = (const float*)d_in[22];
    const float* W3   = (const float*)d_in[23];
    const float* as3  = (const float*)d_in[24];
    const float* ad3  = (const float*)d_in[25];
    const float* b3   = (const float*)d_in[26];
    const float* g3   = (const float*)d_in[27];
    const float* be3  = (const float*)d_in[28];
    const float* lwf  = (const float*)d_in[29];
    const float* lbf  = (const float*)d_in[30];
    float* out = (float*)d_out;

    // ---- workspace carve ----
    char* p = (char*)d_ws;
    auto alloc = [&](size_t bytes) {
        char* r = p;
        p += (bytes + 255) & ~(size_t)255;
        return r;
    };
    int*   rowptr = (int*)alloc(4 * (size_t)(N_NODES + 1));
    int*   cursor = (int*)alloc(4 * (size_t)N_NODES);
    int*   deg    = (int*)alloc(4 * (size_t)N_NODES);
    int*   bsum   = (int*)alloc(4 * (size_t)(SCAN_B + 1));
    int*   col    = (int*)alloc(4 * (size_t)TOT_E);
    int*   cdst   = (int*)alloc(4 * (size_t)TOT_E);
    float* ssrc   = (float*)alloc(4 * (size_t)N_NODES * 20);
    float* sdst   = (float*)alloc(4 * (size_t)N_NODES * 20);
    u16*   hbuf   = (u16*)alloc(2 * (size_t)N_NODES * 512);
    u16*   obuf   = (u16*)alloc(2 * (size_t)N_NODES * 512);
    float* xbuf   = (float*)alloc(4 * (size_t)N_NODES * 32);
    float* psum   = (float*)alloc(4 * (size_t)PB * 512);
    float* psumsq = (float*)alloc(4 * (size_t)PB * 512);
    float* scA    = (float*)alloc(4 * 512);
    float* shA    = (float*)alloc(4 * 512);
    float* scB    = (float*)alloc(4 * 64);
    float* shB    = (float*)alloc(4 * 64);
    float* pooled = (float*)alloc(4 * (size_t)G_GRAPHS * 384);
    int*   cnt    = (int*)alloc(4 * G_GRAPHS);
    u16*   bp1    = (u16*)alloc(2 * (size_t)4 * 20 * 64 * 8);   // 80 KB
    u16*   bp2    = (u16*)alloc(2 * (size_t)1 * 32 * 64 * 8);   // 32 KB
    u16*   bp3    = (u16*)alloc(2 * (size_t)1 * 24 * 64 * 8);   // 24 KB

    const int LB = (N_NODES + 63) / 64;   // 782 row-tiles (k_lin and MFMA gemm)

    // ---- graph build + W packs (reused by all 3 layers) ----
    k_init_deg<<<(N_NODES + 255) / 256, 256, 0, stream>>>(deg);
    k_hist<<<(N_EDGES + 255) / 256, 256, 0, stream>>>(ei, deg);
    k_scan1<<<SCAN_B, 512, 0, stream>>>(deg, rowptr, bsum);
    k_scan2<<<1, 128, 0, stream>>>(bsum);
    k_scan3<<<(N_NODES + 255) / 256, 256, 0, stream>>>(rowptr, cursor, bsum);
    k_scatter<<<(TOT_E + 255) / 256, 256, 0, stream>>>(ei, cursor, col, cdst);
    k_wpack<128, 320><<<20, 256, 0, stream>>>(W1, bp1);
    k_wpack<16, 512><<<8, 256, 0, stream>>>(W2, bp2);
    k_wpack<32, 384><<<6, 256, 0, stream>>>(W3, bp3);
    hipMemsetAsync(pooled, 0, 4 * (size_t)G_GRAPHS * 384 + 256, stream);  // pooled + cnt

    // ---- layer 1: GAT(128 -> 20x16) ----
    k_gemm<128, 320, false><<<LB, 256, 0, stream>>>(x, bp1, nullptr, nullptr, hbuf);
    k_scores<20, 16><<<(N_NODES * 20 + 255) / 256, 256, 0, stream>>>(hbuf, as1, ad1, ssrc, sdst);
    k_agg<20, 16><<<(N_NODES + 3) / 4, 256, 0, stream>>>(hbuf, ssrc, sdst, rowptr, col, b1, obuf);
    k_bnstats<320><<<PB, 320, 0, stream>>>(obuf, psum, psumsq);
    k_bnfinal<<<1, 512, 0, stream>>>(psum, psumsq, g1, be1, scA, shA, 320);
    k_lin<320, 16, 4><<<LB, 256, 0, stream>>>(obuf, lw1, lb1, scA, shA, xbuf);
    k_bnstatsf<16><<<PB, 256, 0, stream>>>(xbuf, psum, psumsq);
    k_bnfinal<<<1, 512, 0, stream>>>(psum, psumsq, gl1, bel1, scB, shB, 16);

    // ---- layer 2: GAT(16 -> 16x32) ----
    k_gemm<16, 512, true><<<LB, 256, 0, stream>>>(xbuf, bp2, scB, shB, hbuf);
    k_scores<16, 32><<<(N_NODES * 16 + 255) / 256, 256, 0, stream>>>(hbuf, as2, ad2, ssrc, sdst);
    k_agg<16, 32><<<(N_NODES + 3) / 4, 256, 0, stream>>>(hbuf, ssrc, sdst, rowptr, col, b2, obuf);
    k_bnstats<512><<<PB, 512, 0, stream>>>(obuf, psum, psumsq);
    k_bnfinal<<<1, 512, 0, stream>>>(psum, psumsq, g2, be2, scA, shA, 512);
    k_lin<512, 32, 4><<<LB, 256, 0, stream>>>(obuf, lw2, lb2, scA, shA, xbuf);
    k_bnstatsf<32><<<PB, 256, 0, stream>>>(xbuf, psum, psumsq);
    k_bnfinal<<<1, 512, 0, stream>>>(psum, psumsq, gl2, bel2, scB, shB, 32);

    // ---- layer 3: GAT(32 -> 8x48) ----
    k_gemm<32, 384, true><<<LB, 256, 0, stream>>>(xbuf, bp3, scB, shB, hbuf);
    k_scores<8, 48><<<(N_NODES * 8 + 255) / 256, 256, 0, stream>>>(hbuf, as3, ad3, ssrc, sdst);
    k_agg<8, 48><<<(N_NODES + 3) / 4, 256, 0, stream>>>(hbuf, ssrc, sdst, rowptr, col, b3, obuf);
    k_bnstats<384><<<PB, 384, 0, stream>>>(obuf, psum, psumsq);
    k_bnfinal<<<1, 512, 0, stream>>>(psum, psumsq, g3, be3, scA, shA, 384);

    // ---- pool + classifier ----
    k_bhist<<<(N_NODES + 255) / 256, 256, 0, stream>>>(batch, cnt);
    k_pool<<<512, 384, 0, stream>>>(obuf, batch, scA, shA, pooled);
    k_final<<<1, 640, 0, stream>>>(pooled, cnt, lwf, lbf, out);
}

// Round 16
// 873.694 us; speedup vs baseline: 1.7541x; 1.0394x over previous
//
#include <hip/hip_runtime.h>
#include <cstdint>
#include <cstddef>

#define N_NODES 50000
#define N_EDGES 400000
#define TOT_E   450000
#define G_GRAPHS 64
#define PB 256   // partial blocks for bnstats
#define SCAN_B 98  // scan blocks of 512 (98*512 = 50176 >= N_NODES)

typedef unsigned short u16;
typedef unsigned int u32;
typedef __attribute__((ext_vector_type(8))) short s16x8;  // 8 bf16 (4 VGPRs)
typedef __attribute__((ext_vector_type(4))) float f32x4;  // MFMA accumulator

__device__ __forceinline__ float b2f(u16 v) {
    union { u32 u; float f; } x; x.u = ((u32)v) << 16; return x.f;
}
__device__ __forceinline__ float lo2f(u32 u) {
    union { u32 u; float f; } x; x.u = u << 16; return x.f;
}
__device__ __forceinline__ float hi2f(u32 u) {
    union { u32 u; float f; } x; x.u = u & 0xffff0000u; return x.f;
}
__device__ __forceinline__ u16 f2b(float f) {
    union { float f; u32 u; } x; x.f = f;
    u32 r = x.u + 0x7fffu + ((x.u >> 16) & 1u);  // round-nearest-even
    return (u16)(r >> 16);
}
__device__ __forceinline__ u32 pack2(float a, float b) {
    return (u32)f2b(a) | ((u32)f2b(b) << 16);
}

// ---------------- graph build ----------------
__global__ void k_init_deg(int* __restrict__ deg) {
    int i = blockIdx.x * blockDim.x + threadIdx.x;
    if (i < N_NODES) deg[i] = 1;  // self loop
}

__global__ void k_hist(const int* __restrict__ ei, int* __restrict__ deg) {
    int e = blockIdx.x * blockDim.x + threadIdx.x;
    if (e < N_EDGES) atomicAdd(&deg[ei[N_EDGES + e]], 1);
}

// phase 1: block-local exclusive scan, block totals to bsum
__global__ void k_scan1(const int* __restrict__ deg, int* __restrict__ rowptr,
                        int* __restrict__ bsum) {
    __shared__ int buf[512];
    int tid = threadIdx.x;
    int i = blockIdx.x * 512 + tid;
    int v = (i < N_NODES) ? deg[i] : 0;
    buf[tid] = v;
    __syncthreads();
    for (int off = 1; off < 512; off <<= 1) {
        int t = (tid >= off) ? buf[tid - off] : 0;
        __syncthreads();
        buf[tid] += t;
        __syncthreads();
    }
    if (i < N_NODES) rowptr[i] = buf[tid] - v;  // block-local exclusive
    if (tid == 511) bsum[blockIdx.x] = buf[511];
}

// phase 2: exclusive scan of the 98 block sums (single 128-thread block)
__global__ void k_scan2(int* __restrict__ bsum) {
    __shared__ int buf[128];
    int tid = threadIdx.x;
    int v = (tid < SCAN_B) ? bsum[tid] : 0;
    buf[tid] = v;
    __syncthreads();
    for (int off = 1; off < 128; off <<= 1) {
        int t = (tid >= off) ? buf[tid - off] : 0;
        __syncthreads();
        buf[tid] += t;
        __syncthreads();
    }
    if (tid < SCAN_B) bsum[tid] = buf[tid] - v;  // exclusive
}

// phase 3: add block offsets; write cursor; rowptr[N] = TOT_E (statically known)
__global__ void k_scan3(int* __restrict__ rowptr, int* __restrict__ cursor,
                        const int* __restrict__ bsum) {
    int i = blockIdx.x * blockDim.x + threadIdx.x;
    if (i < N_NODES) {
        int v = rowptr[i] + bsum[i >> 9];
        rowptr[i] = v;
        cursor[i] = v;
    }
    if (i == 0) rowptr[N_NODES] = TOT_E;
}

__global__ void k_scatter(const int* __restrict__ ei, int* __restrict__ cursor,
                          int* __restrict__ col, int* __restrict__ cdst) {
    int e = blockIdx.x * blockDim.x + threadIdx.x;
    if (e < N_EDGES) {
        int s = ei[e], d = ei[N_EDGES + e];
        int p = atomicAdd(&cursor[d], 1);
        col[p] = s;
        cdst[p] = d;
    } else if (e < TOT_E) {
        int i = e - N_EDGES;
        int p = atomicAdd(&cursor[i], 1);
        col[p] = i;
        cdst[p] = i;
    }
}

// ---------------- W pack: fp32 [K][NO] -> bf16 B-fragment layout ----------------
// Bp[((c*NT + t)*64 + lane)*8 + j] = W[c*32 + (lane>>4)*8 + j][t*16 + (lane&15)]
// (zero-padded for k >= K). One thread per (c,t,lane); writes 16 B contiguous.
template<int K, int NO>
__global__ void k_wpack(const float* __restrict__ W, u16* __restrict__ Bp) {
    constexpr int KC = (K + 31) / 32;
    constexpr int NT = NO / 16;
    int idx = blockIdx.x * 256 + threadIdx.x;
    if (idx >= KC * NT * 64) return;
    int lane = idx & 63;
    int t = (idx >> 6) % NT;
    int c = (idx >> 6) / NT;
    int n = t * 16 + (lane & 15);
    int kbase = c * 32 + (lane >> 4) * 8;
    u16 v[8];
#pragma unroll
    for (int j = 0; j < 8; j++) {
        int k = kbase + j;
        v[j] = (k < K) ? f2b(W[(size_t)k * NO + n]) : (u16)0;
    }
    *(uint4*)(Bp + (size_t)idx * 8) = *(const uint4*)v;
}

// ---------------- MFMA GEMM (fp32 input): Y[N,NO] = xform(X)[N,K] @ W, bf16 out -----
template<int K, int NO, bool XFORM>
__global__ __launch_bounds__(256, 2)
void k_gemm(const float* __restrict__ X, const u16* __restrict__ Bp,
            const float* __restrict__ scale, const float* __restrict__ shift,
            u16* __restrict__ Y) {
    constexpr int KC = (K + 31) / 32;
    constexpr int NT = NO / 16;
    int lane = threadIdx.x & 63;
    int wv = __builtin_amdgcn_readfirstlane((int)(threadIdx.x >> 6));
    int rbase = blockIdx.x * 64 + wv * 16;
    int m = lane & 15, quad = lane >> 4;
    int arow = rbase + m;
    if (arow >= N_NODES) arow = N_NODES - 1;  // clamp; stores guarded
    const float* xr = X + (size_t)arow * K;

    f32x4 acc[NT];
#pragma unroll
    for (int t = 0; t < NT; t++) acc[t] = (f32x4){0.f, 0.f, 0.f, 0.f};

    for (int c = 0; c < KC; c++) {
        int kbase = c * 32 + quad * 8;
        float xv[8];
        if (kbase < K) {
            float4 va = *(const float4*)&xr[kbase];
            float4 vb = *(const float4*)&xr[kbase + 4];
            xv[0] = va.x; xv[1] = va.y; xv[2] = va.z; xv[3] = va.w;
            xv[4] = vb.x; xv[5] = vb.y; xv[6] = vb.z; xv[7] = vb.w;
            if (XFORM) {
                float4 sa = *(const float4*)&scale[kbase];
                float4 sb = *(const float4*)&scale[kbase + 4];
                float4 ha = *(const float4*)&shift[kbase];
                float4 hb = *(const float4*)&shift[kbase + 4];
                xv[0] = fmaxf(xv[0] * sa.x + ha.x, 0.f);
                xv[1] = fmaxf(xv[1] * sa.y + ha.y, 0.f);
                xv[2] = fmaxf(xv[2] * sa.z + ha.z, 0.f);
                xv[3] = fmaxf(xv[3] * sa.w + ha.w, 0.f);
                xv[4] = fmaxf(xv[4] * sb.x + hb.x, 0.f);
                xv[5] = fmaxf(xv[5] * sb.y + hb.y, 0.f);
                xv[6] = fmaxf(xv[6] * sb.z + hb.z, 0.f);
                xv[7] = fmaxf(xv[7] * sb.w + hb.w, 0.f);
            }
        } else {
#pragma unroll
            for (int j = 0; j < 8; j++) xv[j] = 0.f;
        }
        s16x8 a;
#pragma unroll
        for (int j = 0; j < 8; j++) a[j] = (short)f2b(xv[j]);

        const u16* bp = Bp + (size_t)(c * NT) * 64 * 8;
#pragma unroll
        for (int t = 0; t < NT; t++) {
            s16x8 b = *(const s16x8*)(bp + ((size_t)(t * 64 + lane)) * 8);
            acc[t] = __builtin_amdgcn_mfma_f32_16x16x32_bf16(a, b, acc[t], 0, 0, 0);
        }
    }

#pragma unroll
    for (int t = 0; t < NT; t++) {
        int colb = t * 16 + m;
#pragma unroll
        for (int i = 0; i < 4; i++) {
            int grow = rbase + quad * 4 + i;
            if (grow < N_NODES) Y[(size_t)grow * NO + colb] = f2b(acc[t][i]);
        }
    }
}

// ---------------- MFMA GEMM (bf16 input): Y[N,NO] = xform(X)[N,K] @ W (+wb), bf16 out
// Same structure; A built from u32-packed bf16 with fused BN+ReLU; optional bias.
template<int K, int NO, bool XFORM, bool BIAS>
__global__ __launch_bounds__(256, 2)
void k_gemmb(const u16* __restrict__ X, const u16* __restrict__ Bp,
             const float* __restrict__ scale, const float* __restrict__ shift,
             const float* __restrict__ wb, u16* __restrict__ Y) {
    constexpr int KC = (K + 31) / 32;
    constexpr int NT = NO / 16;
    int lane = threadIdx.x & 63;
    int wv = __builtin_amdgcn_readfirstlane((int)(threadIdx.x >> 6));
    int rbase = blockIdx.x * 64 + wv * 16;
    int m = lane & 15, quad = lane >> 4;
    int arow = rbase + m;
    if (arow >= N_NODES) arow = N_NODES - 1;  // clamp; stores guarded
    const u32* xr = (const u32*)(X + (size_t)arow * K);

    f32x4 acc[NT];
#pragma unroll
    for (int t = 0; t < NT; t++) acc[t] = (f32x4){0.f, 0.f, 0.f, 0.f};

    for (int c = 0; c < KC; c++) {
        int kbase = c * 32 + quad * 8;
        s16x8 a;
        if (kbase < K) {
            uint4 w = *(const uint4*)&xr[kbase >> 1];
            if (XFORM) {
                float xv[8];
                xv[0] = lo2f(w.x); xv[1] = hi2f(w.x);
                xv[2] = lo2f(w.y); xv[3] = hi2f(w.y);
                xv[4] = lo2f(w.z); xv[5] = hi2f(w.z);
                xv[6] = lo2f(w.w); xv[7] = hi2f(w.w);
                float4 sa = *(const float4*)&scale[kbase];
                float4 sb = *(const float4*)&scale[kbase + 4];
                float4 ha = *(const float4*)&shift[kbase];
                float4 hb = *(const float4*)&shift[kbase + 4];
                xv[0] = fmaxf(xv[0] * sa.x + ha.x, 0.f);
                xv[1] = fmaxf(xv[1] * sa.y + ha.y, 0.f);
                xv[2] = fmaxf(xv[2] * sa.z + ha.z, 0.f);
                xv[3] = fmaxf(xv[3] * sa.w + ha.w, 0.f);
                xv[4] = fmaxf(xv[4] * sb.x + hb.x, 0.f);
                xv[5] = fmaxf(xv[5] * sb.y + hb.y, 0.f);
                xv[6] = fmaxf(xv[6] * sb.z + hb.z, 0.f);
                xv[7] = fmaxf(xv[7] * sb.w + hb.w, 0.f);
#pragma unroll
                for (int j = 0; j < 8; j++) a[j] = (short)f2b(xv[j]);
            } else {
                a = *(const s16x8*)&w;  // bf16 passthrough
            }
        } else {
#pragma unroll
            for (int j = 0; j < 8; j++) a[j] = 0;
        }

        const u16* bp = Bp + (size_t)(c * NT) * 64 * 8;
#pragma unroll
        for (int t = 0; t < NT; t++) {
            s16x8 b = *(const s16x8*)(bp + ((size_t)(t * 64 + lane)) * 8);
            acc[t] = __builtin_amdgcn_mfma_f32_16x16x32_bf16(a, b, acc[t], 0, 0, 0);
        }
    }

#pragma unroll
    for (int t = 0; t < NT; t++) {
        int colb = t * 16 + m;
        float bv = BIAS ? wb[colb] : 0.f;
#pragma unroll
        for (int i = 0; i < 4; i++) {
            int grow = rbase + quad * 4 + i;
            if (grow < N_NODES) Y[(size_t)grow * NO + colb] = f2b(acc[t][i] + bv);
        }
    }
}

// ---------------- attention scores (bf16 input, uint-packed reads) ----------------
template<int H, int C>
__global__ void k_scores(const u16* __restrict__ Hm, const float* __restrict__ asrc,
                         const float* __restrict__ adst, float* __restrict__ ssrc,
                         float* __restrict__ sdst) {
    int t = blockIdx.x * blockDim.x + threadIdx.x;
    if (t >= N_NODES * H) return;
    int i = t / H, h = t - i * H;
    const u32* row = (const u32*)(Hm + (size_t)i * H * C + h * C);
    float s1 = 0.f, s2 = 0.f;
#pragma unroll
    for (int c2 = 0; c2 < C / 2; c2++) {
        u32 u = row[c2];
        float v0 = lo2f(u), v1 = hi2f(u);
        int c = c2 * 2;
        s1 = fmaf(v0, asrc[h * C + c], fmaf(v1, asrc[h * C + c + 1], s1));
        s2 = fmaf(v0, adst[h * C + c], fmaf(v1, adst[h * C + c + 1], s2));
    }
    ssrc[t] = s1;
    sdst[t] = s2;
}

// ---------------- fused edge-softmax + aggregation (u32-packed bf16 gather) ----------
template<int H, int C>
__global__ void k_agg(const u16* __restrict__ Hm, const float* __restrict__ ssrc,
                      const float* __restrict__ sdst, const int* __restrict__ rowptr,
                      const int* __restrict__ col, const float* __restrict__ bias,
                      u16* __restrict__ out) {
    constexpr int HC = H * C;
    constexpr int HW = HC / 2;            // u32 words per row
    constexpr int KU = HW / 64;           // full word rounds
    constexpr int REM = HW % 64;          // remainder words (lane < REM valid)
    constexpr int KT = KU + (REM ? 1 : 0);
    int wid = (int)((blockIdx.x * blockDim.x + threadIdx.x) >> 6);
    int lane = threadIdx.x & 63;
    if (wid >= N_NODES) return;
    float sd = (lane < H) ? sdst[(size_t)wid * H + lane] : 0.f;
    float2 acc[KT];
    int hidx[KT];
#pragma unroll
    for (int k = 0; k < KT; k++) {
        acc[k] = make_float2(0.f, 0.f);
        hidx[k] = (2 * (lane + 64 * k)) / C;  // head of both packed elements
    }
    float z = 0.f;
    int beg = rowptr[wid], end = rowptr[wid + 1];
    for (int base = beg; base < end; base += 64) {
        int nmax = min(64, end - base);
        int myc = (base + lane < end) ? col[base + lane] : 0;
        int j = 0;
        for (; j + 4 <= nmax; j += 4) {
            int s0 = __shfl(myc, j), s1 = __shfl(myc, j + 1);
            int s2 = __shfl(myc, j + 2), s3 = __shfl(myc, j + 3);
            float w0 = 0.f, w1 = 0.f, w2 = 0.f, w3 = 0.f;
            if (lane < H) {
                float v0 = ssrc[(size_t)s0 * H + lane] + sd;
                float v1 = ssrc[(size_t)s1 * H + lane] + sd;
                float v2 = ssrc[(size_t)s2 * H + lane] + sd;
                float v3 = ssrc[(size_t)s3 * H + lane] + sd;
                v0 = (v0 > 0.f) ? v0 : 0.2f * v0;
                v1 = (v1 > 0.f) ? v1 : 0.2f * v1;
                v2 = (v2 > 0.f) ? v2 : 0.2f * v2;
                v3 = (v3 > 0.f) ? v3 : 0.2f * v3;
                w0 = __expf(v0); w1 = __expf(v1);
                w2 = __expf(v2); w3 = __expf(v3);
                z += (w0 + w1) + (w2 + w3);
            }
            const u32* r0 = (const u32*)(Hm + (size_t)s0 * HC);
            const u32* r1 = (const u32*)(Hm + (size_t)s1 * HC);
            const u32* r2 = (const u32*)(Hm + (size_t)s2 * HC);
            const u32* r3 = (const u32*)(Hm + (size_t)s3 * HC);
#pragma unroll
            for (int k = 0; k < KT; k++) {
                int idx = lane + 64 * k;  // rem round may over-read within pitch: safe
                u32 a0 = r0[idx], a1 = r1[idx], a2 = r2[idx], a3 = r3[idx];
                float wk0 = __shfl(w0, hidx[k]);
                float wk1 = __shfl(w1, hidx[k]);
                float wk2 = __shfl(w2, hidx[k]);
                float wk3 = __shfl(w3, hidx[k]);
                acc[k].x = fmaf(wk0, lo2f(a0), acc[k].x);
                acc[k].y = fmaf(wk0, hi2f(a0), acc[k].y);
                acc[k].x = fmaf(wk1, lo2f(a1), acc[k].x);
                acc[k].y = fmaf(wk1, hi2f(a1), acc[k].y);
                acc[k].x = fmaf(wk2, lo2f(a2), acc[k].x);
                acc[k].y = fmaf(wk2, hi2f(a2), acc[k].y);
                acc[k].x = fmaf(wk3, lo2f(a3), acc[k].x);
                acc[k].y = fmaf(wk3, hi2f(a3), acc[k].y);
            }
        }
        for (; j < nmax; j++) {
            int s0 = __shfl(myc, j);
            float w0 = 0.f;
            if (lane < H) {
                float v = ssrc[(size_t)s0 * H + lane] + sd;
                v = (v > 0.f) ? v : 0.2f * v;
                w0 = __expf(v);
                z += w0;
            }
            const u32* r0 = (const u32*)(Hm + (size_t)s0 * HC);
#pragma unroll
            for (int k = 0; k < KT; k++) {
                int idx = lane + 64 * k;
                u32 a0 = r0[idx];
                float wk0 = __shfl(w0, hidx[k]);
                acc[k].x = fmaf(wk0, lo2f(a0), acc[k].x);
                acc[k].y = fmaf(wk0, hi2f(a0), acc[k].y);
            }
        }
    }
    const float2* bias2 = (const float2*)bias;
    u32* orow = (u32*)(out + (size_t)wid * HC);
#pragma unroll
    for (int k = 0; k < KT; k++) {
        float zk = __shfl(z, hidx[k]);  // all lanes execute shfl
        if (k < KU || lane < REM) {
            int idx = lane + 64 * k;
            float2 b = bias2[idx];
            float inv = 1.0f / (zk + 1e-16f);
            orow[idx] = pack2(fmaf(acc[k].x, inv, b.x), fmaf(acc[k].y, inv, b.y));
        }
    }
}

// ---------------- batchnorm stats over bf16 input: atomic-free per-block partials ----
template<int NO>
__global__ void k_bnstats(const u16* __restrict__ X, float* __restrict__ psum,
                          float* __restrict__ psumsq) {
    constexpr int BS = (NO >= 256) ? NO : 256;
    constexpr int RPS = BS / NO;
    __shared__ float ls[BS], ls2[BS];
    int c = threadIdx.x % NO;
    int rsub = threadIdx.x / NO;
    constexpr int chunk = (N_NODES + PB - 1) / PB;
    int r0 = blockIdx.x * chunk;
    int r1 = min(N_NODES, r0 + chunk);
    float s = 0.f, s2 = 0.f;
    for (int r = r0 + rsub; r < r1; r += RPS) {
        float v = b2f(X[(size_t)r * NO + c]);
        s += v;
        s2 += v * v;
    }
    if (RPS > 1) {
        ls[threadIdx.x] = s;
        ls2[threadIdx.x] = s2;
        __syncthreads();
        for (int off = BS / 2; off >= NO; off >>= 1) {
            if (threadIdx.x < off) {
                ls[threadIdx.x] += ls[threadIdx.x + off];
                ls2[threadIdx.x] += ls2[threadIdx.x + off];
            }
            __syncthreads();
        }
        s = ls[threadIdx.x];
        s2 = ls2[threadIdx.x];
    }
    if (rsub == 0) {
        psum[(size_t)blockIdx.x * NO + c] = s;
        psumsq[(size_t)blockIdx.x * NO + c] = s2;
    }
}

__global__ void k_bnfinal(const float* __restrict__ psum, const float* __restrict__ psumsq,
                          const float* __restrict__ g, const float* __restrict__ be,
                          float* __restrict__ scale, float* __restrict__ shift, int NO) {
    int t = threadIdx.x;
    if (t >= NO) return;
    float s = 0.f, s2 = 0.f;
    for (int b = 0; b < PB; b++) {
        s += psum[(size_t)b * NO + t];
        s2 += psumsq[(size_t)b * NO + t];
    }
    float mu = s / (float)N_NODES;
    float var = s2 / (float)N_NODES - mu * mu;
    float sc = g[t] * rsqrtf(var + 1e-5f);
    scale[t] = sc;
    shift[t] = be[t] - mu * sc;
}

// ---------------- pooling (bf16 input) ----------------
__global__ void k_bhist(const int* __restrict__ batch, int* __restrict__ cnt) {
    __shared__ int h[G_GRAPHS];
    int tid = threadIdx.x;
    if (tid < G_GRAPHS) h[tid] = 0;
    __syncthreads();
    int i = blockIdx.x * blockDim.x + tid;
    if (i < N_NODES) atomicAdd(&h[batch[i]], 1);
    __syncthreads();
    if (tid < G_GRAPHS) atomicAdd(&cnt[tid], h[tid]);
}

__global__ void k_pool(const u16* __restrict__ X, const int* __restrict__ batch,
                       const float* __restrict__ sc, const float* __restrict__ sh,
                       float* __restrict__ pooled) {
    int t = threadIdx.x;  // 384
    const int chunk = (N_NODES + 511) / 512;
    int r0 = blockIdx.x * chunk;
    int r1 = min(N_NODES, r0 + chunk);
    if (r0 >= N_NODES) return;
    float acc = 0.f;
    int cur = batch[r0];
    for (int r = r0; r < r1; r++) {
        int gid = batch[r];
        if (gid != cur) {
            atomicAdd(&pooled[(size_t)cur * 384 + t], acc);
            acc = 0.f;
            cur = gid;
        }
        float v = b2f(X[(size_t)r * 384 + t]) * sc[t] + sh[t];
        acc += fmaxf(v, 0.f);
    }
    atomicAdd(&pooled[(size_t)cur * 384 + t], acc);
}

__global__ void k_final(const float* __restrict__ pooled, const int* __restrict__ cnt,
                        const float* __restrict__ lwf, const float* __restrict__ lbf,
                        float* __restrict__ out) {
    int t = threadIdx.x;  // 640
    if (t >= G_GRAPHS * 10) return;
    int g = t / 10, c = t - g * 10;
    float inv = 1.0f / fmaxf((float)cnt[g], 1.0f);
    float acc = lbf[c];
    for (int k = 0; k < 384; k++)
        acc = fmaf(pooled[(size_t)g * 384 + k] * inv, lwf[k * 10 + c], acc);
    out[t] = acc;
}

extern "C" void kernel_launch(void* const* d_in, const int* in_sizes, int n_in,
                              void* d_out, int out_size, void* d_ws, size_t ws_size,
                              hipStream_t stream) {
    const float* x    = (const float*)d_in[0];
    const int*   ei   = (const int*)d_in[1];
    const int*   batch= (const int*)d_in[2];
    const float* W1   = (const float*)d_in[3];
    const float* as1  = (const float*)d_in[4];
    const float* ad1  = (const float*)d_in[5];
    const float* b1   = (const float*)d_in[6];
    const float* g1   = (const float*)d_in[7];
    const float* be1  = (const float*)d_in[8];
    const float* lw1  = (const float*)d_in[9];
    const float* lb1  = (const float*)d_in[10];
    const float* gl1  = (const float*)d_in[11];
    const float* bel1 = (const float*)d_in[12];
    const float* W2   = (const float*)d_in[13];
    const float* as2  = (const float*)d_in[14];
    const float* ad2  = (const float*)d_in[15];
    const float* b2   = (const float*)d_in[16];
    const float* g2   = (const float*)d_in[17];
    const float* be2  = (const float*)d_in[18];
    const float* lw2  = (const float*)d_in[19];
    const float* lb2  = (const float*)d_in[20];
    const float* gl2  = (const float*)d_in[21];
    const float* bel2 = (const float*)d_in[22];
    const float* W3   = (const float*)d_in[23];
    const float* as3  = (const float*)d_in[24];
    const float* ad3  = (const float*)d_in[25];
    const float* b3   = (const float*)d_in[26];
    const float* g3   = (const float*)d_in[27];
    const float* be3  = (const float*)d_in[28];
    const float* lwf  = (const float*)d_in[29];
    const float* lbf  = (const float*)d_in[30];
    float* out = (float*)d_out;

    // ---- workspace carve ----
    char* p = (char*)d_ws;
    auto alloc = [&](size_t bytes) {
        char* r = p;
        p += (bytes + 255) & ~(size_t)255;
        return r;
    };
    int*   rowptr = (int*)alloc(4 * (size_t)(N_NODES + 1));
    int*   cursor = (int*)alloc(4 * (size_t)N_NODES);
    int*   deg    = (int*)alloc(4 * (size_t)N_NODES);
    int*   bsum   = (int*)alloc(4 * (size_t)(SCAN_B + 1));
    int*   col    = (int*)alloc(4 * (size_t)TOT_E);
    int*   cdst   = (int*)alloc(4 * (size_t)TOT_E);
    float* ssrc   = (float*)alloc(4 * (size_t)N_NODES * 20);
    float* sdst   = (float*)alloc(4 * (size_t)N_NODES * 20);
    u16*   hbuf   = (u16*)alloc(2 * (size_t)N_NODES * 512);
    u16*   obuf   = (u16*)alloc(2 * (size_t)N_NODES * 512);
    u16*   xbuf   = (u16*)alloc(2 * (size_t)N_NODES * 32);
    float* psum   = (float*)alloc(4 * (size_t)PB * 512);
    float* psumsq = (float*)alloc(4 * (size_t)PB * 512);
    float* scA    = (float*)alloc(4 * 512);
    float* shA    = (float*)alloc(4 * 512);
    float* scB    = (float*)alloc(4 * 64);
    float* shB    = (float*)alloc(4 * 64);
    float* pooled = (float*)alloc(4 * (size_t)G_GRAPHS * 384);
    int*   cnt    = (int*)alloc(4 * G_GRAPHS);
    u16*   bp1    = (u16*)alloc(2 * (size_t)4 * 20 * 64 * 8);   // W1: KC=4,NT=20
    u16*   bp2    = (u16*)alloc(2 * (size_t)1 * 32 * 64 * 8);   // W2: KC=1,NT=32
    u16*   bp3    = (u16*)alloc(2 * (size_t)1 * 24 * 64 * 8);   // W3: KC=1,NT=24
    u16*   bpl1   = (u16*)alloc(2 * (size_t)10 * 1 * 64 * 8);   // lw1: KC=10,NT=1
    u16*   bpl2   = (u16*)alloc(2 * (size_t)16 * 2 * 64 * 8);   // lw2: KC=16,NT=2

    const int LB = (N_NODES + 63) / 64;   // 782 row-tiles for MFMA gemms

    // ---- graph build + W packs (reused by all 3 layers) ----
    k_init_deg<<<(N_NODES + 255) / 256, 256, 0, stream>>>(deg);
    k_hist<<<(N_EDGES + 255) / 256, 256, 0, stream>>>(ei, deg);
    k_scan1<<<SCAN_B, 512, 0, stream>>>(deg, rowptr, bsum);
    k_scan2<<<1, 128, 0, stream>>>(bsum);
    k_scan3<<<(N_NODES + 255) / 256, 256, 0, stream>>>(rowptr, cursor, bsum);
    k_scatter<<<(TOT_E + 255) / 256, 256, 0, stream>>>(ei, cursor, col, cdst);
    k_wpack<128, 320><<<20, 256, 0, stream>>>(W1, bp1);
    k_wpack<16, 512><<<8, 256, 0, stream>>>(W2, bp2);
    k_wpack<32, 384><<<6, 256, 0, stream>>>(W3, bp3);
    k_wpack<320, 16><<<3, 256, 0, stream>>>(lw1, bpl1);
    k_wpack<512, 32><<<8, 256, 0, stream>>>(lw2, bpl2);
    hipMemsetAsync(pooled, 0, 4 * (size_t)G_GRAPHS * 384 + 256, stream);  // pooled + cnt

    // ---- layer 1: GAT(128 -> 20x16) ----
    k_gemm<128, 320, false><<<LB, 256, 0, stream>>>(x, bp1, nullptr, nullptr, hbuf);
    k_scores<20, 16><<<(N_NODES * 20 + 255) / 256, 256, 0, stream>>>(hbuf, as1, ad1, ssrc, sdst);
    k_agg<20, 16><<<(N_NODES + 3) / 4, 256, 0, stream>>>(hbuf, ssrc, sdst, rowptr, col, b1, obuf);
    k_bnstats<320><<<PB, 320, 0, stream>>>(obuf, psum, psumsq);
    k_bnfinal<<<1, 512, 0, stream>>>(psum, psumsq, g1, be1, scA, shA, 320);
    k_gemmb<320, 16, true, true><<<LB, 256, 0, stream>>>(obuf, bpl1, scA, shA, lb1, xbuf);
    k_bnstats<16><<<PB, 256, 0, stream>>>(xbuf, psum, psumsq);
    k_bnfinal<<<1, 512, 0, stream>>>(psum, psumsq, gl1, bel1, scB, shB, 16);

    // ---- layer 2: GAT(16 -> 16x32) ----
    k_gemmb<16, 512, true, false><<<LB, 256, 0, stream>>>(xbuf, bp2, scB, shB, nullptr, hbuf);
    k_scores<16, 32><<<(N_NODES * 16 + 255) / 256, 256, 0, stream>>>(hbuf, as2, ad2, ssrc, sdst);
    k_agg<16, 32><<<(N_NODES + 3) / 4, 256, 0, stream>>>(hbuf, ssrc, sdst, rowptr, col, b2, obuf);
    k_bnstats<512><<<PB, 512, 0, stream>>>(obuf, psum, psumsq);
    k_bnfinal<<<1, 512, 0, stream>>>(psum, psumsq, g2, be2, scA, shA, 512);
    k_gemmb<512, 32, true, true><<<LB, 256, 0, stream>>>(obuf, bpl2, scA, shA, lb2, xbuf);
    k_bnstats<32><<<PB, 256, 0, stream>>>(xbuf, psum, psumsq);
    k_bnfinal<<<1, 512, 0, stream>>>(psum, psumsq, gl2, bel2, scB, shB, 32);

    // ---- layer 3: GAT(32 -> 8x48) ----
    k_gemmb<32, 384, true, false><<<LB, 256, 0, stream>>>(xbuf, bp3, scB, shB, nullptr, hbuf);
    k_scores<8, 48><<<(N_NODES * 8 + 255) / 256, 256, 0, stream>>>(hbuf, as3, ad3, ssrc, sdst);
    k_agg<8, 48><<<(N_NODES + 3) / 4, 256, 0, stream>>>(hbuf, ssrc, sdst, rowptr, col, b3, obuf);
    k_bnstats<384><<<PB, 384, 0, stream>>>(obuf, psum, psumsq);
    k_bnfinal<<<1, 512, 0, stream>>>(psum, psumsq, g3, be3, scA, shA, 384);

    // ---- pool + classifier ----
    k_bhist<<<(N_NODES + 255) / 256, 256, 0, stream>>>(batch, cnt);
    k_pool<<<512, 384, 0, stream>>>(obuf, batch, scA, shA, pooled);
    k_final<<<1, 640, 0, stream>>>(pooled, cnt, lwf, lbf, out);
}

// Round 17
// 827.849 us; speedup vs baseline: 1.8512x; 1.0554x over previous
//
#include <hip/hip_runtime.h>
#include <cstdint>
#include <cstddef>

#define N_NODES 50000
#define N_EDGES 400000
#define TOT_E   450000
#define G_GRAPHS 64
#define PB 256   // partial blocks for bnstats
#define SCAN_B 98  // scan blocks of 512 (98*512 = 50176 >= N_NODES)

typedef unsigned short u16;
typedef unsigned int u32;
typedef __attribute__((ext_vector_type(8))) short s16x8;  // 8 bf16 (4 VGPRs)
typedef __attribute__((ext_vector_type(4))) float f32x4;  // MFMA accumulator

__device__ __forceinline__ float b2f(u16 v) {
    union { u32 u; float f; } x; x.u = ((u32)v) << 16; return x.f;
}
__device__ __forceinline__ float lo2f(u32 u) {
    union { u32 u; float f; } x; x.u = u << 16; return x.f;
}
__device__ __forceinline__ float hi2f(u32 u) {
    union { u32 u; float f; } x; x.u = u & 0xffff0000u; return x.f;
}
__device__ __forceinline__ u16 f2b(float f) {
    union { float f; u32 u; } x; x.f = f;
    u32 r = x.u + 0x7fffu + ((x.u >> 16) & 1u);  // round-nearest-even
    return (u16)(r >> 16);
}
__device__ __forceinline__ u32 pack2(float a, float b) {
    return (u32)f2b(a) | ((u32)f2b(b) << 16);
}

// ---------------- graph build ----------------
__global__ void k_init_deg(int* __restrict__ deg) {
    int i = blockIdx.x * blockDim.x + threadIdx.x;
    if (i < N_NODES) deg[i] = 1;  // self loop
}

__global__ void k_hist(const int* __restrict__ ei, int* __restrict__ deg) {
    int e = blockIdx.x * blockDim.x + threadIdx.x;
    if (e < N_EDGES) atomicAdd(&deg[ei[N_EDGES + e]], 1);
}

// phase 1: block-local exclusive scan, block totals to bsum
__global__ void k_scan1(const int* __restrict__ deg, int* __restrict__ rowptr,
                        int* __restrict__ bsum) {
    __shared__ int buf[512];
    int tid = threadIdx.x;
    int i = blockIdx.x * 512 + tid;
    int v = (i < N_NODES) ? deg[i] : 0;
    buf[tid] = v;
    __syncthreads();
    for (int off = 1; off < 512; off <<= 1) {
        int t = (tid >= off) ? buf[tid - off] : 0;
        __syncthreads();
        buf[tid] += t;
        __syncthreads();
    }
    if (i < N_NODES) rowptr[i] = buf[tid] - v;  // block-local exclusive
    if (tid == 511) bsum[blockIdx.x] = buf[511];
}

// phase 2: exclusive scan of the 98 block sums (single 128-thread block)
__global__ void k_scan2(int* __restrict__ bsum) {
    __shared__ int buf[128];
    int tid = threadIdx.x;
    int v = (tid < SCAN_B) ? bsum[tid] : 0;
    buf[tid] = v;
    __syncthreads();
    for (int off = 1; off < 128; off <<= 1) {
        int t = (tid >= off) ? buf[tid - off] : 0;
        __syncthreads();
        buf[tid] += t;
        __syncthreads();
    }
    if (tid < SCAN_B) bsum[tid] = buf[tid] - v;  // exclusive
}

// phase 3: add block offsets; write cursor; rowptr[N] = TOT_E (statically known)
__global__ void k_scan3(int* __restrict__ rowptr, int* __restrict__ cursor,
                        const int* __restrict__ bsum) {
    int i = blockIdx.x * blockDim.x + threadIdx.x;
    if (i < N_NODES) {
        int v = rowptr[i] + bsum[i >> 9];
        rowptr[i] = v;
        cursor[i] = v;
    }
    if (i == 0) rowptr[N_NODES] = TOT_E;
}

__global__ void k_scatter(const int* __restrict__ ei, int* __restrict__ cursor,
                          int* __restrict__ col, int* __restrict__ cdst) {
    int e = blockIdx.x * blockDim.x + threadIdx.x;
    if (e < N_EDGES) {
        int s = ei[e], d = ei[N_EDGES + e];
        int p = atomicAdd(&cursor[d], 1);
        col[p] = s;
        cdst[p] = d;
    } else if (e < TOT_E) {
        int i = e - N_EDGES;
        int p = atomicAdd(&cursor[i], 1);
        col[p] = i;
        cdst[p] = i;
    }
}

// ---------------- W pack: fp32 [K][NO] -> bf16 B-fragment layout ----------------
template<int K, int NO>
__global__ void k_wpack(const float* __restrict__ W, u16* __restrict__ Bp) {
    constexpr int KC = (K + 31) / 32;
    constexpr int NT = NO / 16;
    int idx = blockIdx.x * 256 + threadIdx.x;
    if (idx >= KC * NT * 64) return;
    int lane = idx & 63;
    int t = (idx >> 6) % NT;
    int c = (idx >> 6) / NT;
    int n = t * 16 + (lane & 15);
    int kbase = c * 32 + (lane >> 4) * 8;
    u16 v[8];
#pragma unroll
    for (int j = 0; j < 8; j++) {
        int k = kbase + j;
        v[j] = (k < K) ? f2b(W[(size_t)k * NO + n]) : (u16)0;
    }
    *(uint4*)(Bp + (size_t)idx * 8) = *(const uint4*)v;
}

// ---------------- MFMA GEMM (fp32 input): Y[N,NO] = xform(X)[N,K] @ W, bf16 out -----
template<int K, int NO, bool XFORM>
__global__ __launch_bounds__(256, 2)
void k_gemm(const float* __restrict__ X, const u16* __restrict__ Bp,
            const float* __restrict__ scale, const float* __restrict__ shift,
            u16* __restrict__ Y) {
    constexpr int KC = (K + 31) / 32;
    constexpr int NT = NO / 16;
    int lane = threadIdx.x & 63;
    int wv = __builtin_amdgcn_readfirstlane((int)(threadIdx.x >> 6));
    int rbase = blockIdx.x * 64 + wv * 16;
    int m = lane & 15, quad = lane >> 4;
    int arow = rbase + m;
    if (arow >= N_NODES) arow = N_NODES - 1;  // clamp; stores guarded
    const float* xr = X + (size_t)arow * K;

    f32x4 acc[NT];
#pragma unroll
    for (int t = 0; t < NT; t++) acc[t] = (f32x4){0.f, 0.f, 0.f, 0.f};

    for (int c = 0; c < KC; c++) {
        int kbase = c * 32 + quad * 8;
        float xv[8];
        if (kbase < K) {
            float4 va = *(const float4*)&xr[kbase];
            float4 vb = *(const float4*)&xr[kbase + 4];
            xv[0] = va.x; xv[1] = va.y; xv[2] = va.z; xv[3] = va.w;
            xv[4] = vb.x; xv[5] = vb.y; xv[6] = vb.z; xv[7] = vb.w;
            if (XFORM) {
                float4 sa = *(const float4*)&scale[kbase];
                float4 sb = *(const float4*)&scale[kbase + 4];
                float4 ha = *(const float4*)&shift[kbase];
                float4 hb = *(const float4*)&shift[kbase + 4];
                xv[0] = fmaxf(xv[0] * sa.x + ha.x, 0.f);
                xv[1] = fmaxf(xv[1] * sa.y + ha.y, 0.f);
                xv[2] = fmaxf(xv[2] * sa.z + ha.z, 0.f);
                xv[3] = fmaxf(xv[3] * sa.w + ha.w, 0.f);
                xv[4] = fmaxf(xv[4] * sb.x + hb.x, 0.f);
                xv[5] = fmaxf(xv[5] * sb.y + hb.y, 0.f);
                xv[6] = fmaxf(xv[6] * sb.z + hb.z, 0.f);
                xv[7] = fmaxf(xv[7] * sb.w + hb.w, 0.f);
            }
        } else {
#pragma unroll
            for (int j = 0; j < 8; j++) xv[j] = 0.f;
        }
        s16x8 a;
#pragma unroll
        for (int j = 0; j < 8; j++) a[j] = (short)f2b(xv[j]);

        const u16* bp = Bp + (size_t)(c * NT) * 64 * 8;
#pragma unroll
        for (int t = 0; t < NT; t++) {
            s16x8 b = *(const s16x8*)(bp + ((size_t)(t * 64 + lane)) * 8);
            acc[t] = __builtin_amdgcn_mfma_f32_16x16x32_bf16(a, b, acc[t], 0, 0, 0);
        }
    }

#pragma unroll
    for (int t = 0; t < NT; t++) {
        int colb = t * 16 + m;
#pragma unroll
        for (int i = 0; i < 4; i++) {
            int grow = rbase + quad * 4 + i;
            if (grow < N_NODES) Y[(size_t)grow * NO + colb] = f2b(acc[t][i]);
        }
    }
}

// ---------------- MFMA GEMM (bf16 input): Y[N,NO] = xform(X)[N,K] @ W (+wb), bf16 out
template<int K, int NO, bool XFORM, bool BIAS>
__global__ __launch_bounds__(256, 2)
void k_gemmb(const u16* __restrict__ X, const u16* __restrict__ Bp,
             const float* __restrict__ scale, const float* __restrict__ shift,
             const float* __restrict__ wb, u16* __restrict__ Y) {
    constexpr int KC = (K + 31) / 32;
    constexpr int NT = NO / 16;
    int lane = threadIdx.x & 63;
    int wv = __builtin_amdgcn_readfirstlane((int)(threadIdx.x >> 6));
    int rbase = blockIdx.x * 64 + wv * 16;
    int m = lane & 15, quad = lane >> 4;
    int arow = rbase + m;
    if (arow >= N_NODES) arow = N_NODES - 1;  // clamp; stores guarded
    const u32* xr = (const u32*)(X + (size_t)arow * K);

    f32x4 acc[NT];
#pragma unroll
    for (int t = 0; t < NT; t++) acc[t] = (f32x4){0.f, 0.f, 0.f, 0.f};

    for (int c = 0; c < KC; c++) {
        int kbase = c * 32 + quad * 8;
        s16x8 a;
        if (kbase < K) {
            uint4 w = *(const uint4*)&xr[kbase >> 1];
            if (XFORM) {
                float xv[8];
                xv[0] = lo2f(w.x); xv[1] = hi2f(w.x);
                xv[2] = lo2f(w.y); xv[3] = hi2f(w.y);
                xv[4] = lo2f(w.z); xv[5] = hi2f(w.z);
                xv[6] = lo2f(w.w); xv[7] = hi2f(w.w);
                float4 sa = *(const float4*)&scale[kbase];
                float4 sb = *(const float4*)&scale[kbase + 4];
                float4 ha = *(const float4*)&shift[kbase];
                float4 hb = *(const float4*)&shift[kbase + 4];
                xv[0] = fmaxf(xv[0] * sa.x + ha.x, 0.f);
                xv[1] = fmaxf(xv[1] * sa.y + ha.y, 0.f);
                xv[2] = fmaxf(xv[2] * sa.z + ha.z, 0.f);
                xv[3] = fmaxf(xv[3] * sa.w + ha.w, 0.f);
                xv[4] = fmaxf(xv[4] * sb.x + hb.x, 0.f);
                xv[5] = fmaxf(xv[5] * sb.y + hb.y, 0.f);
                xv[6] = fmaxf(xv[6] * sb.z + hb.z, 0.f);
                xv[7] = fmaxf(xv[7] * sb.w + hb.w, 0.f);
#pragma unroll
                for (int j = 0; j < 8; j++) a[j] = (short)f2b(xv[j]);
            } else {
                a = *(const s16x8*)&w;  // bf16 passthrough
            }
        } else {
#pragma unroll
            for (int j = 0; j < 8; j++) a[j] = 0;
        }

        const u16* bp = Bp + (size_t)(c * NT) * 64 * 8;
#pragma unroll
        for (int t = 0; t < NT; t++) {
            s16x8 b = *(const s16x8*)(bp + ((size_t)(t * 64 + lane)) * 8);
            acc[t] = __builtin_amdgcn_mfma_f32_16x16x32_bf16(a, b, acc[t], 0, 0, 0);
        }
    }

#pragma unroll
    for (int t = 0; t < NT; t++) {
        int colb = t * 16 + m;
        float bv = BIAS ? wb[colb] : 0.f;
#pragma unroll
        for (int i = 0; i < 4; i++) {
            int grow = rbase + quad * 4 + i;
            if (grow < N_NODES) Y[(size_t)grow * NO + colb] = f2b(acc[t][i] + bv);
        }
    }
}

// ---------------- attention scores (bf16 input, uint4-vectorized reads) ------------
template<int H, int C>
__global__ void k_scores(const u16* __restrict__ Hm, const float* __restrict__ asrc,
                         const float* __restrict__ adst, float* __restrict__ ssrc,
                         float* __restrict__ sdst) {
    int t = blockIdx.x * blockDim.x + threadIdx.x;
    if (t >= N_NODES * H) return;
    int i = t / H, h = t - i * H;
    const uint4* row4 = (const uint4*)(Hm + (size_t)i * H * C + h * C);
    const float4* a4 = (const float4*)(asrc + h * C);
    const float4* d4 = (const float4*)(adst + h * C);
    float s1 = 0.f, s2 = 0.f;
#pragma unroll
    for (int c8 = 0; c8 < C / 8; c8++) {
        uint4 u = row4[c8];
        float v0 = lo2f(u.x), v1 = hi2f(u.x), v2 = lo2f(u.y), v3 = hi2f(u.y);
        float v4 = lo2f(u.z), v5 = hi2f(u.z), v6 = lo2f(u.w), v7 = hi2f(u.w);
        float4 aa = a4[c8 * 2], ab = a4[c8 * 2 + 1];
        float4 da = d4[c8 * 2], db = d4[c8 * 2 + 1];
        s1 = fmaf(v0, aa.x, fmaf(v1, aa.y, fmaf(v2, aa.z, fmaf(v3, aa.w, s1))));
        s1 = fmaf(v4, ab.x, fmaf(v5, ab.y, fmaf(v6, ab.z, fmaf(v7, ab.w, s1))));
        s2 = fmaf(v0, da.x, fmaf(v1, da.y, fmaf(v2, da.z, fmaf(v3, da.w, s2))));
        s2 = fmaf(v4, db.x, fmaf(v5, db.y, fmaf(v6, db.z, fmaf(v7, db.w, s2))));
    }
    ssrc[t] = s1;
    sdst[t] = s2;
}

// ---------------- fused edge-softmax + aggregation (u32-packed bf16 gather) ----------
template<int H, int C>
__global__ void k_agg(const u16* __restrict__ Hm, const float* __restrict__ ssrc,
                      const float* __restrict__ sdst, const int* __restrict__ rowptr,
                      const int* __restrict__ col, const float* __restrict__ bias,
                      u16* __restrict__ out) {
    constexpr int HC = H * C;
    constexpr int HW = HC / 2;            // u32 words per row
    constexpr int KU = HW / 64;           // full word rounds
    constexpr int REM = HW % 64;          // remainder words (lane < REM valid)
    constexpr int KT = KU + (REM ? 1 : 0);
    int wid = (int)((blockIdx.x * blockDim.x + threadIdx.x) >> 6);
    int lane = threadIdx.x & 63;
    if (wid >= N_NODES) return;
    float sd = (lane < H) ? sdst[(size_t)wid * H + lane] : 0.f;
    float2 acc[KT];
    int hidx[KT];
#pragma unroll
    for (int k = 0; k < KT; k++) {
        acc[k] = make_float2(0.f, 0.f);
        hidx[k] = (2 * (lane + 64 * k)) / C;  // head of both packed elements
    }
    float z = 0.f;
    int beg = rowptr[wid], end = rowptr[wid + 1];
    for (int base = beg; base < end; base += 64) {
        int nmax = min(64, end - base);
        int myc = (base + lane < end) ? col[base + lane] : 0;
        int j = 0;
        for (; j + 4 <= nmax; j += 4) {
            int s0 = __shfl(myc, j), s1 = __shfl(myc, j + 1);
            int s2 = __shfl(myc, j + 2), s3 = __shfl(myc, j + 3);
            float w0 = 0.f, w1 = 0.f, w2 = 0.f, w3 = 0.f;
            if (lane < H) {
                float v0 = ssrc[(size_t)s0 * H + lane] + sd;
                float v1 = ssrc[(size_t)s1 * H + lane] + sd;
                float v2 = ssrc[(size_t)s2 * H + lane] + sd;
                float v3 = ssrc[(size_t)s3 * H + lane] + sd;
                v0 = (v0 > 0.f) ? v0 : 0.2f * v0;
                v1 = (v1 > 0.f) ? v1 : 0.2f * v1;
                v2 = (v2 > 0.f) ? v2 : 0.2f * v2;
                v3 = (v3 > 0.f) ? v3 : 0.2f * v3;
                w0 = __expf(v0); w1 = __expf(v1);
                w2 = __expf(v2); w3 = __expf(v3);
                z += (w0 + w1) + (w2 + w3);
            }
            const u32* r0 = (const u32*)(Hm + (size_t)s0 * HC);
            const u32* r1 = (const u32*)(Hm + (size_t)s1 * HC);
            const u32* r2 = (const u32*)(Hm + (size_t)s2 * HC);
            const u32* r3 = (const u32*)(Hm + (size_t)s3 * HC);
#pragma unroll
            for (int k = 0; k < KT; k++) {
                int idx = lane + 64 * k;  // rem round may over-read within pitch: safe
                u32 a0 = r0[idx], a1 = r1[idx], a2 = r2[idx], a3 = r3[idx];
                float wk0 = __shfl(w0, hidx[k]);
                float wk1 = __shfl(w1, hidx[k]);
                float wk2 = __shfl(w2, hidx[k]);
                float wk3 = __shfl(w3, hidx[k]);
                acc[k].x = fmaf(wk0, lo2f(a0), acc[k].x);
                acc[k].y = fmaf(wk0, hi2f(a0), acc[k].y);
                acc[k].x = fmaf(wk1, lo2f(a1), acc[k].x);
                acc[k].y = fmaf(wk1, hi2f(a1), acc[k].y);
                acc[k].x = fmaf(wk2, lo2f(a2), acc[k].x);
                acc[k].y = fmaf(wk2, hi2f(a2), acc[k].y);
                acc[k].x = fmaf(wk3, lo2f(a3), acc[k].x);
                acc[k].y = fmaf(wk3, hi2f(a3), acc[k].y);
            }
        }
        for (; j < nmax; j++) {
            int s0 = __shfl(myc, j);
            float w0 = 0.f;
            if (lane < H) {
                float v = ssrc[(size_t)s0 * H + lane] + sd;
                v = (v > 0.f) ? v : 0.2f * v;
                w0 = __expf(v);
                z += w0;
            }
            const u32* r0 = (const u32*)(Hm + (size_t)s0 * HC);
#pragma unroll
            for (int k = 0; k < KT; k++) {
                int idx = lane + 64 * k;
                u32 a0 = r0[idx];
                float wk0 = __shfl(w0, hidx[k]);
                acc[k].x = fmaf(wk0, lo2f(a0), acc[k].x);
                acc[k].y = fmaf(wk0, hi2f(a0), acc[k].y);
            }
        }
    }
    const float2* bias2 = (const float2*)bias;
    u32* orow = (u32*)(out + (size_t)wid * HC);
#pragma unroll
    for (int k = 0; k < KT; k++) {
        float zk = __shfl(z, hidx[k]);  // all lanes execute shfl
        if (k < KU || lane < REM) {
            int idx = lane + 64 * k;
            float2 b = bias2[idx];
            float inv = 1.0f / (zk + 1e-16f);
            orow[idx] = pack2(fmaf(acc[k].x, inv, b.x), fmaf(acc[k].y, inv, b.y));
        }
    }
}

// ---------------- batchnorm stats over bf16 input (u32-pair vectorized) -------------
template<int NO>
__global__ void k_bnstats(const u16* __restrict__ X, float* __restrict__ psum,
                          float* __restrict__ psumsq) {
    constexpr int NO2 = NO / 2;
    constexpr int RPS = (NO2 >= 256) ? 1 : ((255 + NO2) / NO2);
    constexpr int BS = NO2 * RPS;
    __shared__ float2 ls[BS], ls2[BS];
    int c2 = threadIdx.x % NO2;
    int rsub = threadIdx.x / NO2;
    constexpr int chunk = (N_NODES + PB - 1) / PB;
    int r0 = blockIdx.x * chunk;
    int r1 = min(N_NODES, r0 + chunk);
    float2 s = make_float2(0.f, 0.f), s2 = make_float2(0.f, 0.f);
    const u32* Xw = (const u32*)X;
    for (int r = r0 + rsub; r < r1; r += RPS) {
        u32 u = Xw[(size_t)r * NO2 + c2];
        float a = lo2f(u), b = hi2f(u);
        s.x += a; s.y += b;
        s2.x += a * a; s2.y += b * b;
    }
    if (RPS > 1) {
        ls[threadIdx.x] = s;
        ls2[threadIdx.x] = s2;
        __syncthreads();
        for (int off = BS / 2; off >= NO2; off >>= 1) {
            if (threadIdx.x < off) {
                ls[threadIdx.x].x += ls[threadIdx.x + off].x;
                ls[threadIdx.x].y += ls[threadIdx.x + off].y;
                ls2[threadIdx.x].x += ls2[threadIdx.x + off].x;
                ls2[threadIdx.x].y += ls2[threadIdx.x + off].y;
            }
            __syncthreads();
        }
        s = ls[threadIdx.x];
        s2 = ls2[threadIdx.x];
    }
    if (rsub == 0) {
        *(float2*)&psum[(size_t)blockIdx.x * NO + 2 * c2] = s;
        *(float2*)&psumsq[(size_t)blockIdx.x * NO + 2 * c2] = s2;
    }
}

__global__ void k_bnfinal(const float* __restrict__ psum, const float* __restrict__ psumsq,
                          const float* __restrict__ g, const float* __restrict__ be,
                          float* __restrict__ scale, float* __restrict__ shift, int NO) {
    int t = threadIdx.x;
    if (t >= NO) return;
    float s = 0.f, s2 = 0.f;
    for (int b = 0; b < PB; b++) {
        s += psum[(size_t)b * NO + t];
        s2 += psumsq[(size_t)b * NO + t];
    }
    float mu = s / (float)N_NODES;
    float var = s2 / (float)N_NODES - mu * mu;
    float sc = g[t] * rsqrtf(var + 1e-5f);
    scale[t] = sc;
    shift[t] = be[t] - mu * sc;
}

// ---------------- pooling (bf16 input, u32-pair vectorized) ----------------
__global__ void k_bhist(const int* __restrict__ batch, int* __restrict__ cnt) {
    __shared__ int h[G_GRAPHS];
    int tid = threadIdx.x;
    if (tid < G_GRAPHS) h[tid] = 0;
    __syncthreads();
    int i = blockIdx.x * blockDim.x + tid;
    if (i < N_NODES) atomicAdd(&h[batch[i]], 1);
    __syncthreads();
    if (tid < G_GRAPHS) atomicAdd(&cnt[tid], h[tid]);
}

__global__ void k_pool(const u16* __restrict__ X, const int* __restrict__ batch,
                       const float* __restrict__ sc, const float* __restrict__ sh,
                       float* __restrict__ pooled) {
    int t2 = threadIdx.x;  // 192 threads, each owns u32 pair (cols 2*t2, 2*t2+1)
    const int chunk = (N_NODES + 511) / 512;
    int r0 = blockIdx.x * chunk;
    int r1 = min(N_NODES, r0 + chunk);
    if (r0 >= N_NODES) return;
    float2 scv = *(const float2*)&sc[2 * t2];
    float2 shv = *(const float2*)&sh[2 * t2];
    const u32* Xw = (const u32*)X;
    float2 acc = make_float2(0.f, 0.f);
    int cur = batch[r0];
    for (int r = r0; r < r1; r++) {
        int gid = batch[r];
        if (gid != cur) {
            atomicAdd(&pooled[(size_t)cur * 384 + 2 * t2], acc.x);
            atomicAdd(&pooled[(size_t)cur * 384 + 2 * t2 + 1], acc.y);
            acc = make_float2(0.f, 0.f);
            cur = gid;
        }
        u32 u = Xw[(size_t)r * 192 + t2];
        acc.x += fmaxf(lo2f(u) * scv.x + shv.x, 0.f);
        acc.y += fmaxf(hi2f(u) * scv.y + shv.y, 0.f);
    }
    atomicAdd(&pooled[(size_t)cur * 384 + 2 * t2], acc.x);
    atomicAdd(&pooled[(size_t)cur * 384 + 2 * t2 + 1], acc.y);
}

__global__ void k_final(const float* __restrict__ pooled, const int* __restrict__ cnt,
                        const float* __restrict__ lwf, const float* __restrict__ lbf,
                        float* __restrict__ out) {
    int t = threadIdx.x;  // 640
    if (t >= G_GRAPHS * 10) return;
    int g = t / 10, c = t - g * 10;
    float inv = 1.0f / fmaxf((float)cnt[g], 1.0f);
    float acc = lbf[c];
    for (int k = 0; k < 384; k++)
        acc = fmaf(pooled[(size_t)g * 384 + k] * inv, lwf[k * 10 + c], acc);
    out[t] = acc;
}

extern "C" void kernel_launch(void* const* d_in, const int* in_sizes, int n_in,
                              void* d_out, int out_size, void* d_ws, size_t ws_size,
                              hipStream_t stream) {
    const float* x    = (const float*)d_in[0];
    const int*   ei   = (const int*)d_in[1];
    const int*   batch= (const int*)d_in[2];
    const float* W1   = (const float*)d_in[3];
    const float* as1  = (const float*)d_in[4];
    const float* ad1  = (const float*)d_in[5];
    const float* b1   = (const float*)d_in[6];
    const float* g1   = (const float*)d_in[7];
    const float* be1  = (const float*)d_in[8];
    const float* lw1  = (const float*)d_in[9];
    const float* lb1  = (const float*)d_in[10];
    const float* gl1  = (const float*)d_in[11];
    const float* bel1 = (const float*)d_in[12];
    const float* W2   = (const float*)d_in[13];
    const float* as2  = (const float*)d_in[14];
    const float* ad2  = (const float*)d_in[15];
    const float* b2   = (const float*)d_in[16];
    const float* g2   = (const float*)d_in[17];
    const float* be2  = (const float*)d_in[18];
    const float* lw2  = (const float*)d_in[19];
    const float* lb2  = (const float*)d_in[20];
    const float* gl2  = (const float*)d_in[21];
    const float* bel2 = (const float*)d_in[22];
    const float* W3   = (const float*)d_in[23];
    const float* as3  = (const float*)d_in[24];
    const float* ad3  = (const float*)d_in[25];
    const float* b3   = (const float*)d_in[26];
    const float* g3   = (const float*)d_in[27];
    const float* be3  = (const float*)d_in[28];
    const float* lwf  = (const float*)d_in[29];
    const float* lbf  = (const float*)d_in[30];
    float* out = (float*)d_out;

    // ---- workspace carve ----
    char* p = (char*)d_ws;
    auto alloc = [&](size_t bytes) {
        char* r = p;
        p += (bytes + 255) & ~(size_t)255;
        return r;
    };
    int*   rowptr = (int*)alloc(4 * (size_t)(N_NODES + 1));
    int*   cursor = (int*)alloc(4 * (size_t)N_NODES);
    int*   deg    = (int*)alloc(4 * (size_t)N_NODES);
    int*   bsum   = (int*)alloc(4 * (size_t)(SCAN_B + 1));
    int*   col    = (int*)alloc(4 * (size_t)TOT_E);
    int*   cdst   = (int*)alloc(4 * (size_t)TOT_E);
    float* ssrc   = (float*)alloc(4 * (size_t)N_NODES * 20);
    float* sdst   = (float*)alloc(4 * (size_t)N_NODES * 20);
    u16*   hbuf   = (u16*)alloc(2 * (size_t)N_NODES * 512);
    u16*   obuf   = (u16*)alloc(2 * (size_t)N_NODES * 512);
    u16*   xbuf   = (u16*)alloc(2 * (size_t)N_NODES * 32);
    float* psum   = (float*)alloc(4 * (size_t)PB * 512);
    float* psumsq = (float*)alloc(4 * (size_t)PB * 512);
    float* scA    = (float*)alloc(4 * 512);
    float* shA    = (float*)alloc(4 * 512);
    float* scB    = (float*)alloc(4 * 64);
    float* shB    = (float*)alloc(4 * 64);
    float* pooled = (float*)alloc(4 * (size_t)G_GRAPHS * 384);
    int*   cnt    = (int*)alloc(4 * G_GRAPHS);
    u16*   bp1    = (u16*)alloc(2 * (size_t)4 * 20 * 64 * 8);   // W1: KC=4,NT=20
    u16*   bp2    = (u16*)alloc(2 * (size_t)1 * 32 * 64 * 8);   // W2: KC=1,NT=32
    u16*   bp3    = (u16*)alloc(2 * (size_t)1 * 24 * 64 * 8);   // W3: KC=1,NT=24
    u16*   bpl1   = (u16*)alloc(2 * (size_t)10 * 1 * 64 * 8);   // lw1: KC=10,NT=1
    u16*   bpl2   = (u16*)alloc(2 * (size_t)16 * 2 * 64 * 8);   // lw2: KC=16,NT=2

    const int LB = (N_NODES + 63) / 64;   // 782 row-tiles for MFMA gemms

    // ---- graph build + W packs (reused by all 3 layers) ----
    k_init_deg<<<(N_NODES + 255) / 256, 256, 0, stream>>>(deg);
    k_hist<<<(N_EDGES + 255) / 256, 256, 0, stream>>>(ei, deg);
    k_scan1<<<SCAN_B, 512, 0, stream>>>(deg, rowptr, bsum);
    k_scan2<<<1, 128, 0, stream>>>(bsum);
    k_scan3<<<(N_NODES + 255) / 256, 256, 0, stream>>>(rowptr, cursor, bsum);
    k_scatter<<<(TOT_E + 255) / 256, 256, 0, stream>>>(ei, cursor, col, cdst);
    k_wpack<128, 320><<<20, 256, 0, stream>>>(W1, bp1);
    k_wpack<16, 512><<<8, 256, 0, stream>>>(W2, bp2);
    k_wpack<32, 384><<<6, 256, 0, stream>>>(W3, bp3);
    k_wpack<320, 16><<<3, 256, 0, stream>>>(lw1, bpl1);
    k_wpack<512, 32><<<8, 256, 0, stream>>>(lw2, bpl2);
    hipMemsetAsync(pooled, 0, 4 * (size_t)G_GRAPHS * 384 + 256, stream);  // pooled + cnt

    // ---- layer 1: GAT(128 -> 20x16) ----
    k_gemm<128, 320, false><<<LB, 256, 0, stream>>>(x, bp1, nullptr, nullptr, hbuf);
    k_scores<20, 16><<<(N_NODES * 20 + 255) / 256, 256, 0, stream>>>(hbuf, as1, ad1, ssrc, sdst);
    k_agg<20, 16><<<(N_NODES + 3) / 4, 256, 0, stream>>>(hbuf, ssrc, sdst, rowptr, col, b1, obuf);
    k_bnstats<320><<<PB, 320, 0, stream>>>(obuf, psum, psumsq);
    k_bnfinal<<<1, 512, 0, stream>>>(psum, psumsq, g1, be1, scA, shA, 320);
    k_gemmb<320, 16, true, true><<<LB, 256, 0, stream>>>(obuf, bpl1, scA, shA, lb1, xbuf);
    k_bnstats<16><<<PB, 256, 0, stream>>>(xbuf, psum, psumsq);
    k_bnfinal<<<1, 512, 0, stream>>>(psum, psumsq, gl1, bel1, scB, shB, 16);

    // ---- layer 2: GAT(16 -> 16x32) ----
    k_gemmb<16, 512, true, false><<<LB, 256, 0, stream>>>(xbuf, bp2, scB, shB, nullptr, hbuf);
    k_scores<16, 32><<<(N_NODES * 16 + 255) / 256, 256, 0, stream>>>(hbuf, as2, ad2, ssrc, sdst);
    k_agg<16, 32><<<(N_NODES + 3) / 4, 256, 0, stream>>>(hbuf, ssrc, sdst, rowptr, col, b2, obuf);
    k_bnstats<512><<<PB, 256, 0, stream>>>(obuf, psum, psumsq);
    k_bnfinal<<<1, 512, 0, stream>>>(psum, psumsq, g2, be2, scA, shA, 512);
    k_gemmb<512, 32, true, true><<<LB, 256, 0, stream>>>(obuf, bpl2, scA, shA, lb2, xbuf);
    k_bnstats<32><<<PB, 256, 0, stream>>>(xbuf, psum, psumsq);
    k_bnfinal<<<1, 512, 0, stream>>>(psum, psumsq, gl2, bel2, scB, shB, 32);

    // ---- layer 3: GAT(32 -> 8x48) ----
    k_gemmb<32, 384, true, false><<<LB, 256, 0, stream>>>(xbuf, bp3, scB, shB, nullptr, hbuf);
    k_scores<8, 48><<<(N_NODES * 8 + 255) / 256, 256, 0, stream>>>(hbuf, as3, ad3, ssrc, sdst);
    k_agg<8, 48><<<(N_NODES + 3) / 4, 256, 0, stream>>>(hbuf, ssrc, sdst, rowptr, col, b3, obuf);
    k_bnstats<384><<<PB, 384, 0, stream>>>(obuf, psum, psumsq);
    k_bnfinal<<<1, 512, 0, stream>>>(psum, psumsq, g3, be3, scA, shA, 384);

    // ---- pool + classifier ----
    k_bhist<<<(N_NODES + 255) / 256, 256, 0, stream>>>(batch, cnt);
    k_pool<<<512, 192, 0, stream>>>(obuf, batch, scA, shA, pooled);
    k_final<<<1, 640, 0, stream>>>(pooled, cnt, lwf, lbf, out);
}